// Round 1
// baseline (1110.903 us; speedup 1.0000x reference)
//
#include <hip/hip_runtime.h>

#define TPB 256
#define Bsz 4
#define Cch 512
#define Nsp 1024      // 32*32 spatial
#define NH 8
#define HDm 64
#define SEQ 77
#define CTX 768
#define GRP_CH 64     // C / 8 groups
#define EPSV 1e-5f

// ---------------- GroupNorm: one block per (b,g) ----------------
__global__ __launch_bounds__(TPB) void gn_kernel(const float* __restrict__ x,
                                                 const float* __restrict__ w,
                                                 const float* __restrict__ bb,
                                                 float* __restrict__ out) {
  int blk = blockIdx.x;
  int b = blk >> 3, g = blk & 7;
  const float* base = x + ((size_t)(b * Cch + g * GRP_CH)) * Nsp;
  float* obase = out + ((size_t)(b * Cch + g * GRP_CH)) * Nsp;
  int tid = threadIdx.x;
  float s = 0.f, s2 = 0.f;
  for (int i = tid; i < (GRP_CH * Nsp) / 4; i += TPB) {
    float4 v = ((const float4*)base)[i];
    s += v.x + v.y + v.z + v.w;
    s2 += v.x * v.x + v.y * v.y + v.z * v.z + v.w * v.w;
  }
  for (int off = 1; off < 64; off <<= 1) {
    s += __shfl_xor(s, off, 64);
    s2 += __shfl_xor(s2, off, 64);
  }
  __shared__ float red[2][4];
  __shared__ float mu_s, rstd_s;
  int wid = tid >> 6;
  if ((tid & 63) == 0) { red[0][wid] = s; red[1][wid] = s2; }
  __syncthreads();
  if (tid == 0) {
    float S = red[0][0] + red[0][1] + red[0][2] + red[0][3];
    float S2 = red[1][0] + red[1][1] + red[1][2] + red[1][3];
    const float inv = 1.f / (float)(GRP_CH * Nsp);
    float mu = S * inv;
    float var = S2 * inv - mu * mu;
    mu_s = mu;
    rstd_s = rsqrtf(var + EPSV);
  }
  __syncthreads();
  float mu = mu_s, rstd = rstd_s;
  for (int i = tid; i < (GRP_CH * Nsp) / 4; i += TPB) {
    float4 v = ((const float4*)base)[i];
    int c = g * GRP_CH + ((i * 4) >> 10);
    float wc = w[c] * rstd;
    float bc = bb[c] - mu * wc;
    float4 o;
    o.x = v.x * wc + bc; o.y = v.y * wc + bc;
    o.z = v.z * wc + bc; o.w = v.w * wc + bc;
    ((float4*)obase)[i] = o;
  }
}

// ---------------- channel-major conv1x1 GEMM ----------------
// Out[b,o,n] = bias[o] + sum_c W[o,c]*In[b,c,n]  (+gelu) (+resid)
__global__ __launch_bounds__(TPB) void gemm_cm(const float* __restrict__ In,
                                               const float* __restrict__ W,
                                               const float* __restrict__ bias,
                                               const float* __restrict__ resid,
                                               float* __restrict__ out,
                                               int Cin, int O, int gelu) {
  int b = blockIdx.z;
  int o0 = blockIdx.y * 128;
  int n0 = blockIdx.x * 128;
  int tid = threadIdx.x;
  __shared__ float Ws[8][128];
  __shared__ float Ins[8][128];
  float acc[8][8];
#pragma unroll
  for (int i = 0; i < 8; ++i)
#pragma unroll
    for (int j = 0; j < 8; ++j) acc[i][j] = 0.f;
  int to = tid >> 4, tn = tid & 15;
  const float* Wp = W + (size_t)(o0 + (tid >> 1)) * Cin + (tid & 1) * 4;
  const float* Ip = In + ((size_t)b * Cin + (tid >> 5)) * Nsp + n0 + (tid & 31) * 4;
  int wc = (tid & 1) * 4, wrow = tid >> 1;
  int ic = tid >> 5, icol = (tid & 31) * 4;
  for (int c0 = 0; c0 < Cin; c0 += 8) {
    float4 wv = *(const float4*)(Wp + c0);
    float4 iv = *(const float4*)(Ip + (size_t)c0 * Nsp);
    __syncthreads();
    Ws[wc + 0][wrow] = wv.x;
    Ws[wc + 1][wrow] = wv.y;
    Ws[wc + 2][wrow] = wv.z;
    Ws[wc + 3][wrow] = wv.w;
    *(float4*)&Ins[ic][icol] = iv;
    __syncthreads();
#pragma unroll
    for (int k = 0; k < 8; ++k) {
      float av[8], bv[8];
      *(float4*)&av[0] = *(const float4*)&Ws[k][to * 8];
      *(float4*)&av[4] = *(const float4*)&Ws[k][to * 8 + 4];
      *(float4*)&bv[0] = *(const float4*)&Ins[k][tn * 8];
      *(float4*)&bv[4] = *(const float4*)&Ins[k][tn * 8 + 4];
#pragma unroll
      for (int i = 0; i < 8; ++i)
#pragma unroll
        for (int j = 0; j < 8; ++j) acc[i][j] += av[i] * bv[j];
    }
  }
#pragma unroll
  for (int i = 0; i < 8; ++i) {
    int o = o0 + to * 8 + i;
    float bs = bias[o];
    size_t off = ((size_t)b * O + o) * Nsp + n0 + tn * 8;
    float r[8];
#pragma unroll
    for (int j = 0; j < 8; ++j) {
      float v = acc[i][j] + bs;
      if (gelu) v = 0.5f * v * (1.f + erff(v * 0.70710678118654752f));
      if (resid) v += resid[off + j];
      r[j] = v;
    }
    *(float4*)(out + off) = make_float4(r[0], r[1], r[2], r[3]);
    *(float4*)(out + off + 4) = make_float4(r[4], r[5], r[6], r[7]);
  }
}

// ---------------- row-major GEMM for context KV projection ----------------
// Out[m,o] = bias[o] + sum_c A[m,c]*W[o,c];  A:[M,K], W:[O,K], Out:[M,O]
__global__ __launch_bounds__(TPB) void gemm_rm(const float* __restrict__ A,
                                               const float* __restrict__ W,
                                               const float* __restrict__ bias,
                                               float* __restrict__ out,
                                               int M, int K, int O) {
  int m0 = blockIdx.x * 64;
  int o0 = blockIdx.y * 64;
  int tid = threadIdx.x;
  __shared__ float As[16][64];
  __shared__ float Bs[16][64];
  float acc[4][4];
#pragma unroll
  for (int i = 0; i < 4; ++i)
#pragma unroll
    for (int j = 0; j < 4; ++j) acc[i][j] = 0.f;
  int tm = tid >> 4, to = tid & 15;
  int lr = tid >> 2, lc = (tid & 3) * 4;
  for (int c0 = 0; c0 < K; c0 += 16) {
    float4 av = make_float4(0.f, 0.f, 0.f, 0.f);
    if (m0 + lr < M) av = *(const float4*)(A + (size_t)(m0 + lr) * K + c0 + lc);
    float4 wv = *(const float4*)(W + (size_t)(o0 + lr) * K + c0 + lc);
    __syncthreads();
    As[lc + 0][lr] = av.x; As[lc + 1][lr] = av.y;
    As[lc + 2][lr] = av.z; As[lc + 3][lr] = av.w;
    Bs[lc + 0][lr] = wv.x; Bs[lc + 1][lr] = wv.y;
    Bs[lc + 2][lr] = wv.z; Bs[lc + 3][lr] = wv.w;
    __syncthreads();
#pragma unroll
    for (int k = 0; k < 16; ++k) {
      float a[4], bv[4];
#pragma unroll
      for (int i = 0; i < 4; ++i) a[i] = As[k][tm * 4 + i];
#pragma unroll
      for (int j = 0; j < 4; ++j) bv[j] = Bs[k][to * 4 + j];
#pragma unroll
      for (int i = 0; i < 4; ++i)
#pragma unroll
        for (int j = 0; j < 4; ++j) acc[i][j] += a[i] * bv[j];
    }
  }
#pragma unroll
  for (int i = 0; i < 4; ++i) {
    int m = m0 + tm * 4 + i;
    if (m < M) {
#pragma unroll
      for (int j = 0; j < 4; ++j) {
        int o = o0 + to * 4 + j;
        out[(size_t)m * O + o] = acc[i][j] + bias[o];
      }
    }
  }
}

// ---------------- self-attention, flash-style ----------------
// qkv layout [B, 3C, N]; q ch [0,512), k [512,1024), v [1024,1536)
// out[b, h*64+d, n] = attn
__global__ __launch_bounds__(TPB) void sa_attn(const float* __restrict__ qkv,
                                               float* __restrict__ out) {
  int b = blockIdx.z, h = blockIdx.y, q0 = blockIdx.x * 32;
  const float* Qp = qkv + ((size_t)(b * 3 * Cch) + h * HDm) * Nsp;
  const float* Kp = Qp + (size_t)Cch * Nsp;
  const float* Vp = Kp + (size_t)Cch * Nsp;
  __shared__ float Qs[HDm][32];
  __shared__ float Ks[HDm][68];
  __shared__ float Vs[64][68];
  __shared__ float Ps[32][68];
  int tid = threadIdx.x;
  for (int i = tid; i < HDm * 32; i += TPB) {
    int d = i >> 5, qr2 = i & 31;
    Qs[d][qr2] = Qp[(size_t)d * Nsp + q0 + qr2] * 0.125f;
  }
  int qr = tid >> 3, sub = tid & 7;
  float m = -1e30f, l = 0.f;
  float acc[8];
#pragma unroll
  for (int i = 0; i < 8; ++i) acc[i] = 0.f;
  for (int kt = 0; kt < 16; ++kt) {
    int k0 = kt * 64;
    __syncthreads();
    for (int i = tid; i < HDm * 64; i += TPB) {
      int d = i >> 6, kj = i & 63;
      float kvl = Kp[(size_t)d * Nsp + k0 + kj];
      float vvl = Vp[(size_t)d * Nsp + k0 + kj];
      Ks[d][kj] = kvl;
      Vs[kj][d] = vvl;
    }
    __syncthreads();
    float s[8];
#pragma unroll
    for (int i = 0; i < 8; ++i) s[i] = 0.f;
    for (int d = 0; d < HDm; ++d) {
      float qv = Qs[d][qr];
      float kk[8];
      *(float4*)&kk[0] = *(const float4*)&Ks[d][sub * 8];
      *(float4*)&kk[4] = *(const float4*)&Ks[d][sub * 8 + 4];
#pragma unroll
      for (int i = 0; i < 8; ++i) s[i] += qv * kk[i];
    }
    float mx = s[0];
#pragma unroll
    for (int i = 1; i < 8; ++i) mx = fmaxf(mx, s[i]);
    for (int off = 1; off < 8; off <<= 1) mx = fmaxf(mx, __shfl_xor(mx, off, 8));
    float mnew = fmaxf(m, mx);
    float scale = __expf(m - mnew);
    float ps = 0.f;
#pragma unroll
    for (int i = 0; i < 8; ++i) {
      s[i] = __expf(s[i] - mnew);
      ps += s[i];
    }
    for (int off = 1; off < 8; off <<= 1) ps += __shfl_xor(ps, off, 8);
    l = l * scale + ps;
    m = mnew;
#pragma unroll
    for (int i = 0; i < 8; ++i) acc[i] *= scale;
    *(float4*)&Ps[qr][sub * 8] = make_float4(s[0], s[1], s[2], s[3]);
    *(float4*)&Ps[qr][sub * 8 + 4] = make_float4(s[4], s[5], s[6], s[7]);
    __syncthreads();
    for (int kj = 0; kj < 64; ++kj) {
      float p = Ps[qr][kj];
      float vv[8];
      *(float4*)&vv[0] = *(const float4*)&Vs[kj][sub * 8];
      *(float4*)&vv[4] = *(const float4*)&Vs[kj][sub * 8 + 4];
#pragma unroll
      for (int i = 0; i < 8; ++i) acc[i] += p * vv[i];
    }
  }
  float rl = 1.f / l;
#pragma unroll
  for (int i = 0; i < 8; ++i) {
    int d = sub * 8 + i;
    out[((size_t)(b * Cch + h * HDm + d)) * Nsp + q0 + qr] = acc[i] * rl;
  }
}

// ---------------- cross-attention ----------------
// q: [B,C,N] channel-major; kv: [B,SEQ,2,NH,HD] row-major
__global__ __launch_bounds__(TPB) void ca_attn(const float* __restrict__ qb,
                                               const float* __restrict__ kv,
                                               float* __restrict__ out) {
  int b = blockIdx.z, h = blockIdx.y, q0 = blockIdx.x * 32;
  const float* Qp = qb + ((size_t)(b * Cch) + h * HDm) * Nsp;
  __shared__ float Qs[HDm][32];
  __shared__ float KsT[HDm][81];
  __shared__ float Vs[SEQ][68];
  __shared__ float Ps[32][80];
  int tid = threadIdx.x;
  for (int i = tid; i < HDm * 32; i += TPB) {
    int d = i >> 5, qr2 = i & 31;
    Qs[d][qr2] = Qp[(size_t)d * Nsp + q0 + qr2] * 0.125f;
  }
  for (int i = tid; i < SEQ * HDm; i += TPB) {
    int s_ = i >> 6, d = i & 63;
    size_t kidx = ((size_t)(b * SEQ + s_)) * 1024 + h * HDm + d;
    KsT[d][s_] = kv[kidx];
    Vs[s_][d] = kv[kidx + 512];
  }
  // zero the KsT pad columns (77..80)
  if (tid < 256) {
    int d = tid >> 2, s_ = 77 + (tid & 3);
    KsT[d][s_] = 0.f;
  }
  __syncthreads();
  int qr = tid >> 3, sub = tid & 7;
  float sc[10];
#pragma unroll
  for (int t = 0; t < 10; ++t) sc[t] = 0.f;
  for (int d = 0; d < HDm; ++d) {
    float qv = Qs[d][qr];
#pragma unroll
    for (int t = 0; t < 10; ++t) sc[t] += qv * KsT[d][sub + 8 * t];
  }
  float mx = -1e30f;
#pragma unroll
  for (int t = 0; t < 10; ++t) {
    int kj = sub + 8 * t;
    if (kj >= SEQ) sc[t] = -1e30f;
    mx = fmaxf(mx, sc[t]);
  }
  for (int off = 1; off < 8; off <<= 1) mx = fmaxf(mx, __shfl_xor(mx, off, 8));
  float l = 0.f;
#pragma unroll
  for (int t = 0; t < 10; ++t) {
    int kj = sub + 8 * t;
    float p = __expf(sc[t] - mx);
    l += p;
    if (kj < 80) Ps[qr][kj] = p;
  }
  for (int off = 1; off < 8; off <<= 1) l += __shfl_xor(l, off, 8);
  __syncthreads();
  float acc[8];
#pragma unroll
  for (int i = 0; i < 8; ++i) acc[i] = 0.f;
  for (int sj = 0; sj < SEQ; ++sj) {
    float p = Ps[qr][sj];
    float vv[8];
    *(float4*)&vv[0] = *(const float4*)&Vs[sj][sub * 8];
    *(float4*)&vv[4] = *(const float4*)&Vs[sj][sub * 8 + 4];
#pragma unroll
    for (int i = 0; i < 8; ++i) acc[i] += p * vv[i];
  }
  float rl = 1.f / l;
#pragma unroll
  for (int i = 0; i < 8; ++i) {
    int d = sub * 8 + i;
    out[((size_t)(b * Cch + h * HDm + d)) * Nsp + q0 + qr] = acc[i] * rl;
  }
}

extern "C" void kernel_launch(void* const* d_in, const int* in_sizes, int n_in,
                              void* d_out, int out_size, void* d_ws, size_t ws_size,
                              hipStream_t stream) {
  const float* x        = (const float*)d_in[0];
  const float* context  = (const float*)d_in[1];
  const float* sa_nw    = (const float*)d_in[2];
  const float* sa_nb    = (const float*)d_in[3];
  const float* sa_qkv_w = (const float*)d_in[4];
  const float* sa_qkv_b = (const float*)d_in[5];
  const float* sa_pw    = (const float*)d_in[6];
  const float* sa_pb    = (const float*)d_in[7];
  const float* ca_nw    = (const float*)d_in[8];
  const float* ca_nb    = (const float*)d_in[9];
  const float* ca_qw    = (const float*)d_in[10];
  const float* ca_qb    = (const float*)d_in[11];
  const float* ca_kvw   = (const float*)d_in[12];
  const float* ca_kvb   = (const float*)d_in[13];
  const float* ca_pw    = (const float*)d_in[14];
  const float* ca_pb    = (const float*)d_in[15];
  const float* ff_nw    = (const float*)d_in[16];
  const float* ff_nb    = (const float*)d_in[17];
  const float* ff_w1    = (const float*)d_in[18];
  const float* ff_b1    = (const float*)d_in[19];
  const float* ff_w2    = (const float*)d_in[20];
  const float* ff_b2    = (const float*)d_in[21];
  float* outp = (float*)d_out;

  char* ws = (char*)d_ws;
  float* xcur  = (float*)(ws);                       // 8 MB  [B,C,N]
  float* hbuf  = (float*)(ws + (8u << 20));          // 8 MB  [B,C,N]
  float* attno = (float*)(ws + (16u << 20));         // 8 MB  [B,C,N]
  float* big   = (float*)(ws + (24u << 20));         // 32 MB (qkv | qbuf+kv | h1)
  float* qkv   = big;                                // 24 MB [B,3C,N]
  float* qbuf  = big;                                //  8 MB [B,C,N]
  float* kvbuf = (float*)(ws + (32u << 20));         // 1.3 MB [B*SEQ, 2C]
  float* h1    = big;                                // 32 MB [B,4C,N]

  dim3 blk(TPB);
  // ---- self-attention ----
  gn_kernel<<<32, blk, 0, stream>>>(x, sa_nw, sa_nb, hbuf);
  gemm_cm<<<dim3(8, 12, 4), blk, 0, stream>>>(hbuf, sa_qkv_w, sa_qkv_b, nullptr, qkv, 512, 1536, 0);
  sa_attn<<<dim3(32, 8, 4), blk, 0, stream>>>(qkv, attno);
  gemm_cm<<<dim3(8, 4, 4), blk, 0, stream>>>(attno, sa_pw, sa_pb, x, xcur, 512, 512, 0);
  // ---- cross-attention ----
  gn_kernel<<<32, blk, 0, stream>>>(xcur, ca_nw, ca_nb, hbuf);
  gemm_cm<<<dim3(8, 4, 4), blk, 0, stream>>>(hbuf, ca_qw, ca_qb, nullptr, qbuf, 512, 512, 0);
  gemm_rm<<<dim3(5, 16), blk, 0, stream>>>(context, ca_kvw, ca_kvb, kvbuf, Bsz * SEQ, CTX, 1024);
  ca_attn<<<dim3(32, 8, 4), blk, 0, stream>>>(qbuf, kvbuf, attno);
  gemm_cm<<<dim3(8, 4, 4), blk, 0, stream>>>(attno, ca_pw, ca_pb, xcur, xcur, 512, 512, 0);
  // ---- FFN ----
  gn_kernel<<<32, blk, 0, stream>>>(xcur, ff_nw, ff_nb, hbuf);
  gemm_cm<<<dim3(8, 16, 4), blk, 0, stream>>>(hbuf, ff_w1, ff_b1, nullptr, h1, 512, 2048, 1);
  gemm_cm<<<dim3(8, 4, 4), blk, 0, stream>>>(h1, ff_w2, ff_b2, xcur, outp, 2048, 512, 0);
}

// Round 2
// 479.747 us; speedup vs baseline: 2.3156x; 2.3156x over previous
//
#include <hip/hip_runtime.h>

#define TPB 256
#define Bsz 4
#define Nsp 1024
#define Cch 512
#define SEQ 77
#define CTX 768
#define EPSV 1e-5f
#define MTOK 4096   // B * N

typedef __attribute__((ext_vector_type(8))) short s8v;
typedef __attribute__((ext_vector_type(4))) float f32x4;
typedef const __attribute__((address_space(1))) void* gas_t;
typedef __attribute__((address_space(3))) void* las_t;

static __device__ __forceinline__ float bf2f(short s) {
  union { unsigned u; float f; } z; z.u = ((unsigned)(unsigned short)s) << 16; return z.f;
}
static __device__ __forceinline__ short f2bf(float f) {
  union { float f; unsigned u; } v; v.f = f;
  unsigned r = v.u + 0x7fffu + ((v.u >> 16) & 1u);
  return (short)(r >> 16);
}

// ---------- transpose x [B,C,N] f32 -> xt [B,N,C] f32 ----------
__global__ __launch_bounds__(TPB) void transpose_in(const float* __restrict__ x,
                                                    float* __restrict__ xt) {
  int b = blockIdx.z, c0 = blockIdx.y * 32, n0 = blockIdx.x * 32;
  __shared__ float t[32][33];
  int tid = threadIdx.x;
  int cl = tid >> 3, nl4 = (tid & 7) * 4;
  float4 v = *(const float4*)(x + ((size_t)(b * Cch + c0 + cl)) * Nsp + n0 + nl4);
  t[cl][nl4 + 0] = v.x; t[cl][nl4 + 1] = v.y; t[cl][nl4 + 2] = v.z; t[cl][nl4 + 3] = v.w;
  __syncthreads();
  int nl = tid >> 3, cl4 = (tid & 7) * 4;
  float4 o = make_float4(t[cl4 + 0][nl], t[cl4 + 1][nl], t[cl4 + 2][nl], t[cl4 + 3][nl]);
  *(float4*)(xt + ((size_t)(b * Nsp + n0 + nl)) * Cch + c0 + cl4) = o;
}

// ---------- transpose ffn-out [B,N,C] f32 -> out [B,C,N] f32 ----------
__global__ __launch_bounds__(TPB) void transpose_out(const float* __restrict__ f,
                                                     float* __restrict__ outp) {
  int b = blockIdx.z, n0 = blockIdx.y * 32, c0 = blockIdx.x * 32;
  __shared__ float t[32][33];
  int tid = threadIdx.x;
  int nl = tid >> 3, cl4 = (tid & 7) * 4;
  float4 v = *(const float4*)(f + ((size_t)(b * Nsp + n0 + nl)) * Cch + c0 + cl4);
  t[nl][cl4 + 0] = v.x; t[nl][cl4 + 1] = v.y; t[nl][cl4 + 2] = v.z; t[nl][cl4 + 3] = v.w;
  __syncthreads();
  int cl = tid >> 3, nl4 = (tid & 7) * 4;
  float4 o = make_float4(t[nl4 + 0][cl], t[nl4 + 1][cl], t[nl4 + 2][cl], t[nl4 + 3][cl]);
  *(float4*)(outp + ((size_t)(b * Cch + c0 + cl)) * Nsp + n0 + nl4) = o;
}

// ---------- weight f32 -> bf16 (7 segments, unit = float4) ----------
__global__ __launch_bounds__(TPB) void convert_w(const float* a0, const float* a1,
                                                 const float* a2, const float* a3,
                                                 const float* a4, const float* a5,
                                                 const float* a6, short* __restrict__ dst) {
  int u = blockIdx.x * TPB + threadIdx.x;
  const float* src; int base;
  if      (u < 196608) { src = a0; base = 0; }
  else if (u < 262144) { src = a1; base = 196608; }
  else if (u < 327680) { src = a2; base = 262144; }
  else if (u < 524288) { src = a3; base = 327680; }
  else if (u < 589824) { src = a4; base = 524288; }
  else if (u < 851968) { src = a5; base = 589824; }
  else                 { src = a6; base = 851968; }
  float4 v = *(const float4*)(src + (size_t)(u - base) * 4);
  short4 o = make_short4(f2bf(v.x), f2bf(v.y), f2bf(v.z), f2bf(v.w));
  *(short4*)(dst + (size_t)u * 4) = o;
}

// ---------- context f32 [B,77,768] -> bf16 padded [B*96,768] ----------
__global__ __launch_bounds__(TPB) void convert_ctx(const float* __restrict__ ctx,
                                                   short* __restrict__ dst) {
  int u = blockIdx.x * TPB + threadIdx.x;   // 73728 units
  int row = u / 192, c4 = u - row * 192;
  int b = row / 96, s_ = row - b * 96;
  short4 o;
  if (s_ < SEQ) {
    float4 v = *(const float4*)(ctx + ((size_t)(b * SEQ + s_)) * CTX + c4 * 4);
    o = make_short4(f2bf(v.x), f2bf(v.y), f2bf(v.z), f2bf(v.w));
  } else {
    o = make_short4(0, 0, 0, 0);
  }
  *(short4*)(dst + (size_t)row * CTX + c4 * 4) = o;
}

// ---------- GroupNorm token-major: f32 [4096,512] -> bf16 [4096,512] ----------
__global__ __launch_bounds__(TPB) void gn_tm(const float* __restrict__ x,
                                             const float* __restrict__ w,
                                             const float* __restrict__ bb,
                                             short* __restrict__ outp) {
  int b = blockIdx.x >> 3, g = blockIdx.x & 7;
  const float* p = x + (size_t)b * Nsp * Cch + g * 64;
  short* op = (short*)outp + (size_t)b * Nsp * Cch + g * 64;
  int tid = threadIdx.x;
  float s = 0.f, s2 = 0.f;
  for (int i = tid; i < Nsp * 16; i += TPB) {
    int n = i >> 4, c4 = i & 15;
    float4 v = *(const float4*)(p + (size_t)n * Cch + c4 * 4);
    s += v.x + v.y + v.z + v.w;
    s2 += v.x * v.x + v.y * v.y + v.z * v.z + v.w * v.w;
  }
  for (int off = 1; off < 64; off <<= 1) {
    s += __shfl_xor(s, off, 64);
    s2 += __shfl_xor(s2, off, 64);
  }
  __shared__ float red[2][4];
  __shared__ float mu_s, rstd_s;
  int wid = tid >> 6;
  if ((tid & 63) == 0) { red[0][wid] = s; red[1][wid] = s2; }
  __syncthreads();
  if (tid == 0) {
    float S = red[0][0] + red[0][1] + red[0][2] + red[0][3];
    float S2 = red[1][0] + red[1][1] + red[1][2] + red[1][3];
    const float inv = 1.f / (float)(64 * Nsp);
    float mu = S * inv;
    float var = S2 * inv - mu * mu;
    mu_s = mu; rstd_s = rsqrtf(var + EPSV);
  }
  __syncthreads();
  float mu = mu_s, rstd = rstd_s;
  for (int i = tid; i < Nsp * 16; i += TPB) {
    int n = i >> 4, c4 = i & 15;
    float4 v = *(const float4*)(p + (size_t)n * Cch + c4 * 4);
    int c = g * 64 + c4 * 4;
    float w0 = w[c] * rstd, w1 = w[c + 1] * rstd, w2 = w[c + 2] * rstd, w3 = w[c + 3] * rstd;
    short4 o = make_short4(f2bf((v.x - mu) * w0 + bb[c]),
                           f2bf((v.y - mu) * w1 + bb[c + 1]),
                           f2bf((v.z - mu) * w2 + bb[c + 2]),
                           f2bf((v.w - mu) * w3 + bb[c + 3]));
    *(short4*)(op + (size_t)n * Cch + c4 * 4) = o;
  }
}

// ---------- bf16 MFMA NT-GEMM: Out[m,o] = sum_k A[m,k] * W[o,k] + bias[o] ----------
// MODE 0: bf16 out; MODE 1: f32 out += resid; MODE 2: gelu -> bf16 out
template<int MODE>
__global__ __launch_bounds__(TPB) void gemm_nt(const short* __restrict__ A,
                                               const short* __restrict__ Bw,
                                               const float* __restrict__ bias,
                                               const float* __restrict__ resid,
                                               void* __restrict__ outp,
                                               int M, int K, int O) {
  __shared__ __align__(16) short As[128 * 64];
  __shared__ __align__(16) short Bs[128 * 64];
  int tid = threadIdx.x;
  int lane = tid & 63, w = tid >> 6;
  int wr = w >> 1, wc = w & 1;
  int m0 = blockIdx.x * 128, o0 = blockIdx.y * 128;
  f32x4 acc[4][4];
#pragma unroll
  for (int i = 0; i < 4; ++i)
#pragma unroll
    for (int j = 0; j < 4; ++j) acc[i][j] = (f32x4){0.f, 0.f, 0.f, 0.f};
  int nk = K >> 6;
  for (int kt = 0; kt < nk; ++kt) {
    int k0 = kt << 6;
    __syncthreads();
#pragma unroll
    for (int i = 0; i < 4; ++i) {
      int c = i * 256 + tid;
      int r = c >> 3, qs = c & 7, qg = qs ^ (r & 7);
      const char* ga = (const char*)(A + ((size_t)(m0 + r) * K + k0)) + (qg << 4);
      __builtin_amdgcn_global_load_lds((gas_t)ga,
          (las_t)((char*)As + ((i * 256 + w * 64) << 4)), 16, 0, 0);
    }
#pragma unroll
    for (int i = 0; i < 4; ++i) {
      int c = i * 256 + tid;
      int r = c >> 3, qs = c & 7, qg = qs ^ (r & 7);
      const char* gb = (const char*)(Bw + ((size_t)(o0 + r) * K + k0)) + (qg << 4);
      __builtin_amdgcn_global_load_lds((gas_t)gb,
          (las_t)((char*)Bs + ((i * 256 + w * 64) << 4)), 16, 0, 0);
    }
    __syncthreads();
#pragma unroll
    for (int kk = 0; kk < 2; ++kk) {
      s8v a[4], bfr[4];
#pragma unroll
      for (int m = 0; m < 4; ++m) {
        int r = wr * 64 + m * 16 + (lane & 15);
        int q = (lane >> 4) + (kk << 2);
        a[m] = *(const s8v*)((const char*)As + r * 128 + ((q ^ (r & 7)) << 4));
      }
#pragma unroll
      for (int n = 0; n < 4; ++n) {
        int r = wc * 64 + n * 16 + (lane & 15);
        int q = (lane >> 4) + (kk << 2);
        bfr[n] = *(const s8v*)((const char*)Bs + r * 128 + ((q ^ (r & 7)) << 4));
      }
#pragma unroll
      for (int m = 0; m < 4; ++m)
#pragma unroll
        for (int n = 0; n < 4; ++n)
          acc[m][n] = __builtin_amdgcn_mfma_f32_16x16x32_bf16(a[m], bfr[n], acc[m][n], 0, 0, 0);
    }
  }
  float bv[4];
#pragma unroll
  for (int n = 0; n < 4; ++n) bv[n] = bias[o0 + wc * 64 + n * 16 + (lane & 15)];
  int row_b = m0 + wr * 64 + ((lane >> 4) << 2);
  int col_b = o0 + wc * 64 + (lane & 15);
#pragma unroll
  for (int m = 0; m < 4; ++m) {
#pragma unroll
    for (int i = 0; i < 4; ++i) {
      int mg = row_b + m * 16 + i;
#pragma unroll
      for (int n = 0; n < 4; ++n) {
        int og = col_b + n * 16;
        float v = acc[m][n][i] + bv[n];
        size_t idx = (size_t)mg * O + og;
        if (MODE == 0) {
          ((short*)outp)[idx] = f2bf(v);
        } else if (MODE == 1) {
          ((float*)outp)[idx] = v + resid[idx];
        } else {
          float gv = 0.5f * v * (1.f + erff(v * 0.70710678118654752f));
          ((short*)outp)[idx] = f2bf(gv);
        }
      }
    }
  }
}

// ---------- self-attention (fp32 math, bf16 token-major I/O) ----------
// qkv bf16 [4096, 1536]; out bf16 [4096, 512]
__global__ __launch_bounds__(TPB) void sa_attn_tm(const short* __restrict__ qkv,
                                                  short* __restrict__ outp) {
  int b = blockIdx.z, h = blockIdx.y, q0 = blockIdx.x * 32;
  __shared__ float Qs[64][32];
  __shared__ float Ks[64][68];
  __shared__ float Vs[64][72];
  __shared__ float Ps[32][68];
  int tid = threadIdx.x;
  {
    int row = tid >> 3, c8 = tid & 7;
    const short* p = qkv + (size_t)(b * Nsp + q0 + row) * 1536 + h * 64 + c8 * 8;
    s8v v = *(const s8v*)p;
#pragma unroll
    for (int j = 0; j < 8; ++j) Qs[c8 * 8 + j][row] = bf2f(v[j]) * 0.125f;
  }
  int qr = tid >> 3, sub = tid & 7;
  float mrun = -1e30f, lrun = 0.f;
  float acc[8];
#pragma unroll
  for (int i = 0; i < 8; ++i) acc[i] = 0.f;
  for (int kt = 0; kt < 16; ++kt) {
    int k0 = kt * 64;
    __syncthreads();
#pragma unroll
    for (int ii = 0; ii < 2; ++ii) {
      int i = ii * 256 + tid;
      int kj = i >> 3, c8 = i & 7;
      const short* pk = qkv + (size_t)(b * Nsp + k0 + kj) * 1536 + 512 + h * 64 + c8 * 8;
      s8v k8 = *(const s8v*)pk;
      s8v v8 = *(const s8v*)(pk + 512);
#pragma unroll
      for (int j = 0; j < 8; ++j) Ks[c8 * 8 + j][kj] = bf2f(k8[j]);
      float vf[8];
#pragma unroll
      for (int j = 0; j < 8; ++j) vf[j] = bf2f(v8[j]);
      *(float4*)&Vs[kj][c8 * 8] = make_float4(vf[0], vf[1], vf[2], vf[3]);
      *(float4*)&Vs[kj][c8 * 8 + 4] = make_float4(vf[4], vf[5], vf[6], vf[7]);
    }
    __syncthreads();
    float s[8];
#pragma unroll
    for (int i = 0; i < 8; ++i) s[i] = 0.f;
    for (int d = 0; d < 64; ++d) {
      float qv = Qs[d][qr];
      float kk[8];
      *(float4*)&kk[0] = *(const float4*)&Ks[d][sub * 8];
      *(float4*)&kk[4] = *(const float4*)&Ks[d][sub * 8 + 4];
#pragma unroll
      for (int i = 0; i < 8; ++i) s[i] += qv * kk[i];
    }
    float mx = s[0];
#pragma unroll
    for (int i = 1; i < 8; ++i) mx = fmaxf(mx, s[i]);
    for (int off = 1; off < 8; off <<= 1) mx = fmaxf(mx, __shfl_xor(mx, off, 8));
    float mnew = fmaxf(mrun, mx);
    float scale = __expf(mrun - mnew);
    float ps = 0.f;
#pragma unroll
    for (int i = 0; i < 8; ++i) { s[i] = __expf(s[i] - mnew); ps += s[i]; }
    for (int off = 1; off < 8; off <<= 1) ps += __shfl_xor(ps, off, 8);
    lrun = lrun * scale + ps;
    mrun = mnew;
#pragma unroll
    for (int i = 0; i < 8; ++i) acc[i] *= scale;
    *(float4*)&Ps[qr][sub * 8] = make_float4(s[0], s[1], s[2], s[3]);
    *(float4*)&Ps[qr][sub * 8 + 4] = make_float4(s[4], s[5], s[6], s[7]);
    __syncthreads();
    for (int kj = 0; kj < 64; ++kj) {
      float p = Ps[qr][kj];
      float vv[8];
      *(float4*)&vv[0] = *(const float4*)&Vs[kj][sub * 8];
      *(float4*)&vv[4] = *(const float4*)&Vs[kj][sub * 8 + 4];
#pragma unroll
      for (int i = 0; i < 8; ++i) acc[i] += p * vv[i];
    }
  }
  float rl = 1.f / lrun;
  union { short s[8]; int4 v; } ob;
#pragma unroll
  for (int i = 0; i < 8; ++i) ob.s[i] = f2bf(acc[i] * rl);
  *(int4*)(outp + (size_t)(b * Nsp + q0 + qr) * Cch + h * 64 + sub * 8) = ob.v;
}

// ---------- cross-attention (fp32 math, bf16 I/O) ----------
// qb bf16 [4096,512]; kvb bf16 [384,1024] (rows b*96+s); out bf16 [4096,512]
__global__ __launch_bounds__(TPB) void ca_attn_tm(const short* __restrict__ qb,
                                                  const short* __restrict__ kvb,
                                                  short* __restrict__ outp) {
  int b = blockIdx.z, h = blockIdx.y, q0 = blockIdx.x * 32;
  __shared__ float Qs[64][32];
  __shared__ float KsT[64][81];
  __shared__ float Vs[SEQ][72];
  __shared__ float Ps[32][80];
  int tid = threadIdx.x;
  {
    int row = tid >> 3, c8 = tid & 7;
    const short* p = qb + (size_t)(b * Nsp + q0 + row) * Cch + h * 64 + c8 * 8;
    s8v v = *(const s8v*)p;
#pragma unroll
    for (int j = 0; j < 8; ++j) Qs[c8 * 8 + j][row] = bf2f(v[j]) * 0.125f;
  }
  for (int i = tid; i < SEQ * 8; i += TPB) {
    int s_ = i >> 3, c8 = i & 7;
    const short* pk = kvb + (size_t)(b * 96 + s_) * 1024 + h * 64 + c8 * 8;
    s8v k8 = *(const s8v*)pk;
    s8v v8 = *(const s8v*)(pk + 512);
#pragma unroll
    for (int j = 0; j < 8; ++j) KsT[c8 * 8 + j][s_] = bf2f(k8[j]);
    float vf[8];
#pragma unroll
    for (int j = 0; j < 8; ++j) vf[j] = bf2f(v8[j]);
    *(float4*)&Vs[s_][c8 * 8] = make_float4(vf[0], vf[1], vf[2], vf[3]);
    *(float4*)&Vs[s_][c8 * 8 + 4] = make_float4(vf[4], vf[5], vf[6], vf[7]);
  }
  {
    int d = tid >> 2, cc = SEQ + (tid & 3);
    KsT[d][cc] = 0.f;
  }
  __syncthreads();
  int qr = tid >> 3, sub = tid & 7;
  float sc[10];
#pragma unroll
  for (int t = 0; t < 10; ++t) sc[t] = 0.f;
  for (int d = 0; d < 64; ++d) {
    float qv = Qs[d][qr];
#pragma unroll
    for (int t = 0; t < 10; ++t) sc[t] += qv * KsT[d][sub + 8 * t];
  }
  float mx = -1e30f;
#pragma unroll
  for (int t = 0; t < 10; ++t) {
    int kj = sub + 8 * t;
    if (kj >= SEQ) sc[t] = -1e30f;
    mx = fmaxf(mx, sc[t]);
  }
  for (int off = 1; off < 8; off <<= 1) mx = fmaxf(mx, __shfl_xor(mx, off, 8));
  float l = 0.f;
#pragma unroll
  for (int t = 0; t < 10; ++t) {
    int kj = sub + 8 * t;
    float p = __expf(sc[t] - mx);
    l += p;
    Ps[qr][kj] = p;
  }
  for (int off = 1; off < 8; off <<= 1) l += __shfl_xor(l, off, 8);
  __syncthreads();
  float acc[8];
#pragma unroll
  for (int i = 0; i < 8; ++i) acc[i] = 0.f;
  for (int sj = 0; sj < SEQ; ++sj) {
    float p = Ps[qr][sj];
    float vv[8];
    *(float4*)&vv[0] = *(const float4*)&Vs[sj][sub * 8];
    *(float4*)&vv[4] = *(const float4*)&Vs[sj][sub * 8 + 4];
#pragma unroll
    for (int i = 0; i < 8; ++i) acc[i] += p * vv[i];
  }
  float rl = 1.f / l;
  union { short s[8]; int4 v; } ob;
#pragma unroll
  for (int i = 0; i < 8; ++i) ob.s[i] = f2bf(acc[i] * rl);
  *(int4*)(outp + (size_t)(b * Nsp + q0 + qr) * Cch + h * 64 + sub * 8) = ob.v;
}

extern "C" void kernel_launch(void* const* d_in, const int* in_sizes, int n_in,
                              void* d_out, int out_size, void* d_ws, size_t ws_size,
                              hipStream_t stream) {
  const float* x        = (const float*)d_in[0];
  const float* context  = (const float*)d_in[1];
  const float* sa_nw    = (const float*)d_in[2];
  const float* sa_nb    = (const float*)d_in[3];
  const float* sa_qkv_w = (const float*)d_in[4];
  const float* sa_qkv_b = (const float*)d_in[5];
  const float* sa_pw    = (const float*)d_in[6];
  const float* sa_pb    = (const float*)d_in[7];
  const float* ca_nw    = (const float*)d_in[8];
  const float* ca_nb    = (const float*)d_in[9];
  const float* ca_qw    = (const float*)d_in[10];
  const float* ca_qb    = (const float*)d_in[11];
  const float* ca_kvw   = (const float*)d_in[12];
  const float* ca_kvb   = (const float*)d_in[13];
  const float* ca_pw    = (const float*)d_in[14];
  const float* ca_pb    = (const float*)d_in[15];
  const float* ff_nw    = (const float*)d_in[16];
  const float* ff_nb    = (const float*)d_in[17];
  const float* ff_w1    = (const float*)d_in[18];
  const float* ff_b1    = (const float*)d_in[19];
  const float* ff_w2    = (const float*)d_in[20];
  const float* ff_b2    = (const float*)d_in[21];
  float* outp = (float*)d_out;

  char* ws = (char*)d_ws;
  float* xt    = (float*)(ws);                    // [0,8M)   xt, later ffn-out
  float* xcur  = (float*)(ws + (8u << 20));       // [8,16M)  residual stream
  short* hb    = (short*)(ws + (16u << 20));      // [16,20M) GN out / attn out (bf16)
  short* qkvb  = (short*)(ws + (20u << 20));      // [20,32M) qkv bf16 (later qb / h1)
  short* qb    = (short*)(ws + (20u << 20));      // [20,24M)
  short* h1    = (short*)(ws + (20u << 20));      // [20,36M)
  short* kvb   = (short*)(ws + (36u << 20));      // [36,37M)
  short* ctxb  = (short*)(ws + (37u << 20));      // [37,38M)
  short* wb    = (short*)(ws + (38u << 20));      // [38,~47M) bf16 weights

  short* w_qkv = wb;
  short* w_sap = wb + 786432;
  short* w_caq = wb + 1048576;
  short* w_kv  = wb + 1310720;
  short* w_cap = wb + 2097152;
  short* w_f1  = wb + 2359296;
  short* w_f2  = wb + 3407872;

  dim3 blk(TPB);
  transpose_in<<<dim3(32, 16, 4), blk, 0, stream>>>(x, xt);
  convert_w<<<4352, blk, 0, stream>>>(sa_qkv_w, sa_pw, ca_qw, ca_kvw, ca_pw, ff_w1, ff_w2, wb);
  convert_ctx<<<288, blk, 0, stream>>>(context, ctxb);

  // ---- self-attention ----
  gn_tm<<<32, blk, 0, stream>>>(xt, sa_nw, sa_nb, hb);
  gemm_nt<0><<<dim3(32, 12), blk, 0, stream>>>(hb, w_qkv, sa_qkv_b, nullptr, qkvb, MTOK, 512, 1536);
  sa_attn_tm<<<dim3(32, 8, 4), blk, 0, stream>>>(qkvb, hb);
  gemm_nt<1><<<dim3(32, 4), blk, 0, stream>>>(hb, w_sap, sa_pb, xt, xcur, MTOK, 512, 512);

  // ---- cross-attention ----
  gn_tm<<<32, blk, 0, stream>>>(xcur, ca_nw, ca_nb, hb);
  gemm_nt<0><<<dim3(32, 4), blk, 0, stream>>>(hb, w_caq, ca_qb, nullptr, qb, MTOK, 512, 512);
  gemm_nt<0><<<dim3(3, 8), blk, 0, stream>>>(ctxb, w_kv, ca_kvb, nullptr, kvb, 384, 768, 1024);
  ca_attn_tm<<<dim3(32, 8, 4), blk, 0, stream>>>(qb, kvb, hb);
  gemm_nt<1><<<dim3(32, 4), blk, 0, stream>>>(hb, w_cap, ca_pb, xcur, xcur, MTOK, 512, 512);

  // ---- FFN ----
  gn_tm<<<32, blk, 0, stream>>>(xcur, ff_nw, ff_nb, hb);
  gemm_nt<2><<<dim3(32, 16), blk, 0, stream>>>(hb, w_f1, ff_b1, nullptr, h1, MTOK, 512, 2048);
  gemm_nt<1><<<dim3(32, 4), blk, 0, stream>>>(h1, w_f2, ff_b2, xcur, xt, MTOK, 2048, 512);
  transpose_out<<<dim3(16, 32, 4), blk, 0, stream>>>(xt, outp);
}

// Round 3
// 295.801 us; speedup vs baseline: 3.7556x; 1.6219x over previous
//
#include <hip/hip_runtime.h>

#define TPB 256
#define Bsz 4
#define Nsp 1024
#define Cch 512
#define SEQ 77
#define CTX 768
#define EPSV 1e-5f
#define MTOK 4096   // B * N

typedef __attribute__((ext_vector_type(8))) short s8v;
typedef __attribute__((ext_vector_type(4))) float f32x4;
typedef const __attribute__((address_space(1))) void* gas_t;
typedef __attribute__((address_space(3))) void* las_t;

static __device__ __forceinline__ float bf2f(short s) {
  union { unsigned u; float f; } z; z.u = ((unsigned)(unsigned short)s) << 16; return z.f;
}
static __device__ __forceinline__ short f2bf(float f) {
  union { float f; unsigned u; } v; v.f = f;
  unsigned r = v.u + 0x7fffu + ((v.u >> 16) & 1u);
  return (short)(r >> 16);
}

// ---------- transpose x [B,C,N] f32 -> xt [B,N,C] f32 ----------
__global__ __launch_bounds__(TPB) void transpose_in(const float* __restrict__ x,
                                                    float* __restrict__ xt) {
  int b = blockIdx.z, c0 = blockIdx.y * 32, n0 = blockIdx.x * 32;
  __shared__ float t[32][33];
  int tid = threadIdx.x;
  int cl = tid >> 3, nl4 = (tid & 7) * 4;
  float4 v = *(const float4*)(x + ((size_t)(b * Cch + c0 + cl)) * Nsp + n0 + nl4);
  t[cl][nl4 + 0] = v.x; t[cl][nl4 + 1] = v.y; t[cl][nl4 + 2] = v.z; t[cl][nl4 + 3] = v.w;
  __syncthreads();
  int nl = tid >> 3, cl4 = (tid & 7) * 4;
  float4 o = make_float4(t[cl4 + 0][nl], t[cl4 + 1][nl], t[cl4 + 2][nl], t[cl4 + 3][nl]);
  *(float4*)(xt + ((size_t)(b * Nsp + n0 + nl)) * Cch + c0 + cl4) = o;
}

// ---------- transpose ffn-out [B,N,C] f32 -> out [B,C,N] f32 ----------
__global__ __launch_bounds__(TPB) void transpose_out(const float* __restrict__ f,
                                                     float* __restrict__ outp) {
  int b = blockIdx.z, n0 = blockIdx.y * 32, c0 = blockIdx.x * 32;
  __shared__ float t[32][33];
  int tid = threadIdx.x;
  int nl = tid >> 3, cl4 = (tid & 7) * 4;
  float4 v = *(const float4*)(f + ((size_t)(b * Nsp + n0 + nl)) * Cch + c0 + cl4);
  t[nl][cl4 + 0] = v.x; t[nl][cl4 + 1] = v.y; t[nl][cl4 + 2] = v.z; t[nl][cl4 + 3] = v.w;
  __syncthreads();
  int cl = tid >> 3, nl4 = (tid & 7) * 4;
  float4 o = make_float4(t[nl4 + 0][cl], t[nl4 + 1][cl], t[nl4 + 2][cl], t[nl4 + 3][cl]);
  *(float4*)(outp + ((size_t)(b * Cch + c0 + cl)) * Nsp + n0 + nl4) = o;
}

// ---------- weight f32 -> bf16 (7 segments, unit = float4) ----------
__global__ __launch_bounds__(TPB) void convert_w(const float* a0, const float* a1,
                                                 const float* a2, const float* a3,
                                                 const float* a4, const float* a5,
                                                 const float* a6, short* __restrict__ dst) {
  int u = blockIdx.x * TPB + threadIdx.x;
  const float* src; int base;
  if      (u < 196608) { src = a0; base = 0; }
  else if (u < 262144) { src = a1; base = 196608; }
  else if (u < 327680) { src = a2; base = 262144; }
  else if (u < 524288) { src = a3; base = 327680; }
  else if (u < 589824) { src = a4; base = 524288; }
  else if (u < 851968) { src = a5; base = 589824; }
  else                 { src = a6; base = 851968; }
  float4 v = *(const float4*)(src + (size_t)(u - base) * 4);
  short4 o = make_short4(f2bf(v.x), f2bf(v.y), f2bf(v.z), f2bf(v.w));
  *(short4*)(dst + (size_t)u * 4) = o;
}

// ---------- context f32 [B,77,768] -> bf16 padded [B*96,768] ----------
__global__ __launch_bounds__(TPB) void convert_ctx(const float* __restrict__ ctx,
                                                   short* __restrict__ dst) {
  int u = blockIdx.x * TPB + threadIdx.x;   // 73728 units
  int row = u / 192, c4 = u - row * 192;
  int b = row / 96, s_ = row - b * 96;
  short4 o;
  if (s_ < SEQ) {
    float4 v = *(const float4*)(ctx + ((size_t)(b * SEQ + s_)) * CTX + c4 * 4);
    o = make_short4(f2bf(v.x), f2bf(v.y), f2bf(v.z), f2bf(v.w));
  } else {
    o = make_short4(0, 0, 0, 0);
  }
  *(short4*)(dst + (size_t)row * CTX + c4 * 4) = o;
}

// ---------- GroupNorm token-major: f32 [4096,512] -> bf16 [4096,512] ----------
__global__ __launch_bounds__(TPB) void gn_tm(const float* __restrict__ x,
                                             const float* __restrict__ w,
                                             const float* __restrict__ bb,
                                             short* __restrict__ outp) {
  int b = blockIdx.x >> 3, g = blockIdx.x & 7;
  const float* p = x + (size_t)b * Nsp * Cch + g * 64;
  short* op = (short*)outp + (size_t)b * Nsp * Cch + g * 64;
  int tid = threadIdx.x;
  float s = 0.f, s2 = 0.f;
  for (int i = tid; i < Nsp * 16; i += TPB) {
    int n = i >> 4, c4 = i & 15;
    float4 v = *(const float4*)(p + (size_t)n * Cch + c4 * 4);
    s += v.x + v.y + v.z + v.w;
    s2 += v.x * v.x + v.y * v.y + v.z * v.z + v.w * v.w;
  }
  for (int off = 1; off < 64; off <<= 1) {
    s += __shfl_xor(s, off, 64);
    s2 += __shfl_xor(s2, off, 64);
  }
  __shared__ float red[2][4];
  __shared__ float mu_s, rstd_s;
  int wid = tid >> 6;
  if ((tid & 63) == 0) { red[0][wid] = s; red[1][wid] = s2; }
  __syncthreads();
  if (tid == 0) {
    float S = red[0][0] + red[0][1] + red[0][2] + red[0][3];
    float S2 = red[1][0] + red[1][1] + red[1][2] + red[1][3];
    const float inv = 1.f / (float)(64 * Nsp);
    float mu = S * inv;
    float var = S2 * inv - mu * mu;
    mu_s = mu; rstd_s = rsqrtf(var + EPSV);
  }
  __syncthreads();
  float mu = mu_s, rstd = rstd_s;
  for (int i = tid; i < Nsp * 16; i += TPB) {
    int n = i >> 4, c4 = i & 15;
    float4 v = *(const float4*)(p + (size_t)n * Cch + c4 * 4);
    int c = g * 64 + c4 * 4;
    float w0 = w[c] * rstd, w1 = w[c + 1] * rstd, w2 = w[c + 2] * rstd, w3 = w[c + 3] * rstd;
    short4 o = make_short4(f2bf((v.x - mu) * w0 + bb[c]),
                           f2bf((v.y - mu) * w1 + bb[c + 1]),
                           f2bf((v.z - mu) * w2 + bb[c + 2]),
                           f2bf((v.w - mu) * w3 + bb[c + 3]));
    *(short4*)(op + (size_t)n * Cch + c4 * 4) = o;
  }
}

// ---------- bf16 MFMA NT-GEMM: Out[m,o] = sum_k A[m,k] * W[o,k] + bias[o] ----------
// MODE 0: bf16 out; MODE 1: f32 out += resid; MODE 2: gelu -> bf16 out
// MODE 3: bf16 out for og<1024, transposed bf16 to tout (stride 4096) for og>=1024
// MODE 4: bf16 out for og<512,  transposed bf16 to tout (stride 384)  for og>=512
template<int MODE>
__global__ __launch_bounds__(TPB) void gemm_nt(const short* __restrict__ A,
                                               const short* __restrict__ Bw,
                                               const float* __restrict__ bias,
                                               const float* __restrict__ resid,
                                               void* __restrict__ outp,
                                               short* __restrict__ tout,
                                               int tstride,
                                               int M, int K, int O) {
  __shared__ __align__(16) short As[128 * 64];
  __shared__ __align__(16) short Bs[128 * 64];
  int tid = threadIdx.x;
  int lane = tid & 63, w = tid >> 6;
  int wr = w >> 1, wc = w & 1;
  int m0 = blockIdx.x * 128, o0 = blockIdx.y * 128;
  f32x4 acc[4][4];
#pragma unroll
  for (int i = 0; i < 4; ++i)
#pragma unroll
    for (int j = 0; j < 4; ++j) acc[i][j] = (f32x4){0.f, 0.f, 0.f, 0.f};
  int nk = K >> 6;
  for (int kt = 0; kt < nk; ++kt) {
    int k0 = kt << 6;
    __syncthreads();
#pragma unroll
    for (int i = 0; i < 4; ++i) {
      int c = i * 256 + tid;
      int r = c >> 3, qs = c & 7, qg = qs ^ (r & 7);
      const char* ga = (const char*)(A + ((size_t)(m0 + r) * K + k0)) + (qg << 4);
      __builtin_amdgcn_global_load_lds((gas_t)ga,
          (las_t)((char*)As + ((i * 256 + w * 64) << 4)), 16, 0, 0);
    }
#pragma unroll
    for (int i = 0; i < 4; ++i) {
      int c = i * 256 + tid;
      int r = c >> 3, qs = c & 7, qg = qs ^ (r & 7);
      const char* gb = (const char*)(Bw + ((size_t)(o0 + r) * K + k0)) + (qg << 4);
      __builtin_amdgcn_global_load_lds((gas_t)gb,
          (las_t)((char*)Bs + ((i * 256 + w * 64) << 4)), 16, 0, 0);
    }
    __syncthreads();
#pragma unroll
    for (int kk = 0; kk < 2; ++kk) {
      s8v a[4], bfr[4];
#pragma unroll
      for (int m = 0; m < 4; ++m) {
        int r = wr * 64 + m * 16 + (lane & 15);
        int q = (lane >> 4) + (kk << 2);
        a[m] = *(const s8v*)((const char*)As + r * 128 + ((q ^ (r & 7)) << 4));
      }
#pragma unroll
      for (int n = 0; n < 4; ++n) {
        int r = wc * 64 + n * 16 + (lane & 15);
        int q = (lane >> 4) + (kk << 2);
        bfr[n] = *(const s8v*)((const char*)Bs + r * 128 + ((q ^ (r & 7)) << 4));
      }
#pragma unroll
      for (int m = 0; m < 4; ++m)
#pragma unroll
        for (int n = 0; n < 4; ++n)
          acc[m][n] = __builtin_amdgcn_mfma_f32_16x16x32_bf16(a[m], bfr[n], acc[m][n], 0, 0, 0);
    }
  }
  float bv[4];
#pragma unroll
  for (int n = 0; n < 4; ++n) bv[n] = bias[o0 + wc * 64 + n * 16 + (lane & 15)];
  int row_b = m0 + wr * 64 + ((lane >> 4) << 2);
  int col_b = o0 + wc * 64 + (lane & 15);
  const int split = (MODE == 3) ? 1024 : 512;
  if ((MODE == 3 || MODE == 4) && o0 >= split) {
    // transposed write: tout[og - split][m]
#pragma unroll
    for (int m = 0; m < 4; ++m) {
#pragma unroll
      for (int n = 0; n < 4; ++n) {
        int og = col_b + n * 16;
        short4 s4 = make_short4(f2bf(acc[m][n][0] + bv[n]),
                                f2bf(acc[m][n][1] + bv[n]),
                                f2bf(acc[m][n][2] + bv[n]),
                                f2bf(acc[m][n][3] + bv[n]));
        *(short4*)(tout + (size_t)(og - split) * tstride + row_b + m * 16) = s4;
      }
    }
    return;
  }
#pragma unroll
  for (int m = 0; m < 4; ++m) {
#pragma unroll
    for (int i = 0; i < 4; ++i) {
      int mg = row_b + m * 16 + i;
#pragma unroll
      for (int n = 0; n < 4; ++n) {
        int og = col_b + n * 16;
        float v = acc[m][n][i] + bv[n];
        size_t idx = (size_t)mg * O + og;
        if (MODE == 1) {
          ((float*)outp)[idx] = v + resid[idx];
        } else if (MODE == 2) {
          float gv = 0.5f * v * (1.f + erff(v * 0.70710678118654752f));
          ((short*)outp)[idx] = f2bf(gv);
        } else {
          ((short*)outp)[idx] = f2bf(v);
        }
      }
    }
  }
}

// ---------- self-attention, MFMA flash ----------
// qkv bf16 [4096,1536] (q cols 0..511, k cols 512..1023); vt bf16 [512][4096]
// out bf16 [4096,512]
__global__ __launch_bounds__(TPB) void sa_attn_mfma(const short* __restrict__ qkv,
                                                    const short* __restrict__ vt,
                                                    short* __restrict__ outp) {
  __shared__ __align__(16) short Ks[64 * 64];
  __shared__ __align__(16) short Vs[64 * 64];      // V^T tile [d][k]
  __shared__ __align__(16) short Ps[4][16 * 64];   // per-wave P [q][key]
  int b = blockIdx.z, h = blockIdx.y, q0 = blockIdx.x * 64;
  int tid = threadIdx.x, lane = tid & 63, w = tid >> 6;
  int g = lane >> 4, qi = lane & 15;
  s8v qf[2];
  {
    const short* qp = qkv + (size_t)(b * 1024 + q0 + w * 16 + qi) * 1536 + h * 64 + g * 8;
    qf[0] = *(const s8v*)qp;
    qf[1] = *(const s8v*)(qp + 32);
  }
  f32x4 o[4];
#pragma unroll
  for (int d = 0; d < 4; ++d) o[d] = (f32x4){0.f, 0.f, 0.f, 0.f};
  float mrun = -1e30f, lrun = 0.f;
  const short* kbase = qkv + (size_t)(b * 1024) * 1536 + 512 + h * 64;
  const short* vbase = vt + (size_t)(h * 64) * 4096 + b * 1024;
  char* psw = (char*)Ps + w * 2048;
  int pswz = (qi & 7) << 4;
  for (int kt = 0; kt < 16; ++kt) {
    int k0 = kt * 64;
    __syncthreads();
#pragma unroll
    for (int i = 0; i < 2; ++i) {
      int c = i * 256 + tid;
      int r = c >> 3, cs = c & 7, cg = cs ^ (r & 7);
      const char* gp = (const char*)(kbase + (size_t)(k0 + r) * 1536) + (cg << 4);
      __builtin_amdgcn_global_load_lds((gas_t)gp, (las_t)((char*)Ks + (c << 4)), 16, 0, 0);
    }
#pragma unroll
    for (int i = 0; i < 2; ++i) {
      int c = i * 256 + tid;
      int r = c >> 3, cs = c & 7, cg = cs ^ (r & 7);
      const char* gp = (const char*)(vbase + (size_t)r * 4096 + k0) + (cg << 4);
      __builtin_amdgcn_global_load_lds((gas_t)gp, (las_t)((char*)Vs + (c << 4)), 16, 0, 0);
    }
    __syncthreads();
    // S^T[key][q] = K . Q^T
    f32x4 st[4];
#pragma unroll
    for (int t = 0; t < 4; ++t) st[t] = (f32x4){0.f, 0.f, 0.f, 0.f};
#pragma unroll
    for (int s = 0; s < 2; ++s) {
#pragma unroll
      for (int t = 0; t < 4; ++t) {
        int r = t * 16 + qi;
        s8v kf = *(const s8v*)((const char*)Ks + r * 128 + (((s * 4 + g) ^ (r & 7)) << 4));
        st[t] = __builtin_amdgcn_mfma_f32_16x16x32_bf16(kf, qf[s], st[t], 0, 0, 0);
      }
    }
    float sv[16];
#pragma unroll
    for (int t = 0; t < 4; ++t)
#pragma unroll
      for (int r2 = 0; r2 < 4; ++r2) sv[t * 4 + r2] = st[t][r2] * 0.125f;
    float mx = sv[0];
#pragma unroll
    for (int i = 1; i < 16; ++i) mx = fmaxf(mx, sv[i]);
    mx = fmaxf(mx, __shfl_xor(mx, 16));
    mx = fmaxf(mx, __shfl_xor(mx, 32));
    float mnew = fmaxf(mrun, mx);
    float psum = 0.f;
#pragma unroll
    for (int i = 0; i < 16; ++i) { sv[i] = __expf(sv[i] - mnew); psum += sv[i]; }
    psum += __shfl_xor(psum, 16);
    psum += __shfl_xor(psum, 32);
    float scale = __expf(mrun - mnew);
    lrun = lrun * scale + psum;
    mrun = mnew;
#pragma unroll
    for (int d = 0; d < 4; ++d) o[d] *= scale;
#pragma unroll
    for (int t = 0; t < 4; ++t) {
      short4 pk = make_short4(f2bf(sv[t * 4]), f2bf(sv[t * 4 + 1]),
                              f2bf(sv[t * 4 + 2]), f2bf(sv[t * 4 + 3]));
      *(short4*)(psw + qi * 128 + ((t * 32 + g * 8) ^ pswz)) = pk;
    }
#pragma unroll
    for (int s = 0; s < 2; ++s) {
      s8v bf = *(const s8v*)(psw + qi * 128 + ((s * 64 + g * 16) ^ pswz));
#pragma unroll
      for (int d = 0; d < 4; ++d) {
        int r = d * 16 + qi;
        s8v af = *(const s8v*)((const char*)Vs + r * 128 + (((s * 4 + g) ^ (r & 7)) << 4));
        o[d] = __builtin_amdgcn_mfma_f32_16x16x32_bf16(af, bf, o[d], 0, 0, 0);
      }
    }
  }
  float rl = 1.f / lrun;
  short* ob = outp + (size_t)(b * 1024 + q0 + w * 16 + qi) * 512 + h * 64;
#pragma unroll
  for (int d = 0; d < 4; ++d) {
    short4 s4 = make_short4(f2bf(o[d][0] * rl), f2bf(o[d][1] * rl),
                            f2bf(o[d][2] * rl), f2bf(o[d][3] * rl));
    *(short4*)(ob + d * 16 + g * 4) = s4;
  }
}

// ---------- cross-attention, MFMA single-pass ----------
// qb bf16 [4096,512]; kvb bf16 [384,1024] (K cols 0..511); cavt bf16 [512][384]
__global__ __launch_bounds__(TPB) void ca_attn_mfma(const short* __restrict__ qb,
                                                    const short* __restrict__ kvb,
                                                    const short* __restrict__ cavt,
                                                    short* __restrict__ outp) {
  __shared__ __align__(16) short Ks[96 * 64];       // 12KB
  __shared__ __align__(16) short Vs[64 * 128];      // 16KB [d][key-slot]
  __shared__ __align__(16) short Ps[4][16 * 128];   // 16KB
  int b = blockIdx.z, h = blockIdx.y, q0 = blockIdx.x * 64;
  int tid = threadIdx.x, lane = tid & 63, w = tid >> 6;
  int g = lane >> 4, qi = lane & 15;
  s8v qf[2];
  {
    const short* qp = qb + (size_t)(b * 1024 + q0 + w * 16 + qi) * 512 + h * 64 + g * 8;
    qf[0] = *(const s8v*)qp;
    qf[1] = *(const s8v*)(qp + 32);
  }
  // stage K (96 rows x 64 d)
  const short* kbase = kvb + (size_t)(b * 96) * 1024 + h * 64;
#pragma unroll
  for (int i = 0; i < 3; ++i) {
    int c = i * 256 + tid;
    int r = c >> 3, cs = c & 7, cg = cs ^ (r & 7);
    const char* gp = (const char*)(kbase + (size_t)r * 1024) + (cg << 4);
    __builtin_amdgcn_global_load_lds((gas_t)gp, (las_t)((char*)Ks + (c << 4)), 16, 0, 0);
  }
  // stage V^T (64 d rows x 96 keys), reg-staged into swizzled [64][128] rows
#pragma unroll
  for (int i = 0; i < 3; ++i) {
    int c = i * 256 + tid;
    int r = c / 12, jj = c - r * 12;
    int4 dv = *(const int4*)(cavt + (size_t)(h * 64 + r) * 384 + b * 96 + jj * 8);
    *(int4*)((char*)Vs + r * 256 + ((jj * 16) ^ ((r & 7) << 4))) = dv;
  }
  __syncthreads();
  // S^T = K . Q^T  (6 key tiles)
  f32x4 st[6];
#pragma unroll
  for (int t = 0; t < 6; ++t) st[t] = (f32x4){0.f, 0.f, 0.f, 0.f};
#pragma unroll
  for (int s = 0; s < 2; ++s) {
#pragma unroll
    for (int t = 0; t < 6; ++t) {
      int r = t * 16 + qi;
      s8v kf = *(const s8v*)((const char*)Ks + r * 128 + (((s * 4 + g) ^ (r & 7)) << 4));
      st[t] = __builtin_amdgcn_mfma_f32_16x16x32_bf16(kf, qf[s], st[t], 0, 0, 0);
    }
  }
  float sv[24];
#pragma unroll
  for (int t = 0; t < 6; ++t)
#pragma unroll
    for (int r2 = 0; r2 < 4; ++r2) {
      int key = t * 16 + g * 4 + r2;
      sv[t * 4 + r2] = (key < SEQ) ? st[t][r2] * 0.125f : -1e30f;
    }
  float mx = sv[0];
#pragma unroll
  for (int i = 1; i < 24; ++i) mx = fmaxf(mx, sv[i]);
  mx = fmaxf(mx, __shfl_xor(mx, 16));
  mx = fmaxf(mx, __shfl_xor(mx, 32));
  float l = 0.f;
#pragma unroll
  for (int i = 0; i < 24; ++i) { sv[i] = __expf(sv[i] - mx); l += sv[i]; }
  l += __shfl_xor(l, 16);
  l += __shfl_xor(l, 32);
  char* psw = (char*)Ps + w * 4096;
  int pswz = (qi & 7) << 4;
#pragma unroll
  for (int t = 0; t < 6; ++t) {
    short4 pk = make_short4(f2bf(sv[t * 4]), f2bf(sv[t * 4 + 1]),
                            f2bf(sv[t * 4 + 2]), f2bf(sv[t * 4 + 3]));
    *(short4*)(psw + qi * 256 + ((t * 32 + g * 8) ^ pswz)) = pk;
  }
  f32x4 o[4];
#pragma unroll
  for (int d = 0; d < 4; ++d) o[d] = (f32x4){0.f, 0.f, 0.f, 0.f};
#pragma unroll
  for (int s = 0; s < 3; ++s) {
    s8v bf = *(const s8v*)(psw + qi * 256 + ((s * 64 + g * 16) ^ pswz));
#pragma unroll
    for (int d = 0; d < 4; ++d) {
      int r = d * 16 + qi;
      s8v af = *(const s8v*)((const char*)Vs + r * 256 + (((s * 64 + g * 16) ^ ((r & 7) << 4))));
      o[d] = __builtin_amdgcn_mfma_f32_16x16x32_bf16(af, bf, o[d], 0, 0, 0);
    }
  }
  float rl = 1.f / l;
  short* ob = outp + (size_t)(b * 1024 + q0 + w * 16 + qi) * 512 + h * 64;
#pragma unroll
  for (int d = 0; d < 4; ++d) {
    short4 s4 = make_short4(f2bf(o[d][0] * rl), f2bf(o[d][1] * rl),
                            f2bf(o[d][2] * rl), f2bf(o[d][3] * rl));
    *(short4*)(ob + d * 16 + g * 4) = s4;
  }
}

extern "C" void kernel_launch(void* const* d_in, const int* in_sizes, int n_in,
                              void* d_out, int out_size, void* d_ws, size_t ws_size,
                              hipStream_t stream) {
  const float* x        = (const float*)d_in[0];
  const float* context  = (const float*)d_in[1];
  const float* sa_nw    = (const float*)d_in[2];
  const float* sa_nb    = (const float*)d_in[3];
  const float* sa_qkv_w = (const float*)d_in[4];
  const float* sa_qkv_b = (const float*)d_in[5];
  const float* sa_pw    = (const float*)d_in[6];
  const float* sa_pb    = (const float*)d_in[7];
  const float* ca_nw    = (const float*)d_in[8];
  const float* ca_nb    = (const float*)d_in[9];
  const float* ca_qw    = (const float*)d_in[10];
  const float* ca_qb    = (const float*)d_in[11];
  const float* ca_kvw   = (const float*)d_in[12];
  const float* ca_kvb   = (const float*)d_in[13];
  const float* ca_pw    = (const float*)d_in[14];
  const float* ca_pb    = (const float*)d_in[15];
  const float* ff_nw    = (const float*)d_in[16];
  const float* ff_nb    = (const float*)d_in[17];
  const float* ff_w1    = (const float*)d_in[18];
  const float* ff_b1    = (const float*)d_in[19];
  const float* ff_w2    = (const float*)d_in[20];
  const float* ff_b2    = (const float*)d_in[21];
  float* outp = (float*)d_out;

  char* ws = (char*)d_ws;
  float* xt    = (float*)(ws);                        // [0,8M)
  float* xcur  = (float*)(ws + (8u << 20));           // [8,16M)
  short* hb    = (short*)(ws + (16u << 20));          // [16,20M)
  short* qkvb  = (short*)(ws + (20u << 20));          // [20,32M)
  short* qb    = (short*)(ws + (20u << 20));
  short* h1    = (short*)(ws + (20u << 20));          // [20,36M)
  short* vt    = (short*)(ws + (32u << 20));          // [32,36M) V^T [512][4096]
  short* kvb   = (short*)(ws + (36u << 20));          // 768KB
  short* cavt  = (short*)(ws + (36u << 20) + (768u << 10));  // 384KB [512][384]
  short* ctxb  = (short*)(ws + (37u << 20) + (512u << 10));  // 576KB
  short* wb    = (short*)(ws + (38u << 20) + (512u << 10));  // bf16 weights

  short* w_qkv = wb;
  short* w_sap = wb + 786432;
  short* w_caq = wb + 1048576;
  short* w_kv  = wb + 1310720;
  short* w_cap = wb + 2097152;
  short* w_f1  = wb + 2359296;
  short* w_f2  = wb + 3407872;

  dim3 blk(TPB);
  transpose_in<<<dim3(32, 16, 4), blk, 0, stream>>>(x, xt);
  convert_w<<<4352, blk, 0, stream>>>(sa_qkv_w, sa_pw, ca_qw, ca_kvw, ca_pw, ff_w1, ff_w2, wb);
  convert_ctx<<<288, blk, 0, stream>>>(context, ctxb);

  // ---- self-attention ----
  gn_tm<<<32, blk, 0, stream>>>(xt, sa_nw, sa_nb, hb);
  gemm_nt<3><<<dim3(32, 12), blk, 0, stream>>>(hb, w_qkv, sa_qkv_b, nullptr, qkvb, vt, 4096, MTOK, 512, 1536);
  sa_attn_mfma<<<dim3(16, 8, 4), blk, 0, stream>>>(qkvb, vt, hb);
  gemm_nt<1><<<dim3(32, 4), blk, 0, stream>>>(hb, w_sap, sa_pb, xt, xcur, nullptr, 0, MTOK, 512, 512);

  // ---- cross-attention ----
  gn_tm<<<32, blk, 0, stream>>>(xcur, ca_nw, ca_nb, hb);
  gemm_nt<0><<<dim3(32, 4), blk, 0, stream>>>(hb, w_caq, ca_qb, nullptr, qb, nullptr, 0, MTOK, 512, 512);
  gemm_nt<4><<<dim3(3, 8), blk, 0, stream>>>(ctxb, w_kv, ca_kvb, nullptr, kvb, cavt, 384, 384, 768, 1024);
  ca_attn_mfma<<<dim3(16, 8, 4), blk, 0, stream>>>(qb, kvb, cavt, hb);
  gemm_nt<1><<<dim3(32, 4), blk, 0, stream>>>(hb, w_cap, ca_pb, xcur, xcur, nullptr, 0, MTOK, 512, 512);

  // ---- FFN ----
  gn_tm<<<32, blk, 0, stream>>>(xcur, ff_nw, ff_nb, hb);
  gemm_nt<2><<<dim3(32, 16), blk, 0, stream>>>(hb, w_f1, ff_b1, nullptr, h1, nullptr, 0, MTOK, 512, 2048);
  gemm_nt<1><<<dim3(32, 4), blk, 0, stream>>>(h1, w_f2, ff_b2, xcur, xt, nullptr, 0, MTOK, 2048, 512);
  transpose_out<<<dim3(16, 32, 4), blk, 0, stream>>>(xt, outp);
}

// Round 4
// 229.370 us; speedup vs baseline: 4.8433x; 1.2896x over previous
//
#include <hip/hip_runtime.h>

#define TPB 256
#define Bsz 4
#define Nsp 1024
#define Cch 512
#define SEQ 77
#define CTX 768
#define EPSV 1e-5f
#define MTOK 4096   // B * N

typedef __attribute__((ext_vector_type(8))) short s8v;
typedef __attribute__((ext_vector_type(4))) float f32x4;
typedef const __attribute__((address_space(1))) void* gas_t;
typedef __attribute__((address_space(3))) void* las_t;

static __device__ __forceinline__ float bf2f(short s) {
  union { unsigned u; float f; } z; z.u = ((unsigned)(unsigned short)s) << 16; return z.f;
}
static __device__ __forceinline__ short f2bf(float f) {
  union { float f; unsigned u; } v; v.f = f;
  unsigned r = v.u + 0x7fffu + ((v.u >> 16) & 1u);
  return (short)(r >> 16);
}

// ---------- weight f32 -> bf16 (7 segments, unit = float4) ----------
__global__ __launch_bounds__(TPB) void convert_w(const float* a0, const float* a1,
                                                 const float* a2, const float* a3,
                                                 const float* a4, const float* a5,
                                                 const float* a6, short* __restrict__ dst) {
  int u = blockIdx.x * TPB + threadIdx.x;
  const float* src; int base;
  if      (u < 196608) { src = a0; base = 0; }
  else if (u < 262144) { src = a1; base = 196608; }
  else if (u < 327680) { src = a2; base = 262144; }
  else if (u < 524288) { src = a3; base = 327680; }
  else if (u < 589824) { src = a4; base = 524288; }
  else if (u < 851968) { src = a5; base = 589824; }
  else                 { src = a6; base = 851968; }
  float4 v = *(const float4*)(src + (size_t)(u - base) * 4);
  short4 o = make_short4(f2bf(v.x), f2bf(v.y), f2bf(v.z), f2bf(v.w));
  *(short4*)(dst + (size_t)u * 4) = o;
}

// ---------- context f32 [B,77,768] -> bf16 padded [B*96,768] ----------
__global__ __launch_bounds__(TPB) void convert_ctx(const float* __restrict__ ctx,
                                                   short* __restrict__ dst) {
  int u = blockIdx.x * TPB + threadIdx.x;   // 73728 units
  int row = u / 192, c4 = u - row * 192;
  int b = row / 96, s_ = row - b * 96;
  short4 o;
  if (s_ < SEQ) {
    float4 v = *(const float4*)(ctx + ((size_t)(b * SEQ + s_)) * CTX + c4 * 4);
    o = make_short4(f2bf(v.x), f2bf(v.y), f2bf(v.z), f2bf(v.w));
  } else {
    o = make_short4(0, 0, 0, 0);
  }
  *(short4*)(dst + (size_t)row * CTX + c4 * 4) = o;
}

// ---------- GroupNorm stats: one block per (b,g), input [B,C,N] f32 ----------
__global__ __launch_bounds__(TPB) void gn_stats(const float* __restrict__ x,
                                                float2* __restrict__ stats) {
  int bg = blockIdx.x;
  const float* base = x + (size_t)bg * 65536;   // 64 ch * 1024 tok
  int tid = threadIdx.x;
  float s = 0.f, s2 = 0.f;
  for (int i = tid; i < 16384; i += TPB) {
    float4 v = ((const float4*)base)[i];
    s += v.x + v.y + v.z + v.w;
    s2 += v.x * v.x + v.y * v.y + v.z * v.z + v.w * v.w;
  }
  for (int off = 1; off < 64; off <<= 1) {
    s += __shfl_xor(s, off, 64);
    s2 += __shfl_xor(s2, off, 64);
  }
  __shared__ float red[2][4];
  int wid = tid >> 6;
  if ((tid & 63) == 0) { red[0][wid] = s; red[1][wid] = s2; }
  __syncthreads();
  if (tid == 0) {
    float S = red[0][0] + red[0][1] + red[0][2] + red[0][3];
    float S2 = red[1][0] + red[1][1] + red[1][2] + red[1][3];
    const float inv = 1.f / 65536.f;
    float mu = S * inv;
    float var = S2 * inv - mu * mu;
    stats[bg] = make_float2(mu, rsqrtf(var + EPSV));
  }
}

// ---------- GroupNorm apply + transpose: [B,C,N] f32 -> token-major bf16 [4096,512] ----------
// grid (16, 32): x = 64-token subtile, y = (b,g)
__global__ __launch_bounds__(TPB) void gn_apply(const float* __restrict__ x,
                                                const float* __restrict__ w,
                                                const float* __restrict__ bb,
                                                const float2* __restrict__ stats,
                                                short* __restrict__ outp) {
  int t = blockIdx.x, bg = blockIdx.y;
  int b = bg >> 3, g = bg & 7;
  float2 st = stats[bg];
  float mu = st.x, rstd = st.y;
  __shared__ float tile[64][65];
  int tid = threadIdx.x;
  int n0 = t * 64;
  const float* p = x + (size_t)bg * 65536;
#pragma unroll
  for (int it = 0; it < 4; ++it) {
    int idx = it * 256 + tid;
    int c = idx >> 4, n4 = (idx & 15) * 4;
    float4 v = *(const float4*)(p + (size_t)c * 1024 + n0 + n4);
    float wc = w[g * 64 + c] * rstd;
    float bc = bb[g * 64 + c] - mu * wc;
    tile[c][n4 + 0] = v.x * wc + bc;
    tile[c][n4 + 1] = v.y * wc + bc;
    tile[c][n4 + 2] = v.z * wc + bc;
    tile[c][n4 + 3] = v.w * wc + bc;
  }
  __syncthreads();
  int n = tid >> 2, cs = (tid & 3) * 16;
  short ob[16];
#pragma unroll
  for (int j = 0; j < 16; ++j) ob[j] = f2bf(tile[cs + j][n]);
  short* op = outp + (size_t)(b * 1024 + n0 + n) * 512 + g * 64 + cs;
  *(int4*)op = *(int4*)&ob[0];
  *(int4*)(op + 8) = *(int4*)&ob[8];
}

// ---------- bf16 MFMA NT-GEMM: Out[m,o] = sum_k A[m,k] * W[o,k] + bias[o] ----------
// MODE 0: bf16 token-major out [M,O]
// MODE 1: f32 channel-major out [B,O,1024] with channel-major f32 residual
// MODE 2: gelu -> bf16 token-major out
// MODE 3: og<1024 bf16 tm out; og>=1024 transposed bf16 to tout (stride 4096)
// MODE 4: og<512  bf16 tm out; og>=512  transposed bf16 to tout (stride 384)
template<int BM, int BN, int MODE>
__global__ __launch_bounds__(TPB) void gemm_nt(const short* __restrict__ A,
                                               const short* __restrict__ Bw,
                                               const float* __restrict__ bias,
                                               const float* __restrict__ resid,
                                               void* __restrict__ outp,
                                               short* __restrict__ tout,
                                               int tstride, int K, int O) {
  const int FM = BM / 32, FN = BN / 32;
  __shared__ __align__(16) short As[BM * 64];
  __shared__ __align__(16) short Bs[BN * 64];
  int tid = threadIdx.x;
  int lane = tid & 63, w = tid >> 6;
  int wr = w >> 1, wc = w & 1;
  int m0 = blockIdx.x * BM, o0 = blockIdx.y * BN;
  f32x4 acc[FM][FN];
#pragma unroll
  for (int i = 0; i < FM; ++i)
#pragma unroll
    for (int j = 0; j < FN; ++j) acc[i][j] = (f32x4){0.f, 0.f, 0.f, 0.f};
  int nk = K >> 6;
  for (int kt = 0; kt < nk; ++kt) {
    int k0 = kt << 6;
    __syncthreads();
#pragma unroll
    for (int i = 0; i < BM / 32; ++i) {
      int c = i * 256 + tid;
      int r = c >> 3, qs = c & 7, qg = qs ^ (r & 7);
      const char* ga = (const char*)(A + ((size_t)(m0 + r) * K + k0)) + (qg << 4);
      __builtin_amdgcn_global_load_lds((gas_t)ga, (las_t)((char*)As + (c << 4)), 16, 0, 0);
    }
#pragma unroll
    for (int i = 0; i < BN / 32; ++i) {
      int c = i * 256 + tid;
      int r = c >> 3, qs = c & 7, qg = qs ^ (r & 7);
      const char* gb = (const char*)(Bw + ((size_t)(o0 + r) * K + k0)) + (qg << 4);
      __builtin_amdgcn_global_load_lds((gas_t)gb, (las_t)((char*)Bs + (c << 4)), 16, 0, 0);
    }
    __syncthreads();
#pragma unroll
    for (int kk = 0; kk < 2; ++kk) {
      s8v a[FM], bfr[FN];
#pragma unroll
      for (int m = 0; m < FM; ++m) {
        int r = wr * (BM / 2) + m * 16 + (lane & 15);
        int q = (lane >> 4) + (kk << 2);
        a[m] = *(const s8v*)((const char*)As + r * 128 + ((q ^ (r & 7)) << 4));
      }
#pragma unroll
      for (int n = 0; n < FN; ++n) {
        int r = wc * (BN / 2) + n * 16 + (lane & 15);
        int q = (lane >> 4) + (kk << 2);
        bfr[n] = *(const s8v*)((const char*)Bs + r * 128 + ((q ^ (r & 7)) << 4));
      }
#pragma unroll
      for (int m = 0; m < FM; ++m)
#pragma unroll
        for (int n = 0; n < FN; ++n)
          acc[m][n] = __builtin_amdgcn_mfma_f32_16x16x32_bf16(a[m], bfr[n], acc[m][n], 0, 0, 0);
    }
  }
  float bv[FN];
#pragma unroll
  for (int n = 0; n < FN; ++n) bv[n] = bias[o0 + wc * (BN / 2) + n * 16 + (lane & 15)];
  int row_b = m0 + wr * (BM / 2) + ((lane >> 4) << 2);
  int col_b = o0 + wc * (BN / 2) + (lane & 15);
  const int split = (MODE == 3) ? 1024 : 512;
  if ((MODE == 3 || MODE == 4) && o0 >= split) {
#pragma unroll
    for (int m = 0; m < FM; ++m) {
#pragma unroll
      for (int n = 0; n < FN; ++n) {
        int og = col_b + n * 16;
        short4 s4 = make_short4(f2bf(acc[m][n][0] + bv[n]), f2bf(acc[m][n][1] + bv[n]),
                                f2bf(acc[m][n][2] + bv[n]), f2bf(acc[m][n][3] + bv[n]));
        *(short4*)(tout + (size_t)(og - split) * tstride + row_b + m * 16) = s4;
      }
    }
    return;
  }
  if (MODE == 1) {
    // channel-major f32 out + residual: out[(b*O+og)*1024 + n], float4 along token
#pragma unroll
    for (int m = 0; m < FM; ++m) {
      int t0 = row_b + m * 16;
      int b = t0 >> 10, n_ = t0 & 1023;
#pragma unroll
      for (int n = 0; n < FN; ++n) {
        int og = col_b + n * 16;
        size_t idx = ((size_t)(b * O + og)) * 1024 + n_;
        float4 rv = *(const float4*)(resid + idx);
        float4 ov;
        ov.x = acc[m][n][0] + bv[n] + rv.x;
        ov.y = acc[m][n][1] + bv[n] + rv.y;
        ov.z = acc[m][n][2] + bv[n] + rv.z;
        ov.w = acc[m][n][3] + bv[n] + rv.w;
        *(float4*)((float*)outp + idx) = ov;
      }
    }
    return;
  }
#pragma unroll
  for (int m = 0; m < FM; ++m) {
#pragma unroll
    for (int i = 0; i < 4; ++i) {
      int mg = row_b + m * 16 + i;
#pragma unroll
      for (int n = 0; n < FN; ++n) {
        int og = col_b + n * 16;
        float v = acc[m][n][i] + bv[n];
        size_t idx = (size_t)mg * O + og;
        if (MODE == 2) {
          float gv = 0.5f * v * (1.f + erff(v * 0.70710678118654752f));
          ((short*)outp)[idx] = f2bf(gv);
        } else {
          ((short*)outp)[idx] = f2bf(v);
        }
      }
    }
  }
}

// ---------- self-attention, MFMA flash, 2-phase double-buffered ----------
__global__ __launch_bounds__(TPB) void sa_attn_mfma(const short* __restrict__ qkv,
                                                    const short* __restrict__ vt,
                                                    short* __restrict__ outp) {
  __shared__ __align__(16) short Ks[2][64 * 64];
  __shared__ __align__(16) short Vs[2][64 * 64];
  __shared__ __align__(16) short Ps[4][16 * 64];
  int b = blockIdx.z, h = blockIdx.y, q0 = blockIdx.x * 64;
  int tid = threadIdx.x, lane = tid & 63, w = tid >> 6;
  int g = lane >> 4, qi = lane & 15;
  s8v qf[2];
  {
    const short* qp = qkv + (size_t)(b * 1024 + q0 + w * 16 + qi) * 1536 + h * 64 + g * 8;
    qf[0] = *(const s8v*)qp;
    qf[1] = *(const s8v*)(qp + 32);
  }
  f32x4 o[4];
#pragma unroll
  for (int d = 0; d < 4; ++d) o[d] = (f32x4){0.f, 0.f, 0.f, 0.f};
  float mrun = -1e30f, lrun = 0.f;
  const short* kbase = qkv + (size_t)(b * 1024) * 1536 + 512 + h * 64;
  const short* vbase = vt + (size_t)(h * 64) * 4096 + b * 1024;
  char* psw = (char*)Ps + w * 2048;
  int pswz = (qi & 7) << 4;

  auto stage = [&](int bufi, int kt) {
    int k0 = kt * 64;
#pragma unroll
    for (int i = 0; i < 2; ++i) {
      int c = i * 256 + tid;
      int r = c >> 3, cs = c & 7, cg = cs ^ (r & 7);
      const char* gp = (const char*)(kbase + (size_t)(k0 + r) * 1536) + (cg << 4);
      __builtin_amdgcn_global_load_lds((gas_t)gp, (las_t)((char*)Ks[bufi] + (c << 4)), 16, 0, 0);
    }
#pragma unroll
    for (int i = 0; i < 2; ++i) {
      int c = i * 256 + tid;
      int r = c >> 3, cs = c & 7, cg = cs ^ (r & 7);
      const char* gp = (const char*)(vbase + (size_t)r * 4096 + k0) + (cg << 4);
      __builtin_amdgcn_global_load_lds((gas_t)gp, (las_t)((char*)Vs[bufi] + (c << 4)), 16, 0, 0);
    }
  };

  stage(0, 0);
  __syncthreads();
  for (int kt = 0; kt < 16; ++kt) {
    int cur = kt & 1;
    if (kt < 15) stage(cur ^ 1, kt + 1);
    // S^T[key][q] = K . Q^T
    f32x4 st[4];
#pragma unroll
    for (int t = 0; t < 4; ++t) st[t] = (f32x4){0.f, 0.f, 0.f, 0.f};
#pragma unroll
    for (int s = 0; s < 2; ++s) {
#pragma unroll
      for (int t = 0; t < 4; ++t) {
        int r = t * 16 + qi;
        s8v kf = *(const s8v*)((const char*)Ks[cur] + r * 128 + (((s * 4 + g) ^ (r & 7)) << 4));
        st[t] = __builtin_amdgcn_mfma_f32_16x16x32_bf16(kf, qf[s], st[t], 0, 0, 0);
      }
    }
    float sv[16];
#pragma unroll
    for (int t = 0; t < 4; ++t)
#pragma unroll
      for (int r2 = 0; r2 < 4; ++r2) sv[t * 4 + r2] = st[t][r2] * 0.125f;
    float mx = sv[0];
#pragma unroll
    for (int i = 1; i < 16; ++i) mx = fmaxf(mx, sv[i]);
    mx = fmaxf(mx, __shfl_xor(mx, 16));
    mx = fmaxf(mx, __shfl_xor(mx, 32));
    float mnew = fmaxf(mrun, mx);
    float psum = 0.f;
#pragma unroll
    for (int i = 0; i < 16; ++i) { sv[i] = __expf(sv[i] - mnew); psum += sv[i]; }
    psum += __shfl_xor(psum, 16);
    psum += __shfl_xor(psum, 32);
    float scale = __expf(mrun - mnew);
    lrun = lrun * scale + psum;
    mrun = mnew;
#pragma unroll
    for (int d = 0; d < 4; ++d) o[d] *= scale;
#pragma unroll
    for (int t = 0; t < 4; ++t) {
      short4 pk = make_short4(f2bf(sv[t * 4]), f2bf(sv[t * 4 + 1]),
                              f2bf(sv[t * 4 + 2]), f2bf(sv[t * 4 + 3]));
      *(short4*)(psw + qi * 128 + ((t * 32 + g * 8) ^ pswz)) = pk;
    }
#pragma unroll
    for (int s = 0; s < 2; ++s) {
      s8v bf = *(const s8v*)(psw + qi * 128 + ((s * 64 + g * 16) ^ pswz));
#pragma unroll
      for (int d = 0; d < 4; ++d) {
        int r = d * 16 + qi;
        s8v af = *(const s8v*)((const char*)Vs[cur] + r * 128 + (((s * 4 + g) ^ (r & 7)) << 4));
        o[d] = __builtin_amdgcn_mfma_f32_16x16x32_bf16(af, bf, o[d], 0, 0, 0);
      }
    }
    __syncthreads();
  }
  float rl = 1.f / lrun;
  short* ob = outp + (size_t)(b * 1024 + q0 + w * 16 + qi) * 512 + h * 64;
#pragma unroll
  for (int d = 0; d < 4; ++d) {
    short4 s4 = make_short4(f2bf(o[d][0] * rl), f2bf(o[d][1] * rl),
                            f2bf(o[d][2] * rl), f2bf(o[d][3] * rl));
    *(short4*)(ob + d * 16 + g * 4) = s4;
  }
}

// ---------- cross-attention, MFMA single-pass ----------
__global__ __launch_bounds__(TPB) void ca_attn_mfma(const short* __restrict__ qb,
                                                    const short* __restrict__ kvb,
                                                    const short* __restrict__ cavt,
                                                    short* __restrict__ outp) {
  __shared__ __align__(16) short Ks[96 * 64];
  __shared__ __align__(16) short Vs[64 * 128];
  __shared__ __align__(16) short Ps[4][16 * 128];
  int b = blockIdx.z, h = blockIdx.y, q0 = blockIdx.x * 64;
  int tid = threadIdx.x, lane = tid & 63, w = tid >> 6;
  int g = lane >> 4, qi = lane & 15;
  s8v qf[2];
  {
    const short* qp = qb + (size_t)(b * 1024 + q0 + w * 16 + qi) * 512 + h * 64 + g * 8;
    qf[0] = *(const s8v*)qp;
    qf[1] = *(const s8v*)(qp + 32);
  }
  const short* kbase = kvb + (size_t)(b * 96) * 1024 + h * 64;
#pragma unroll
  for (int i = 0; i < 3; ++i) {
    int c = i * 256 + tid;
    int r = c >> 3, cs = c & 7, cg = cs ^ (r & 7);
    const char* gp = (const char*)(kbase + (size_t)r * 1024) + (cg << 4);
    __builtin_amdgcn_global_load_lds((gas_t)gp, (las_t)((char*)Ks + (c << 4)), 16, 0, 0);
  }
#pragma unroll
  for (int i = 0; i < 3; ++i) {
    int c = i * 256 + tid;
    int r = c / 12, jj = c - r * 12;
    int4 dv = *(const int4*)(cavt + (size_t)(h * 64 + r) * 384 + b * 96 + jj * 8);
    *(int4*)((char*)Vs + r * 256 + ((jj * 16) ^ ((r & 7) << 4))) = dv;
  }
  __syncthreads();
  f32x4 st[6];
#pragma unroll
  for (int t = 0; t < 6; ++t) st[t] = (f32x4){0.f, 0.f, 0.f, 0.f};
#pragma unroll
  for (int s = 0; s < 2; ++s) {
#pragma unroll
    for (int t = 0; t < 6; ++t) {
      int r = t * 16 + qi;
      s8v kf = *(const s8v*)((const char*)Ks + r * 128 + (((s * 4 + g) ^ (r & 7)) << 4));
      st[t] = __builtin_amdgcn_mfma_f32_16x16x32_bf16(kf, qf[s], st[t], 0, 0, 0);
    }
  }
  float sv[24];
#pragma unroll
  for (int t = 0; t < 6; ++t)
#pragma unroll
    for (int r2 = 0; r2 < 4; ++r2) {
      int key = t * 16 + g * 4 + r2;
      sv[t * 4 + r2] = (key < SEQ) ? st[t][r2] * 0.125f : -1e30f;
    }
  float mx = sv[0];
#pragma unroll
  for (int i = 1; i < 24; ++i) mx = fmaxf(mx, sv[i]);
  mx = fmaxf(mx, __shfl_xor(mx, 16));
  mx = fmaxf(mx, __shfl_xor(mx, 32));
  float l = 0.f;
#pragma unroll
  for (int i = 0; i < 24; ++i) { sv[i] = __expf(sv[i] - mx); l += sv[i]; }
  l += __shfl_xor(l, 16);
  l += __shfl_xor(l, 32);
  char* psw = (char*)Ps + w * 4096;
  int pswz = (qi & 7) << 4;
#pragma unroll
  for (int t = 0; t < 6; ++t) {
    short4 pk = make_short4(f2bf(sv[t * 4]), f2bf(sv[t * 4 + 1]),
                            f2bf(sv[t * 4 + 2]), f2bf(sv[t * 4 + 3]));
    *(short4*)(psw + qi * 256 + ((t * 32 + g * 8) ^ pswz)) = pk;
  }
  f32x4 o[4];
#pragma unroll
  for (int d = 0; d < 4; ++d) o[d] = (f32x4){0.f, 0.f, 0.f, 0.f};
#pragma unroll
  for (int s = 0; s < 3; ++s) {
    s8v bf = *(const s8v*)(psw + qi * 256 + ((s * 64 + g * 16) ^ pswz));
#pragma unroll
    for (int d = 0; d < 4; ++d) {
      int r = d * 16 + qi;
      s8v af = *(const s8v*)((const char*)Vs + r * 256 + (((s * 64 + g * 16) ^ ((r & 7) << 4))));
      o[d] = __builtin_amdgcn_mfma_f32_16x16x32_bf16(af, bf, o[d], 0, 0, 0);
    }
  }
  float rl = 1.f / l;
  short* ob = outp + (size_t)(b * 1024 + q0 + w * 16 + qi) * 512 + h * 64;
#pragma unroll
  for (int d = 0; d < 4; ++d) {
    short4 s4 = make_short4(f2bf(o[d][0] * rl), f2bf(o[d][1] * rl),
                            f2bf(o[d][2] * rl), f2bf(o[d][3] * rl));
    *(short4*)(ob + d * 16 + g * 4) = s4;
  }
}

extern "C" void kernel_launch(void* const* d_in, const int* in_sizes, int n_in,
                              void* d_out, int out_size, void* d_ws, size_t ws_size,
                              hipStream_t stream) {
  const float* x        = (const float*)d_in[0];
  const float* context  = (const float*)d_in[1];
  const float* sa_nw    = (const float*)d_in[2];
  const float* sa_nb    = (const float*)d_in[3];
  const float* sa_qkv_w = (const float*)d_in[4];
  const float* sa_qkv_b = (const float*)d_in[5];
  const float* sa_pw    = (const float*)d_in[6];
  const float* sa_pb    = (const float*)d_in[7];
  const float* ca_nw    = (const float*)d_in[8];
  const float* ca_nb    = (const float*)d_in[9];
  const float* ca_qw    = (const float*)d_in[10];
  const float* ca_qb    = (const float*)d_in[11];
  const float* ca_kvw   = (const float*)d_in[12];
  const float* ca_kvb   = (const float*)d_in[13];
  const float* ca_pw    = (const float*)d_in[14];
  const float* ca_pb    = (const float*)d_in[15];
  const float* ff_nw    = (const float*)d_in[16];
  const float* ff_nb    = (const float*)d_in[17];
  const float* ff_w1    = (const float*)d_in[18];
  const float* ff_b1    = (const float*)d_in[19];
  const float* ff_w2    = (const float*)d_in[20];
  const float* ff_b2    = (const float*)d_in[21];
  float* outp = (float*)d_out;

  char* ws = (char*)d_ws;
  float*  xcur  = (float*)(ws);                          // [0,8M)  residual stream (cm f32)
  short*  hb    = (short*)(ws + (8u << 20));             // [8,12M) GN out / attn out (bf16 tm)
  short*  big   = (short*)(ws + (12u << 20));            // [12,28M) qkvb / qb / h1
  short*  qkvb  = big;
  short*  qb    = big;
  short*  h1    = big;
  short*  vt    = (short*)(ws + (28u << 20));            // [28,32M) V^T [512][4096]
  short*  kvb   = (short*)(ws + (32u << 20));            // 768KB
  short*  cavt  = (short*)(ws + (33u << 20));            // 384KB [512][384]
  short*  ctxb  = (short*)(ws + (34u << 20));            // 576KB
  float2* stats = (float2*)(ws + (35u << 20));           // 3 x 32 float2
  short*  wb    = (short*)(ws + (36u << 20));            // bf16 weights (~8.7MB)

  short* w_qkv = wb;
  short* w_sap = wb + 786432;
  short* w_caq = wb + 1048576;
  short* w_kv  = wb + 1310720;
  short* w_cap = wb + 2097152;
  short* w_f1  = wb + 2359296;
  short* w_f2  = wb + 3407872;

  dim3 blk(TPB);
  convert_w<<<4352, blk, 0, stream>>>(sa_qkv_w, sa_pw, ca_qw, ca_kvw, ca_pw, ff_w1, ff_w2, wb);
  convert_ctx<<<288, blk, 0, stream>>>(context, ctxb);

  // ---- self-attention ----
  gn_stats<<<32, blk, 0, stream>>>(x, stats);
  gn_apply<<<dim3(16, 32), blk, 0, stream>>>(x, sa_nw, sa_nb, stats, hb);
  gemm_nt<128, 128, 3><<<dim3(32, 12), blk, 0, stream>>>(hb, w_qkv, sa_qkv_b, nullptr, qkvb, vt, 4096, 512, 1536);
  sa_attn_mfma<<<dim3(16, 8, 4), blk, 0, stream>>>(qkvb, vt, hb);
  gemm_nt<128, 64, 1><<<dim3(32, 8), blk, 0, stream>>>(hb, w_sap, sa_pb, x, xcur, nullptr, 0, 512, 512);

  // ---- cross-attention ----
  gn_stats<<<32, blk, 0, stream>>>(xcur, stats + 32);
  gn_apply<<<dim3(16, 32), blk, 0, stream>>>(xcur, ca_nw, ca_nb, stats + 32, hb);
  gemm_nt<128, 64, 0><<<dim3(32, 8), blk, 0, stream>>>(hb, w_caq, ca_qb, nullptr, qb, nullptr, 0, 512, 512);
  gemm_nt<64, 64, 4><<<dim3(6, 16), blk, 0, stream>>>(ctxb, w_kv, ca_kvb, nullptr, kvb, cavt, 384, 768, 1024);
  ca_attn_mfma<<<dim3(16, 8, 4), blk, 0, stream>>>(qb, kvb, cavt, hb);
  gemm_nt<128, 64, 1><<<dim3(32, 8), blk, 0, stream>>>(hb, w_cap, ca_pb, xcur, xcur, nullptr, 0, 512, 512);

  // ---- FFN ----
  gn_stats<<<32, blk, 0, stream>>>(xcur, stats + 64);
  gn_apply<<<dim3(16, 32), blk, 0, stream>>>(xcur, ff_nw, ff_nb, stats + 64, hb);
  gemm_nt<128, 128, 2><<<dim3(32, 16), blk, 0, stream>>>(hb, w_f1, ff_b1, nullptr, h1, nullptr, 0, 512, 2048);
  gemm_nt<128, 64, 1><<<dim3(32, 8), blk, 0, stream>>>(h1, w_f2, ff_b2, xcur, outp, nullptr, 0, 2048, 512);
}

// Round 5
// 186.914 us; speedup vs baseline: 5.9434x; 1.2271x over previous
//
#include <hip/hip_runtime.h>

#define TPB 256
#define Bsz 4
#define Nsp 1024
#define Cch 512
#define SEQ 77
#define CTX 768
#define EPSV 1e-5f
#define MTOK 4096   // B * N

typedef __attribute__((ext_vector_type(8))) short s8v;
typedef __attribute__((ext_vector_type(4))) float f32x4;
typedef const __attribute__((address_space(1))) void* gas_t;
typedef __attribute__((address_space(3))) void* las_t;

static __device__ __forceinline__ float bf2f(short s) {
  union { unsigned u; float f; } z; z.u = ((unsigned)(unsigned short)s) << 16; return z.f;
}
static __device__ __forceinline__ short f2bf(float f) {
  union { float f; unsigned u; } v; v.f = f;
  unsigned r = v.u + 0x7fffu + ((v.u >> 16) & 1u);
  return (short)(r >> 16);
}

// ---------- prep: weight/ctx convert + SA gn_stats + stats zero ----------
// blocks [0,4352): weights; [4352,4640): ctx; [4640,4672): gn_stats(x)
__global__ __launch_bounds__(TPB) void prep(const float* a0, const float* a1,
                                            const float* a2, const float* a3,
                                            const float* a4, const float* a5,
                                            const float* a6, short* __restrict__ wdst,
                                            const float* __restrict__ ctx,
                                            short* __restrict__ cdst,
                                            const float* __restrict__ x,
                                            float2* __restrict__ stats) {
  int blk = blockIdx.x;
  int tid = threadIdx.x;
  if (blk < 4352) {
    int u = blk * TPB + tid;
    const float* src; int base;
    if      (u < 196608) { src = a0; base = 0; }
    else if (u < 262144) { src = a1; base = 196608; }
    else if (u < 327680) { src = a2; base = 262144; }
    else if (u < 524288) { src = a3; base = 327680; }
    else if (u < 589824) { src = a4; base = 524288; }
    else if (u < 851968) { src = a5; base = 589824; }
    else                 { src = a6; base = 851968; }
    float4 v = *(const float4*)(src + (size_t)(u - base) * 4);
    short4 o = make_short4(f2bf(v.x), f2bf(v.y), f2bf(v.z), f2bf(v.w));
    *(short4*)(wdst + (size_t)u * 4) = o;
    return;
  }
  if (blk < 4640) {
    int u = (blk - 4352) * TPB + tid;
    int row = u / 192, c4 = u - row * 192;
    int b = row / 96, s_ = row - b * 96;
    short4 o;
    if (s_ < SEQ) {
      float4 v = *(const float4*)(ctx + ((size_t)(b * SEQ + s_)) * CTX + c4 * 4);
      o = make_short4(f2bf(v.x), f2bf(v.y), f2bf(v.z), f2bf(v.w));
    } else {
      o = make_short4(0, 0, 0, 0);
    }
    *(short4*)(cdst + (size_t)row * CTX + c4 * 4) = o;
    return;
  }
  // gn_stats for SA (raw sums) + zero CA/FFN stats
  int bg = blk - 4640;
  const float* base = x + (size_t)bg * 65536;
  float s = 0.f, s2 = 0.f;
  for (int i = tid; i < 16384; i += TPB) {
    float4 v = ((const float4*)base)[i];
    s += v.x + v.y + v.z + v.w;
    s2 += v.x * v.x + v.y * v.y + v.z * v.z + v.w * v.w;
  }
  for (int off = 1; off < 64; off <<= 1) {
    s += __shfl_xor(s, off, 64);
    s2 += __shfl_xor(s2, off, 64);
  }
  __shared__ float red[2][4];
  int wid = tid >> 6;
  if ((tid & 63) == 0) { red[0][wid] = s; red[1][wid] = s2; }
  __syncthreads();
  if (tid == 0) {
    float S = red[0][0] + red[0][1] + red[0][2] + red[0][3];
    float S2 = red[1][0] + red[1][1] + red[1][2] + red[1][3];
    stats[bg] = make_float2(S, S2);
  } else if (tid == 1) {
    stats[32 + bg] = make_float2(0.f, 0.f);
  } else if (tid == 2) {
    stats[64 + bg] = make_float2(0.f, 0.f);
  }
}

// ---------- GroupNorm apply + transpose: [B,C,N] f32 -> token-major bf16 [4096,512] ----------
// stats holds RAW (S, S2) per (b,g)
__global__ __launch_bounds__(TPB) void gn_apply(const float* __restrict__ x,
                                                const float* __restrict__ w,
                                                const float* __restrict__ bb,
                                                const float2* __restrict__ stats,
                                                short* __restrict__ outp) {
  int t = blockIdx.x, bg = blockIdx.y;
  int b = bg >> 3, g = bg & 7;
  float2 st = stats[bg];
  const float inv = 1.f / 65536.f;
  float mu = st.x * inv;
  float var = st.y * inv - mu * mu;
  float rstd = rsqrtf(var + EPSV);
  __shared__ float tile[64][65];
  int tid = threadIdx.x;
  int n0 = t * 64;
  const float* p = x + (size_t)bg * 65536;
#pragma unroll
  for (int it = 0; it < 4; ++it) {
    int idx = it * 256 + tid;
    int c = idx >> 4, n4 = (idx & 15) * 4;
    float4 v = *(const float4*)(p + (size_t)c * 1024 + n0 + n4);
    float wc = w[g * 64 + c] * rstd;
    float bc = bb[g * 64 + c] - mu * wc;
    tile[c][n4 + 0] = v.x * wc + bc;
    tile[c][n4 + 1] = v.y * wc + bc;
    tile[c][n4 + 2] = v.z * wc + bc;
    tile[c][n4 + 3] = v.w * wc + bc;
  }
  __syncthreads();
  int n = tid >> 2, cs = (tid & 3) * 16;
  short ob[16];
#pragma unroll
  for (int j = 0; j < 16; ++j) ob[j] = f2bf(tile[cs + j][n]);
  short* op = outp + (size_t)(b * 1024 + n0 + n) * 512 + g * 64 + cs;
  *(int4*)op = *(int4*)&ob[0];
  *(int4*)(op + 8) = *(int4*)&ob[8];
}

// ---------- bf16 MFMA NT-GEMM: Out[m,o] = sum_k A[m,k] * W[o,k] + bias[o] ----------
// MODE 0: bf16 tm out, scaled by oscale
// MODE 1: f32 channel-major out [B,O,1024] + cm f32 residual; optional stats accumulation
// MODE 2: gelu -> bf16 tm out
// MODE 3: og<1024 bf16 tm out (og<512 scaled 0.125); og>=1024 transposed to tout (stride 4096)
// MODE 4: og<512  bf16 tm out; og>=512  transposed to tout (stride 384)
template<int BM, int BN, int MODE>
__global__ __launch_bounds__(TPB) void gemm_nt(const short* __restrict__ A,
                                               const short* __restrict__ Bw,
                                               const float* __restrict__ bias,
                                               const float* __restrict__ resid,
                                               void* __restrict__ outp,
                                               short* __restrict__ tout,
                                               int tstride, int K, int O,
                                               float oscale,
                                               float2* __restrict__ stats_out) {
  const int FM = BM / 32, FN = BN / 32;
  __shared__ __align__(16) short As[BM * 64];
  __shared__ __align__(16) short Bs[BN * 64];
  int tid = threadIdx.x;
  int lane = tid & 63, w = tid >> 6;
  int wr = w >> 1, wc = w & 1;
  int m0 = blockIdx.x * BM, o0 = blockIdx.y * BN;
  f32x4 acc[FM][FN];
#pragma unroll
  for (int i = 0; i < FM; ++i)
#pragma unroll
    for (int j = 0; j < FN; ++j) acc[i][j] = (f32x4){0.f, 0.f, 0.f, 0.f};
  int nk = K >> 6;
  for (int kt = 0; kt < nk; ++kt) {
    int k0 = kt << 6;
    __syncthreads();
#pragma unroll
    for (int i = 0; i < BM / 32; ++i) {
      int c = i * 256 + tid;
      int r = c >> 3, qs = c & 7, qg = qs ^ (r & 7);
      const char* ga = (const char*)(A + ((size_t)(m0 + r) * K + k0)) + (qg << 4);
      __builtin_amdgcn_global_load_lds((gas_t)ga, (las_t)((char*)As + (c << 4)), 16, 0, 0);
    }
#pragma unroll
    for (int i = 0; i < BN / 32; ++i) {
      int c = i * 256 + tid;
      int r = c >> 3, qs = c & 7, qg = qs ^ (r & 7);
      const char* gb = (const char*)(Bw + ((size_t)(o0 + r) * K + k0)) + (qg << 4);
      __builtin_amdgcn_global_load_lds((gas_t)gb, (las_t)((char*)Bs + (c << 4)), 16, 0, 0);
    }
    __syncthreads();
#pragma unroll
    for (int kk = 0; kk < 2; ++kk) {
      s8v a[FM], bfr[FN];
#pragma unroll
      for (int m = 0; m < FM; ++m) {
        int r = wr * (BM / 2) + m * 16 + (lane & 15);
        int q = (lane >> 4) + (kk << 2);
        a[m] = *(const s8v*)((const char*)As + r * 128 + ((q ^ (r & 7)) << 4));
      }
#pragma unroll
      for (int n = 0; n < FN; ++n) {
        int r = wc * (BN / 2) + n * 16 + (lane & 15);
        int q = (lane >> 4) + (kk << 2);
        bfr[n] = *(const s8v*)((const char*)Bs + r * 128 + ((q ^ (r & 7)) << 4));
      }
#pragma unroll
      for (int m = 0; m < FM; ++m)
#pragma unroll
        for (int n = 0; n < FN; ++n)
          acc[m][n] = __builtin_amdgcn_mfma_f32_16x16x32_bf16(a[m], bfr[n], acc[m][n], 0, 0, 0);
    }
  }
  float bv[FN];
#pragma unroll
  for (int n = 0; n < FN; ++n) bv[n] = bias[o0 + wc * (BN / 2) + n * 16 + (lane & 15)];
  int row_b = m0 + wr * (BM / 2) + ((lane >> 4) << 2);
  int col_b = o0 + wc * (BN / 2) + (lane & 15);
  const int split = (MODE == 3) ? 1024 : 512;
  if ((MODE == 3 || MODE == 4) && o0 >= split) {
#pragma unroll
    for (int m = 0; m < FM; ++m) {
#pragma unroll
      for (int n = 0; n < FN; ++n) {
        int og = col_b + n * 16;
        short4 s4 = make_short4(f2bf(acc[m][n][0] + bv[n]), f2bf(acc[m][n][1] + bv[n]),
                                f2bf(acc[m][n][2] + bv[n]), f2bf(acc[m][n][3] + bv[n]));
        *(short4*)(tout + (size_t)(og - split) * tstride + row_b + m * 16) = s4;
      }
    }
    return;
  }
  if (MODE == 1) {
    float ls = 0.f, ls2 = 0.f;
#pragma unroll
    for (int m = 0; m < FM; ++m) {
      int t0 = row_b + m * 16;
      int b = t0 >> 10, n_ = t0 & 1023;
#pragma unroll
      for (int n = 0; n < FN; ++n) {
        int og = col_b + n * 16;
        size_t idx = ((size_t)(b * O + og)) * 1024 + n_;
        float4 rv = *(const float4*)(resid + idx);
        float4 ov;
        ov.x = acc[m][n][0] + bv[n] + rv.x;
        ov.y = acc[m][n][1] + bv[n] + rv.y;
        ov.z = acc[m][n][2] + bv[n] + rv.z;
        ov.w = acc[m][n][3] + bv[n] + rv.w;
        *(float4*)((float*)outp + idx) = ov;
        ls += ov.x + ov.y + ov.z + ov.w;
        ls2 += ov.x * ov.x + ov.y * ov.y + ov.z * ov.z + ov.w * ov.w;
      }
    }
    if (stats_out != nullptr) {
      float s = ls, s2 = ls2;
      for (int off = 1; off < 64; off <<= 1) {
        s += __shfl_xor(s, off, 64);
        s2 += __shfl_xor(s2, off, 64);
      }
      __syncthreads();
      float* red = (float*)As;
      if (lane == 0) { red[w * 2] = s; red[w * 2 + 1] = s2; }
      __syncthreads();
      if (tid == 0) {
        float S = red[0] + red[2] + red[4] + red[6];
        float S2 = red[1] + red[3] + red[5] + red[7];
        int bg = (m0 >> 10) * 8 + (o0 >> 6);
        atomicAdd((float*)stats_out + bg * 2, S);
        atomicAdd((float*)stats_out + bg * 2 + 1, S2);
      }
    }
    return;
  }
#pragma unroll
  for (int m = 0; m < FM; ++m) {
#pragma unroll
    for (int i = 0; i < 4; ++i) {
      int mg = row_b + m * 16 + i;
#pragma unroll
      for (int n = 0; n < FN; ++n) {
        int og = col_b + n * 16;
        float v = acc[m][n][i] + bv[n];
        size_t idx = (size_t)mg * O + og;
        if (MODE == 2) {
          float gv = 0.5f * v * (1.f + erff(v * 0.70710678118654752f));
          ((short*)outp)[idx] = f2bf(gv);
        } else if (MODE == 3) {
          if (og < 512) v *= 0.125f;
          ((short*)outp)[idx] = f2bf(v);
        } else if (MODE == 0) {
          ((short*)outp)[idx] = f2bf(v * oscale);
        } else {
          ((short*)outp)[idx] = f2bf(v);
        }
      }
    }
  }
}

// ---------- self-attention, MFMA flash, KVBLK=128, double-buffered ----------
// qkv bf16 [4096,1536] (q pre-scaled by 0.125); vt bf16 [512][4096]
__global__ __launch_bounds__(TPB) void sa_attn_mfma(const short* __restrict__ qkv,
                                                    const short* __restrict__ vt,
                                                    short* __restrict__ outp) {
  __shared__ __align__(16) short Ks[2][128 * 64];
  __shared__ __align__(16) short Vs[2][64 * 128];
  __shared__ __align__(16) short Ps[4][16 * 128];
  int b = blockIdx.z, h = blockIdx.y, q0 = blockIdx.x * 64;
  int tid = threadIdx.x, lane = tid & 63, w = tid >> 6;
  int g = lane >> 4, qi = lane & 15;
  s8v qf[2];
  {
    const short* qp = qkv + (size_t)(b * 1024 + q0 + w * 16 + qi) * 1536 + h * 64 + g * 8;
    qf[0] = *(const s8v*)qp;
    qf[1] = *(const s8v*)(qp + 32);
  }
  f32x4 o[4];
#pragma unroll
  for (int d = 0; d < 4; ++d) o[d] = (f32x4){0.f, 0.f, 0.f, 0.f};
  float mrun = -1e30f, lrun = 0.f;
  const short* kbase = qkv + (size_t)(b * 1024) * 1536 + 512 + h * 64;
  const short* vbase = vt + (size_t)(h * 64) * 4096 + b * 1024;
  char* psw = (char*)Ps + w * 4096;
  int pswz = (qi & 15) << 4;

  auto stage = [&](int bufi, int kt) {
    int k0 = kt * 128;
#pragma unroll
    for (int i = 0; i < 4; ++i) {            // K: 128 rows x 8 slots
      int c = i * 256 + tid;
      int r = c >> 3, cs = c & 7, cg = cs ^ (r & 7);
      const char* gp = (const char*)(kbase + (size_t)(k0 + r) * 1536) + (cg << 4);
      __builtin_amdgcn_global_load_lds((gas_t)gp, (las_t)((char*)Ks[bufi] + (c << 4)), 16, 0, 0);
    }
#pragma unroll
    for (int i = 0; i < 4; ++i) {            // V^T: 64 rows x 16 slots
      int c = i * 256 + tid;
      int r = c >> 4, cs = c & 15, cg = cs ^ (r & 15);
      const char* gp = (const char*)(vbase + (size_t)r * 4096 + k0) + (cg << 4);
      __builtin_amdgcn_global_load_lds((gas_t)gp, (las_t)((char*)Vs[bufi] + (c << 4)), 16, 0, 0);
    }
  };

  stage(0, 0);
  __syncthreads();
  for (int kt = 0; kt < 8; ++kt) {
    int cur = kt & 1;
    if (kt < 7) stage(cur ^ 1, kt + 1);
    // S^T[key][q] = K . Q^T
    f32x4 st[8];
#pragma unroll
    for (int t = 0; t < 8; ++t) st[t] = (f32x4){0.f, 0.f, 0.f, 0.f};
#pragma unroll
    for (int s = 0; s < 2; ++s) {
#pragma unroll
      for (int t = 0; t < 8; ++t) {
        int r = t * 16 + qi;
        s8v kf = *(const s8v*)((const char*)Ks[cur] + r * 128 + (((s * 4 + g) ^ (r & 7)) << 4));
        st[t] = __builtin_amdgcn_mfma_f32_16x16x32_bf16(kf, qf[s], st[t], 0, 0, 0);
      }
    }
    float sv[32];
#pragma unroll
    for (int t = 0; t < 8; ++t)
#pragma unroll
      for (int r2 = 0; r2 < 4; ++r2) sv[t * 4 + r2] = st[t][r2];
    float mx = sv[0];
#pragma unroll
    for (int i = 1; i < 32; ++i) mx = fmaxf(mx, sv[i]);
    mx = fmaxf(mx, __shfl_xor(mx, 16));
    mx = fmaxf(mx, __shfl_xor(mx, 32));
    float mnew = fmaxf(mrun, mx);
    float psum = 0.f;
#pragma unroll
    for (int i = 0; i < 32; ++i) { sv[i] = __expf(sv[i] - mnew); psum += sv[i]; }
    psum += __shfl_xor(psum, 16);
    psum += __shfl_xor(psum, 32);
    float scale = __expf(mrun - mnew);
    lrun = lrun * scale + psum;
    mrun = mnew;
#pragma unroll
    for (int d = 0; d < 4; ++d) o[d] *= scale;
#pragma unroll
    for (int t = 0; t < 8; ++t) {
      short4 pk = make_short4(f2bf(sv[t * 4]), f2bf(sv[t * 4 + 1]),
                              f2bf(sv[t * 4 + 2]), f2bf(sv[t * 4 + 3]));
      *(short4*)(psw + qi * 256 + ((t * 32 + g * 8) ^ pswz)) = pk;
    }
#pragma unroll
    for (int s = 0; s < 4; ++s) {
      s8v bf = *(const s8v*)(psw + qi * 256 + ((s * 64 + g * 16) ^ pswz));
#pragma unroll
      for (int d = 0; d < 4; ++d) {
        int r = d * 16 + qi;
        s8v af = *(const s8v*)((const char*)Vs[cur] + r * 256 + (((s * 4 + g) ^ (r & 15)) << 4));
        o[d] = __builtin_amdgcn_mfma_f32_16x16x32_bf16(af, bf, o[d], 0, 0, 0);
      }
    }
    __syncthreads();
  }
  float rl = 1.f / lrun;
  short* ob = outp + (size_t)(b * 1024 + q0 + w * 16 + qi) * 512 + h * 64;
#pragma unroll
  for (int d = 0; d < 4; ++d) {
    short4 s4 = make_short4(f2bf(o[d][0] * rl), f2bf(o[d][1] * rl),
                            f2bf(o[d][2] * rl), f2bf(o[d][3] * rl));
    *(short4*)(ob + d * 16 + g * 4) = s4;
  }
}

// ---------- cross-attention, MFMA single-pass (q pre-scaled) ----------
__global__ __launch_bounds__(TPB) void ca_attn_mfma(const short* __restrict__ qb,
                                                    const short* __restrict__ kvb,
                                                    const short* __restrict__ cavt,
                                                    short* __restrict__ outp) {
  __shared__ __align__(16) short Ks[96 * 64];
  __shared__ __align__(16) short Vs[64 * 128];
  __shared__ __align__(16) short Ps[4][16 * 128];
  int b = blockIdx.z, h = blockIdx.y, q0 = blockIdx.x * 64;
  int tid = threadIdx.x, lane = tid & 63, w = tid >> 6;
  int g = lane >> 4, qi = lane & 15;
  s8v qf[2];
  {
    const short* qp = qb + (size_t)(b * 1024 + q0 + w * 16 + qi) * 512 + h * 64 + g * 8;
    qf[0] = *(const s8v*)qp;
    qf[1] = *(const s8v*)(qp + 32);
  }
  const short* kbase = kvb + (size_t)(b * 96) * 1024 + h * 64;
#pragma unroll
  for (int i = 0; i < 3; ++i) {
    int c = i * 256 + tid;
    int r = c >> 3, cs = c & 7, cg = cs ^ (r & 7);
    const char* gp = (const char*)(kbase + (size_t)r * 1024) + (cg << 4);
    __builtin_amdgcn_global_load_lds((gas_t)gp, (las_t)((char*)Ks + (c << 4)), 16, 0, 0);
  }
#pragma unroll
  for (int i = 0; i < 3; ++i) {
    int c = i * 256 + tid;
    int r = c / 12, jj = c - r * 12;
    int4 dv = *(const int4*)(cavt + (size_t)(h * 64 + r) * 384 + b * 96 + jj * 8);
    *(int4*)((char*)Vs + r * 256 + ((jj * 16) ^ ((r & 7) << 4))) = dv;
  }
  __syncthreads();
  f32x4 st[6];
#pragma unroll
  for (int t = 0; t < 6; ++t) st[t] = (f32x4){0.f, 0.f, 0.f, 0.f};
#pragma unroll
  for (int s = 0; s < 2; ++s) {
#pragma unroll
    for (int t = 0; t < 6; ++t) {
      int r = t * 16 + qi;
      s8v kf = *(const s8v*)((const char*)Ks + r * 128 + (((s * 4 + g) ^ (r & 7)) << 4));
      st[t] = __builtin_amdgcn_mfma_f32_16x16x32_bf16(kf, qf[s], st[t], 0, 0, 0);
    }
  }
  float sv[24];
#pragma unroll
  for (int t = 0; t < 6; ++t)
#pragma unroll
    for (int r2 = 0; r2 < 4; ++r2) {
      int key = t * 16 + g * 4 + r2;
      sv[t * 4 + r2] = (key < SEQ) ? st[t][r2] : -1e30f;
    }
  float mx = sv[0];
#pragma unroll
  for (int i = 1; i < 24; ++i) mx = fmaxf(mx, sv[i]);
  mx = fmaxf(mx, __shfl_xor(mx, 16));
  mx = fmaxf(mx, __shfl_xor(mx, 32));
  float l = 0.f;
#pragma unroll
  for (int i = 0; i < 24; ++i) { sv[i] = __expf(sv[i] - mx); l += sv[i]; }
  l += __shfl_xor(l, 16);
  l += __shfl_xor(l, 32);
  char* psw = (char*)Ps + w * 4096;
  int pswz = (qi & 7) << 4;
#pragma unroll
  for (int t = 0; t < 6; ++t) {
    short4 pk = make_short4(f2bf(sv[t * 4]), f2bf(sv[t * 4 + 1]),
                            f2bf(sv[t * 4 + 2]), f2bf(sv[t * 4 + 3]));
    *(short4*)(psw + qi * 256 + ((t * 32 + g * 8) ^ pswz)) = pk;
  }
  f32x4 o[4];
#pragma unroll
  for (int d = 0; d < 4; ++d) o[d] = (f32x4){0.f, 0.f, 0.f, 0.f};
#pragma unroll
  for (int s = 0; s < 3; ++s) {
    s8v bf = *(const s8v*)(psw + qi * 256 + ((s * 64 + g * 16) ^ pswz));
#pragma unroll
    for (int d = 0; d < 4; ++d) {
      int r = d * 16 + qi;
      s8v af = *(const s8v*)((const char*)Vs + r * 256 + (((s * 64 + g * 16) ^ ((r & 7) << 4))));
      o[d] = __builtin_amdgcn_mfma_f32_16x16x32_bf16(af, bf, o[d], 0, 0, 0);
    }
  }
  float rl = 1.f / l;
  short* ob = outp + (size_t)(b * 1024 + q0 + w * 16 + qi) * 512 + h * 64;
#pragma unroll
  for (int d = 0; d < 4; ++d) {
    short4 s4 = make_short4(f2bf(o[d][0] * rl), f2bf(o[d][1] * rl),
                            f2bf(o[d][2] * rl), f2bf(o[d][3] * rl));
    *(short4*)(ob + d * 16 + g * 4) = s4;
  }
}

extern "C" void kernel_launch(void* const* d_in, const int* in_sizes, int n_in,
                              void* d_out, int out_size, void* d_ws, size_t ws_size,
                              hipStream_t stream) {
  const float* x        = (const float*)d_in[0];
  const float* context  = (const float*)d_in[1];
  const float* sa_nw    = (const float*)d_in[2];
  const float* sa_nb    = (const float*)d_in[3];
  const float* sa_qkv_w = (const float*)d_in[4];
  const float* sa_qkv_b = (const float*)d_in[5];
  const float* sa_pw    = (const float*)d_in[6];
  const float* sa_pb    = (const float*)d_in[7];
  const float* ca_nw    = (const float*)d_in[8];
  const float* ca_nb    = (const float*)d_in[9];
  const float* ca_qw    = (const float*)d_in[10];
  const float* ca_qb    = (const float*)d_in[11];
  const float* ca_kvw   = (const float*)d_in[12];
  const float* ca_kvb   = (const float*)d_in[13];
  const float* ca_pw    = (const float*)d_in[14];
  const float* ca_pb    = (const float*)d_in[15];
  const float* ff_nw    = (const float*)d_in[16];
  const float* ff_nb    = (const float*)d_in[17];
  const float* ff_w1    = (const float*)d_in[18];
  const float* ff_b1    = (const float*)d_in[19];
  const float* ff_w2    = (const float*)d_in[20];
  const float* ff_b2    = (const float*)d_in[21];
  float* outp = (float*)d_out;

  char* ws = (char*)d_ws;
  float*  xcur  = (float*)(ws);                          // [0,8M)  residual stream (cm f32)
  short*  hb    = (short*)(ws + (8u << 20));             // [8,12M) GN out / attn out (bf16 tm)
  short*  big   = (short*)(ws + (12u << 20));            // [12,28M) qkvb / qb / h1
  short*  qkvb  = big;
  short*  qb    = big;
  short*  h1    = big;
  short*  vt    = (short*)(ws + (28u << 20));            // [28,32M) V^T [512][4096]
  short*  kvb   = (short*)(ws + (32u << 20));            // 768KB
  short*  cavt  = (short*)(ws + (33u << 20));            // 384KB [512][384]
  short*  ctxb  = (short*)(ws + (34u << 20));            // 576KB
  float2* stats = (float2*)(ws + (35u << 20));           // 96 float2 raw sums
  short*  wb    = (short*)(ws + (36u << 20));            // bf16 weights (~8.7MB)

  short* w_qkv = wb;
  short* w_sap = wb + 786432;
  short* w_caq = wb + 1048576;
  short* w_kv  = wb + 1310720;
  short* w_cap = wb + 2097152;
  short* w_f1  = wb + 2359296;
  short* w_f2  = wb + 3407872;

  dim3 blk(TPB);
  prep<<<4672, blk, 0, stream>>>(sa_qkv_w, sa_pw, ca_qw, ca_kvw, ca_pw, ff_w1, ff_w2, wb,
                                 context, ctxb, x, stats);

  // ---- self-attention ----
  gn_apply<<<dim3(16, 32), blk, 0, stream>>>(x, sa_nw, sa_nb, stats, hb);
  gemm_nt<128, 128, 3><<<dim3(32, 12), blk, 0, stream>>>(hb, w_qkv, sa_qkv_b, nullptr, qkvb, vt, 4096, 512, 1536, 1.f, nullptr);
  sa_attn_mfma<<<dim3(16, 8, 4), blk, 0, stream>>>(qkvb, vt, hb);
  gemm_nt<128, 64, 1><<<dim3(32, 8), blk, 0, stream>>>(hb, w_sap, sa_pb, x, xcur, nullptr, 0, 512, 512, 1.f, stats + 32);

  // ---- cross-attention ----
  gn_apply<<<dim3(16, 32), blk, 0, stream>>>(xcur, ca_nw, ca_nb, stats + 32, hb);
  gemm_nt<128, 64, 0><<<dim3(32, 8), blk, 0, stream>>>(hb, w_caq, ca_qb, nullptr, qb, nullptr, 0, 512, 512, 0.125f, nullptr);
  gemm_nt<64, 64, 4><<<dim3(6, 16), blk, 0, stream>>>(ctxb, w_kv, ca_kvb, nullptr, kvb, cavt, 384, 768, 1024, 1.f, nullptr);
  ca_attn_mfma<<<dim3(16, 8, 4), blk, 0, stream>>>(qb, kvb, cavt, hb);
  gemm_nt<128, 64, 1><<<dim3(32, 8), blk, 0, stream>>>(hb, w_cap, ca_pb, xcur, xcur, nullptr, 0, 512, 512, 1.f, stats + 64);

  // ---- FFN ----
  gn_apply<<<dim3(16, 32), blk, 0, stream>>>(xcur, ff_nw, ff_nb, stats + 64, hb);
  gemm_nt<128, 128, 2><<<dim3(32, 16), blk, 0, stream>>>(hb, w_f1, ff_b1, nullptr, h1, nullptr, 0, 512, 2048, 1.f, nullptr);
  gemm_nt<128, 64, 1><<<dim3(32, 8), blk, 0, stream>>>(h1, w_f2, ff_b2, xcur, outp, nullptr, 0, 2048, 512, 1.f, nullptr);
}

// Round 6
// 175.885 us; speedup vs baseline: 6.3161x; 1.0627x over previous
//
#include <hip/hip_runtime.h>

#define TPB 256
#define Bsz 4
#define Nsp 1024
#define Cch 512
#define SEQ 77
#define CTX 768
#define EPSV 1e-5f
#define MTOK 4096   // B * N
#define SCL_L2E 0.18033688011111834f   // 0.125 * log2(e)

typedef __attribute__((ext_vector_type(8))) short s8v;
typedef __attribute__((ext_vector_type(4))) float f32x4;
typedef const __attribute__((address_space(1))) void* gas_t;
typedef __attribute__((address_space(3))) void* las_t;

static __device__ __forceinline__ float bf2f(short s) {
  union { unsigned u; float f; } z; z.u = ((unsigned)(unsigned short)s) << 16; return z.f;
}
static __device__ __forceinline__ short f2bf(float f) {
  union { float f; unsigned u; } v; v.f = f;
  unsigned r = v.u + 0x7fffu + ((v.u >> 16) & 1u);
  return (short)(r >> 16);
}

// ---------- prep: weight/ctx convert + SA gn partial stats + stats zero ----------
// blocks [0,4352): weights; [4352,4640): ctx; [4640,4896): gn partials (8 per bg)
__global__ __launch_bounds__(TPB) void prep(const float* a0, const float* a1,
                                            const float* a2, const float* a3,
                                            const float* a4, const float* a5,
                                            const float* a6, short* __restrict__ wdst,
                                            const float* __restrict__ ctx,
                                            short* __restrict__ cdst,
                                            const float* __restrict__ x,
                                            float2* __restrict__ statsPart,
                                            float2* __restrict__ statsCA,
                                            float2* __restrict__ statsFFN) {
  int blk = blockIdx.x;
  int tid = threadIdx.x;
  if (blk < 4352) {
    int u = blk * TPB + tid;
    const float* src; int base;
    if      (u < 196608) { src = a0; base = 0; }
    else if (u < 262144) { src = a1; base = 196608; }
    else if (u < 327680) { src = a2; base = 262144; }
    else if (u < 524288) { src = a3; base = 327680; }
    else if (u < 589824) { src = a4; base = 524288; }
    else if (u < 851968) { src = a5; base = 589824; }
    else                 { src = a6; base = 851968; }
    float4 v = *(const float4*)(src + (size_t)(u - base) * 4);
    short4 o = make_short4(f2bf(v.x), f2bf(v.y), f2bf(v.z), f2bf(v.w));
    *(short4*)(wdst + (size_t)u * 4) = o;
    return;
  }
  if (blk < 4640) {
    int u = (blk - 4352) * TPB + tid;
    int row = u / 192, c4 = u - row * 192;
    int b = row / 96, s_ = row - b * 96;
    short4 o;
    if (s_ < SEQ) {
      float4 v = *(const float4*)(ctx + ((size_t)(b * SEQ + s_)) * CTX + c4 * 4);
      o = make_short4(f2bf(v.x), f2bf(v.y), f2bf(v.z), f2bf(v.w));
    } else {
      o = make_short4(0, 0, 0, 0);
    }
    *(short4*)(cdst + (size_t)row * CTX + c4 * 4) = o;
    return;
  }
  // SA gn partial sums: idx = (bg, part); 8192 floats each
  int idx = blk - 4640;
  int bg = idx >> 3, part = idx & 7;
  const float* base = x + (size_t)bg * 65536 + part * 8192;
  float s = 0.f, s2 = 0.f;
#pragma unroll
  for (int it = 0; it < 8; ++it) {
    float4 v = ((const float4*)base)[it * 256 + tid];
    s += v.x + v.y + v.z + v.w;
    s2 += v.x * v.x + v.y * v.y + v.z * v.z + v.w * v.w;
  }
  for (int off = 1; off < 64; off <<= 1) {
    s += __shfl_xor(s, off, 64);
    s2 += __shfl_xor(s2, off, 64);
  }
  __shared__ float red[2][4];
  int wid = tid >> 6;
  if ((tid & 63) == 0) { red[0][wid] = s; red[1][wid] = s2; }
  __syncthreads();
  if (tid == 0) {
    float S = red[0][0] + red[0][1] + red[0][2] + red[0][3];
    float S2 = red[1][0] + red[1][1] + red[1][2] + red[1][3];
    statsPart[idx] = make_float2(S, S2);
  } else if (tid == 1 && part == 0) {
    statsCA[bg] = make_float2(0.f, 0.f);
  } else if (tid == 2 && part == 0) {
    statsFFN[bg] = make_float2(0.f, 0.f);
  }
}

// ---------- GroupNorm apply + transpose: [B,C,N] f32 -> token-major bf16 [4096,512] ----------
// stats holds npart RAW (S,S2) partials per (b,g)
__global__ __launch_bounds__(TPB) void gn_apply(const float* __restrict__ x,
                                                const float* __restrict__ w,
                                                const float* __restrict__ bb,
                                                const float2* __restrict__ stats,
                                                short* __restrict__ outp,
                                                int npart) {
  int t = blockIdx.x, bg = blockIdx.y;
  int b = bg >> 3, g = bg & 7;
  float S = 0.f, S2 = 0.f;
  for (int p = 0; p < npart; ++p) {
    float2 st = stats[bg * npart + p];
    S += st.x; S2 += st.y;
  }
  const float inv = 1.f / 65536.f;
  float mu = S * inv;
  float var = S2 * inv - mu * mu;
  float rstd = rsqrtf(var + EPSV);
  __shared__ float tile[64][65];
  int tid = threadIdx.x;
  int n0 = t * 64;
  const float* p = x + (size_t)bg * 65536;
#pragma unroll
  for (int it = 0; it < 4; ++it) {
    int idx = it * 256 + tid;
    int c = idx >> 4, n4 = (idx & 15) * 4;
    float4 v = *(const float4*)(p + (size_t)c * 1024 + n0 + n4);
    float wc = w[g * 64 + c] * rstd;
    float bc = bb[g * 64 + c] - mu * wc;
    tile[c][n4 + 0] = v.x * wc + bc;
    tile[c][n4 + 1] = v.y * wc + bc;
    tile[c][n4 + 2] = v.z * wc + bc;
    tile[c][n4 + 3] = v.w * wc + bc;
  }
  __syncthreads();
  int n = tid >> 2, cs = (tid & 3) * 16;
  short ob[16];
#pragma unroll
  for (int j = 0; j < 16; ++j) ob[j] = f2bf(tile[cs + j][n]);
  short* op = outp + (size_t)(b * 1024 + n0 + n) * 512 + g * 64 + cs;
  *(int4*)op = *(int4*)&ob[0];
  *(int4*)(op + 8) = *(int4*)&ob[8];
}

// ---------- bf16 MFMA NT-GEMM: Out[m,o] = sum_k A[m,k] * W[o,k] + bias[o] ----------
// MODE 0: bf16 tm out, scaled by oscale
// MODE 1: f32 channel-major out [B,O,1024] + cm f32 residual; optional stats accumulation
// MODE 2: gelu -> bf16 tm out
// MODE 3: og<1024 bf16 tm out (og<512 scaled SCL_L2E); og>=1024 transposed to tout (stride 4096)
// MODE 4: og<512  bf16 tm out; og>=512  transposed to tout (stride 384)
template<int BM, int BN, int MODE>
__global__ __launch_bounds__(TPB) void gemm_nt(const short* __restrict__ A,
                                               const short* __restrict__ Bw,
                                               const float* __restrict__ bias,
                                               const float* __restrict__ resid,
                                               void* __restrict__ outp,
                                               short* __restrict__ tout,
                                               int tstride, int K, int O,
                                               float oscale,
                                               float2* __restrict__ stats_out) {
  const int FM = BM / 32, FN = BN / 32;
  __shared__ __align__(16) short As[BM * 64];
  __shared__ __align__(16) short Bs[BN * 64];
  int tid = threadIdx.x;
  int lane = tid & 63, w = tid >> 6;
  int wr = w >> 1, wc = w & 1;
  int m0 = blockIdx.x * BM, o0 = blockIdx.y * BN;
  f32x4 acc[FM][FN];
#pragma unroll
  for (int i = 0; i < FM; ++i)
#pragma unroll
    for (int j = 0; j < FN; ++j) acc[i][j] = (f32x4){0.f, 0.f, 0.f, 0.f};
  int nk = K >> 6;
  for (int kt = 0; kt < nk; ++kt) {
    int k0 = kt << 6;
    __syncthreads();
#pragma unroll
    for (int i = 0; i < BM / 32; ++i) {
      int c = i * 256 + tid;
      int r = c >> 3, qs = c & 7, qg = qs ^ (r & 7);
      const char* ga = (const char*)(A + ((size_t)(m0 + r) * K + k0)) + (qg << 4);
      __builtin_amdgcn_global_load_lds((gas_t)ga, (las_t)((char*)As + (c << 4)), 16, 0, 0);
    }
#pragma unroll
    for (int i = 0; i < BN / 32; ++i) {
      int c = i * 256 + tid;
      int r = c >> 3, qs = c & 7, qg = qs ^ (r & 7);
      const char* gb = (const char*)(Bw + ((size_t)(o0 + r) * K + k0)) + (qg << 4);
      __builtin_amdgcn_global_load_lds((gas_t)gb, (las_t)((char*)Bs + (c << 4)), 16, 0, 0);
    }
    __syncthreads();
#pragma unroll
    for (int kk = 0; kk < 2; ++kk) {
      s8v a[FM], bfr[FN];
#pragma unroll
      for (int m = 0; m < FM; ++m) {
        int r = wr * (BM / 2) + m * 16 + (lane & 15);
        int q = (lane >> 4) + (kk << 2);
        a[m] = *(const s8v*)((const char*)As + r * 128 + ((q ^ (r & 7)) << 4));
      }
#pragma unroll
      for (int n = 0; n < FN; ++n) {
        int r = wc * (BN / 2) + n * 16 + (lane & 15);
        int q = (lane >> 4) + (kk << 2);
        bfr[n] = *(const s8v*)((const char*)Bs + r * 128 + ((q ^ (r & 7)) << 4));
      }
#pragma unroll
      for (int m = 0; m < FM; ++m)
#pragma unroll
        for (int n = 0; n < FN; ++n)
          acc[m][n] = __builtin_amdgcn_mfma_f32_16x16x32_bf16(a[m], bfr[n], acc[m][n], 0, 0, 0);
    }
  }
  float bv[FN];
#pragma unroll
  for (int n = 0; n < FN; ++n) bv[n] = bias[o0 + wc * (BN / 2) + n * 16 + (lane & 15)];
  int row_b = m0 + wr * (BM / 2) + ((lane >> 4) << 2);
  int col_b = o0 + wc * (BN / 2) + (lane & 15);
  const int split = (MODE == 3) ? 1024 : 512;
  if ((MODE == 3 || MODE == 4) && o0 >= split) {
#pragma unroll
    for (int m = 0; m < FM; ++m) {
#pragma unroll
      for (int n = 0; n < FN; ++n) {
        int og = col_b + n * 16;
        short4 s4 = make_short4(f2bf(acc[m][n][0] + bv[n]), f2bf(acc[m][n][1] + bv[n]),
                                f2bf(acc[m][n][2] + bv[n]), f2bf(acc[m][n][3] + bv[n]));
        *(short4*)(tout + (size_t)(og - split) * tstride + row_b + m * 16) = s4;
      }
    }
    return;
  }
  if (MODE == 1) {
    float ls = 0.f, ls2 = 0.f;
#pragma unroll
    for (int m = 0; m < FM; ++m) {
      int t0 = row_b + m * 16;
      int b = t0 >> 10, n_ = t0 & 1023;
#pragma unroll
      for (int n = 0; n < FN; ++n) {
        int og = col_b + n * 16;
        size_t idx = ((size_t)(b * O + og)) * 1024 + n_;
        float4 rv = *(const float4*)(resid + idx);
        float4 ov;
        ov.x = acc[m][n][0] + bv[n] + rv.x;
        ov.y = acc[m][n][1] + bv[n] + rv.y;
        ov.z = acc[m][n][2] + bv[n] + rv.z;
        ov.w = acc[m][n][3] + bv[n] + rv.w;
        *(float4*)((float*)outp + idx) = ov;
        ls += ov.x + ov.y + ov.z + ov.w;
        ls2 += ov.x * ov.x + ov.y * ov.y + ov.z * ov.z + ov.w * ov.w;
      }
    }
    if (stats_out != nullptr) {
      float s = ls, s2 = ls2;
      for (int off = 1; off < 64; off <<= 1) {
        s += __shfl_xor(s, off, 64);
        s2 += __shfl_xor(s2, off, 64);
      }
      __syncthreads();
      float* red = (float*)As;
      if (lane == 0) { red[w * 2] = s; red[w * 2 + 1] = s2; }
      __syncthreads();
      if (tid == 0) {
        float S = red[0] + red[2] + red[4] + red[6];
        float S2 = red[1] + red[3] + red[5] + red[7];
        int bg = (m0 >> 10) * 8 + (o0 >> 6);
        atomicAdd((float*)stats_out + bg * 2, S);
        atomicAdd((float*)stats_out + bg * 2 + 1, S2);
      }
    }
    return;
  }
#pragma unroll
  for (int m = 0; m < FM; ++m) {
#pragma unroll
    for (int i = 0; i < 4; ++i) {
      int mg = row_b + m * 16 + i;
#pragma unroll
      for (int n = 0; n < FN; ++n) {
        int og = col_b + n * 16;
        float v = acc[m][n][i] + bv[n];
        size_t idx = (size_t)mg * O + og;
        if (MODE == 2) {
          float gv = 0.5f * v * (1.f + erff(v * 0.70710678118654752f));
          ((short*)outp)[idx] = f2bf(gv);
        } else if (MODE == 3) {
          if (og < 512) v *= SCL_L2E;
          ((short*)outp)[idx] = f2bf(v);
        } else if (MODE == 0) {
          ((short*)outp)[idx] = f2bf(v * oscale);
        } else {
          ((short*)outp)[idx] = f2bf(v);
        }
      }
    }
  }
}

// ---------- self-attention, MFMA flash, KVBLK=128, double-buffered, exp2 softmax ----------
// qkv bf16 [4096,1536] (q pre-scaled by 0.125*log2e); vt bf16 [512][4096]
__global__ __launch_bounds__(TPB) void sa_attn_mfma(const short* __restrict__ qkv,
                                                    const short* __restrict__ vt,
                                                    short* __restrict__ outp) {
  __shared__ __align__(16) short Ks[2][128 * 64];
  __shared__ __align__(16) short Vs[2][64 * 128];
  __shared__ __align__(16) short Ps[4][16 * 128];
  int b = blockIdx.z, h = blockIdx.y, q0 = blockIdx.x * 64;
  int tid = threadIdx.x, lane = tid & 63, w = tid >> 6;
  int g = lane >> 4, qi = lane & 15;
  s8v qf[2];
  {
    const short* qp = qkv + (size_t)(b * 1024 + q0 + w * 16 + qi) * 1536 + h * 64 + g * 8;
    qf[0] = *(const s8v*)qp;
    qf[1] = *(const s8v*)(qp + 32);
  }
  f32x4 o[4];
#pragma unroll
  for (int d = 0; d < 4; ++d) o[d] = (f32x4){0.f, 0.f, 0.f, 0.f};
  float mrun = -1e30f, lrun = 0.f;
  const short* kbase = qkv + (size_t)(b * 1024) * 1536 + 512 + h * 64;
  const short* vbase = vt + (size_t)(h * 64) * 4096 + b * 1024;
  char* psw = (char*)Ps + w * 4096;
  int pswz = (qi & 15) << 4;

  auto stage = [&](int bufi, int kt) {
    int k0 = kt * 128;
#pragma unroll
    for (int i = 0; i < 4; ++i) {            // K: 128 rows x 8 slots
      int c = i * 256 + tid;
      int r = c >> 3, cs = c & 7, cg = cs ^ (r & 7);
      const char* gp = (const char*)(kbase + (size_t)(k0 + r) * 1536) + (cg << 4);
      __builtin_amdgcn_global_load_lds((gas_t)gp, (las_t)((char*)Ks[bufi] + (c << 4)), 16, 0, 0);
    }
#pragma unroll
    for (int i = 0; i < 4; ++i) {            // V^T: 64 rows x 16 slots
      int c = i * 256 + tid;
      int r = c >> 4, cs = c & 15, cg = cs ^ (r & 15);
      const char* gp = (const char*)(vbase + (size_t)r * 4096 + k0) + (cg << 4);
      __builtin_amdgcn_global_load_lds((gas_t)gp, (las_t)((char*)Vs[bufi] + (c << 4)), 16, 0, 0);
    }
  };

  stage(0, 0);
  __syncthreads();
  for (int kt = 0; kt < 8; ++kt) {
    int cur = kt & 1;
    if (kt < 7) stage(cur ^ 1, kt + 1);
    // S^T[key][q] = K . Q^T   (log2-domain scores)
    f32x4 st[8];
#pragma unroll
    for (int t = 0; t < 8; ++t) st[t] = (f32x4){0.f, 0.f, 0.f, 0.f};
#pragma unroll
    for (int s = 0; s < 2; ++s) {
#pragma unroll
      for (int t = 0; t < 8; ++t) {
        int r = t * 16 + qi;
        s8v kf = *(const s8v*)((const char*)Ks[cur] + r * 128 + (((s * 4 + g) ^ (r & 7)) << 4));
        st[t] = __builtin_amdgcn_mfma_f32_16x16x32_bf16(kf, qf[s], st[t], 0, 0, 0);
      }
    }
    float sv[32];
#pragma unroll
    for (int t = 0; t < 8; ++t)
#pragma unroll
      for (int r2 = 0; r2 < 4; ++r2) sv[t * 4 + r2] = st[t][r2];
    float mx = sv[0];
#pragma unroll
    for (int i = 1; i < 32; ++i) mx = fmaxf(mx, sv[i]);
    mx = fmaxf(mx, __shfl_xor(mx, 16));
    mx = fmaxf(mx, __shfl_xor(mx, 32));
    float mnew = fmaxf(mrun, mx);
    float psum = 0.f;
#pragma unroll
    for (int i = 0; i < 32; ++i) { sv[i] = exp2f(sv[i] - mnew); psum += sv[i]; }
    psum += __shfl_xor(psum, 16);
    psum += __shfl_xor(psum, 32);
    float scale = exp2f(mrun - mnew);
    lrun = lrun * scale + psum;
    mrun = mnew;
#pragma unroll
    for (int d = 0; d < 4; ++d) o[d] *= scale;
#pragma unroll
    for (int t = 0; t < 8; ++t) {
      short4 pk = make_short4(f2bf(sv[t * 4]), f2bf(sv[t * 4 + 1]),
                              f2bf(sv[t * 4 + 2]), f2bf(sv[t * 4 + 3]));
      *(short4*)(psw + qi * 256 + ((t * 32 + g * 8) ^ pswz)) = pk;
    }
#pragma unroll
    for (int s = 0; s < 4; ++s) {
      s8v bf = *(const s8v*)(psw + qi * 256 + ((s * 64 + g * 16) ^ pswz));
#pragma unroll
      for (int d = 0; d < 4; ++d) {
        int r = d * 16 + qi;
        s8v af = *(const s8v*)((const char*)Vs[cur] + r * 256 + (((s * 4 + g) ^ (r & 15)) << 4));
        o[d] = __builtin_amdgcn_mfma_f32_16x16x32_bf16(af, bf, o[d], 0, 0, 0);
      }
    }
    __syncthreads();
  }
  float rl = 1.f / lrun;
  short* ob = outp + (size_t)(b * 1024 + q0 + w * 16 + qi) * 512 + h * 64;
#pragma unroll
  for (int d = 0; d < 4; ++d) {
    short4 s4 = make_short4(f2bf(o[d][0] * rl), f2bf(o[d][1] * rl),
                            f2bf(o[d][2] * rl), f2bf(o[d][3] * rl));
    *(short4*)(ob + d * 16 + g * 4) = s4;
  }
}

// ---------- cross-attention, MFMA single-pass (q pre-scaled, exp2) ----------
__global__ __launch_bounds__(TPB) void ca_attn_mfma(const short* __restrict__ qb,
                                                    const short* __restrict__ kvb,
                                                    const short* __restrict__ cavt,
                                                    short* __restrict__ outp) {
  __shared__ __align__(16) short Ks[96 * 64];
  __shared__ __align__(16) short Vs[64 * 128];
  __shared__ __align__(16) short Ps[4][16 * 128];
  int b = blockIdx.z, h = blockIdx.y, q0 = blockIdx.x * 64;
  int tid = threadIdx.x, lane = tid & 63, w = tid >> 6;
  int g = lane >> 4, qi = lane & 15;
  s8v qf[2];
  {
    const short* qp = qb + (size_t)(b * 1024 + q0 + w * 16 + qi) * 512 + h * 64 + g * 8;
    qf[0] = *(const s8v*)qp;
    qf[1] = *(const s8v*)(qp + 32);
  }
  const short* kbase = kvb + (size_t)(b * 96) * 1024 + h * 64;
#pragma unroll
  for (int i = 0; i < 3; ++i) {
    int c = i * 256 + tid;
    int r = c >> 3, cs = c & 7, cg = cs ^ (r & 7);
    const char* gp = (const char*)(kbase + (size_t)r * 1024) + (cg << 4);
    __builtin_amdgcn_global_load_lds((gas_t)gp, (las_t)((char*)Ks + (c << 4)), 16, 0, 0);
  }
#pragma unroll
  for (int i = 0; i < 3; ++i) {
    int c = i * 256 + tid;
    int r = c / 12, jj = c - r * 12;
    int4 dv = *(const int4*)(cavt + (size_t)(h * 64 + r) * 384 + b * 96 + jj * 8);
    *(int4*)((char*)Vs + r * 256 + ((jj * 16) ^ ((r & 7) << 4))) = dv;
  }
  __syncthreads();
  f32x4 st[6];
#pragma unroll
  for (int t = 0; t < 6; ++t) st[t] = (f32x4){0.f, 0.f, 0.f, 0.f};
#pragma unroll
  for (int s = 0; s < 2; ++s) {
#pragma unroll
    for (int t = 0; t < 6; ++t) {
      int r = t * 16 + qi;
      s8v kf = *(const s8v*)((const char*)Ks + r * 128 + (((s * 4 + g) ^ (r & 7)) << 4));
      st[t] = __builtin_amdgcn_mfma_f32_16x16x32_bf16(kf, qf[s], st[t], 0, 0, 0);
    }
  }
  float sv[24];
#pragma unroll
  for (int t = 0; t < 6; ++t)
#pragma unroll
    for (int r2 = 0; r2 < 4; ++r2) {
      int key = t * 16 + g * 4 + r2;
      sv[t * 4 + r2] = (key < SEQ) ? st[t][r2] : -1e30f;
    }
  float mx = sv[0];
#pragma unroll
  for (int i = 1; i < 24; ++i) mx = fmaxf(mx, sv[i]);
  mx = fmaxf(mx, __shfl_xor(mx, 16));
  mx = fmaxf(mx, __shfl_xor(mx, 32));
  float l = 0.f;
#pragma unroll
  for (int i = 0; i < 24; ++i) { sv[i] = exp2f(sv[i] - mx); l += sv[i]; }
  l += __shfl_xor(l, 16);
  l += __shfl_xor(l, 32);
  char* psw = (char*)Ps + w * 4096;
  int pswz = (qi & 7) << 4;
#pragma unroll
  for (int t = 0; t < 6; ++t) {
    short4 pk = make_short4(f2bf(sv[t * 4]), f2bf(sv[t * 4 + 1]),
                            f2bf(sv[t * 4 + 2]), f2bf(sv[t * 4 + 3]));
    *(short4*)(psw + qi * 256 + ((t * 32 + g * 8) ^ pswz)) = pk;
  }
  f32x4 o[4];
#pragma unroll
  for (int d = 0; d < 4; ++d) o[d] = (f32x4){0.f, 0.f, 0.f, 0.f};
#pragma unroll
  for (int s = 0; s < 3; ++s) {
    s8v bf = *(const s8v*)(psw + qi * 256 + ((s * 64 + g * 16) ^ pswz));
#pragma unroll
    for (int d = 0; d < 4; ++d) {
      int r = d * 16 + qi;
      s8v af = *(const s8v*)((const char*)Vs + r * 256 + (((s * 64 + g * 16) ^ ((r & 7) << 4))));
      o[d] = __builtin_amdgcn_mfma_f32_16x16x32_bf16(af, bf, o[d], 0, 0, 0);
    }
  }
  float rl = 1.f / l;
  short* ob = outp + (size_t)(b * 1024 + q0 + w * 16 + qi) * 512 + h * 64;
#pragma unroll
  for (int d = 0; d < 4; ++d) {
    short4 s4 = make_short4(f2bf(o[d][0] * rl), f2bf(o[d][1] * rl),
                            f2bf(o[d][2] * rl), f2bf(o[d][3] * rl));
    *(short4*)(ob + d * 16 + g * 4) = s4;
  }
}

extern "C" void kernel_launch(void* const* d_in, const int* in_sizes, int n_in,
                              void* d_out, int out_size, void* d_ws, size_t ws_size,
                              hipStream_t stream) {
  const float* x        = (const float*)d_in[0];
  const float* context  = (const float*)d_in[1];
  const float* sa_nw    = (const float*)d_in[2];
  const float* sa_nb    = (const float*)d_in[3];
  const float* sa_qkv_w = (const float*)d_in[4];
  const float* sa_qkv_b = (const float*)d_in[5];
  const float* sa_pw    = (const float*)d_in[6];
  const float* sa_pb    = (const float*)d_in[7];
  const float* ca_nw    = (const float*)d_in[8];
  const float* ca_nb    = (const float*)d_in[9];
  const float* ca_qw    = (const float*)d_in[10];
  const float* ca_qb    = (const float*)d_in[11];
  const float* ca_kvw   = (const float*)d_in[12];
  const float* ca_kvb   = (const float*)d_in[13];
  const float* ca_pw    = (const float*)d_in[14];
  const float* ca_pb    = (const float*)d_in[15];
  const float* ff_nw    = (const float*)d_in[16];
  const float* ff_nb    = (const float*)d_in[17];
  const float* ff_w1    = (const float*)d_in[18];
  const float* ff_b1    = (const float*)d_in[19];
  const float* ff_w2    = (const float*)d_in[20];
  const float* ff_b2    = (const float*)d_in[21];
  float* outp = (float*)d_out;

  char* ws = (char*)d_ws;
  float*  xcur  = (float*)(ws);                          // [0,8M)  residual stream (cm f32)
  short*  hb    = (short*)(ws + (8u << 20));             // [8,12M) GN out / attn out (bf16 tm)
  short*  big   = (short*)(ws + (12u << 20));            // [12,28M) qkvb / qb / h1
  short*  qkvb  = big;
  short*  qb    = big;
  short*  h1    = big;
  short*  vt    = (short*)(ws + (28u << 20));            // [28,32M) V^T [512][4096]
  short*  kvb   = (short*)(ws + (32u << 20));            // 768KB
  short*  cavt  = (short*)(ws + (33u << 20));            // 384KB [512][384]
  short*  ctxb  = (short*)(ws + (34u << 20));            // 576KB
  float2* statsPart = (float2*)(ws + (35u << 20));       // [32][8] partials (SA)
  float2* statsCA   = statsPart + 256;                   // 32 raw sums (CA)
  float2* statsFFN  = statsPart + 288;                   // 32 raw sums (FFN)
  short*  wb    = (short*)(ws + (36u << 20));            // bf16 weights (~8.7MB)

  short* w_qkv = wb;
  short* w_sap = wb + 786432;
  short* w_caq = wb + 1048576;
  short* w_kv  = wb + 1310720;
  short* w_cap = wb + 2097152;
  short* w_f1  = wb + 2359296;
  short* w_f2  = wb + 3407872;

  dim3 blk(TPB);
  prep<<<4896, blk, 0, stream>>>(sa_qkv_w, sa_pw, ca_qw, ca_kvw, ca_pw, ff_w1, ff_w2, wb,
                                 context, ctxb, x, statsPart, statsCA, statsFFN);

  // ---- self-attention ----
  gn_apply<<<dim3(16, 32), blk, 0, stream>>>(x, sa_nw, sa_nb, statsPart, hb, 8);
  gemm_nt<128, 128, 3><<<dim3(32, 12), blk, 0, stream>>>(hb, w_qkv, sa_qkv_b, nullptr, qkvb, vt, 4096, 512, 1536, 1.f, nullptr);
  sa_attn_mfma<<<dim3(16, 8, 4), blk, 0, stream>>>(qkvb, vt, hb);
  gemm_nt<128, 64, 1><<<dim3(32, 8), blk, 0, stream>>>(hb, w_sap, sa_pb, x, xcur, nullptr, 0, 512, 512, 1.f, statsCA);

  // ---- cross-attention ----
  gn_apply<<<dim3(16, 32), blk, 0, stream>>>(xcur, ca_nw, ca_nb, statsCA, hb, 1);
  gemm_nt<128, 64, 0><<<dim3(32, 8), blk, 0, stream>>>(hb, w_caq, ca_qb, nullptr, qb, nullptr, 0, 512, 512, SCL_L2E, nullptr);
  gemm_nt<64, 64, 4><<<dim3(6, 16), blk, 0, stream>>>(ctxb, w_kv, ca_kvb, nullptr, kvb, cavt, 384, 768, 1024, 1.f, nullptr);
  ca_attn_mfma<<<dim3(16, 8, 4), blk, 0, stream>>>(qb, kvb, cavt, hb);
  gemm_nt<128, 64, 1><<<dim3(32, 8), blk, 0, stream>>>(hb, w_cap, ca_pb, xcur, xcur, nullptr, 0, 512, 512, 1.f, statsFFN);

  // ---- FFN ----
  gn_apply<<<dim3(16, 32), blk, 0, stream>>>(xcur, ff_nw, ff_nb, statsFFN, hb, 1);
  gemm_nt<128, 128, 2><<<dim3(32, 16), blk, 0, stream>>>(hb, w_f1, ff_b1, nullptr, h1, nullptr, 0, 512, 2048, 1.f, nullptr);
  gemm_nt<128, 64, 1><<<dim3(32, 8), blk, 0, stream>>>(h1, w_f2, ff_b2, xcur, outp, nullptr, 0, 2048, 512, 1.f, nullptr);
}

// Round 7
// 169.027 us; speedup vs baseline: 6.5724x; 1.0406x over previous
//
#include <hip/hip_runtime.h>
#include <hip/hip_bf16.h>

#define TPB 256
#define Bsz 4
#define Nsp 1024
#define Cch 512
#define SEQ 77
#define CTX 768
#define EPSV 1e-5f
#define MTOK 4096   // B * N
#define SCL_L2E 0.18033688011111834f   // 0.125 * log2(e)

typedef __attribute__((ext_vector_type(8))) short s8v;
typedef __attribute__((ext_vector_type(4))) float f32x4;
typedef const __attribute__((address_space(1))) void* gas_t;
typedef __attribute__((address_space(3))) void* las_t;

static __device__ __forceinline__ float bf2f(short s) {
  union { unsigned u; float f; } z; z.u = ((unsigned)(unsigned short)s) << 16; return z.f;
}
static __device__ __forceinline__ short f2bf(float f) {
  union { __hip_bfloat16 h; short s; } u;
  u.h = __float2bfloat16(f);
  return u.s;
}

// ---------- prep: weight/ctx convert + SA gn partial stats + stats zero ----------
// blocks [0,4352): weights; [4352,4640): ctx; [4640,4896): gn partials (8 per bg)
__global__ __launch_bounds__(TPB) void prep(const float* a0, const float* a1,
                                            const float* a2, const float* a3,
                                            const float* a4, const float* a5,
                                            const float* a6, short* __restrict__ wdst,
                                            const float* __restrict__ ctx,
                                            short* __restrict__ cdst,
                                            const float* __restrict__ x,
                                            float2* __restrict__ statsPart,
                                            float2* __restrict__ statsCA,
                                            float2* __restrict__ statsFFN) {
  int blk = blockIdx.x;
  int tid = threadIdx.x;
  if (blk < 4352) {
    int u = blk * TPB + tid;
    const float* src; int base;
    if      (u < 196608) { src = a0; base = 0; }
    else if (u < 262144) { src = a1; base = 196608; }
    else if (u < 327680) { src = a2; base = 262144; }
    else if (u < 524288) { src = a3; base = 327680; }
    else if (u < 589824) { src = a4; base = 524288; }
    else if (u < 851968) { src = a5; base = 589824; }
    else                 { src = a6; base = 851968; }
    float4 v = *(const float4*)(src + (size_t)(u - base) * 4);
    short4 o = make_short4(f2bf(v.x), f2bf(v.y), f2bf(v.z), f2bf(v.w));
    *(short4*)(wdst + (size_t)u * 4) = o;
    return;
  }
  if (blk < 4640) {
    int u = (blk - 4352) * TPB + tid;
    int row = u / 192, c4 = u - row * 192;
    int b = row / 96, s_ = row - b * 96;
    short4 o;
    if (s_ < SEQ) {
      float4 v = *(const float4*)(ctx + ((size_t)(b * SEQ + s_)) * CTX + c4 * 4);
      o = make_short4(f2bf(v.x), f2bf(v.y), f2bf(v.z), f2bf(v.w));
    } else {
      o = make_short4(0, 0, 0, 0);
    }
    *(short4*)(cdst + (size_t)row * CTX + c4 * 4) = o;
    return;
  }
  // SA gn partial sums: idx = (bg, part); 8192 floats each
  int idx = blk - 4640;
  int bg = idx >> 3, part = idx & 7;
  const float* base = x + (size_t)bg * 65536 + part * 8192;
  float s = 0.f, s2 = 0.f;
#pragma unroll
  for (int it = 0; it < 8; ++it) {
    float4 v = ((const float4*)base)[it * 256 + tid];
    s += v.x + v.y + v.z + v.w;
    s2 += v.x * v.x + v.y * v.y + v.z * v.z + v.w * v.w;
  }
  for (int off = 1; off < 64; off <<= 1) {
    s += __shfl_xor(s, off, 64);
    s2 += __shfl_xor(s2, off, 64);
  }
  __shared__ float red[2][4];
  int wid = tid >> 6;
  if ((tid & 63) == 0) { red[0][wid] = s; red[1][wid] = s2; }
  __syncthreads();
  if (tid == 0) {
    float S = red[0][0] + red[0][1] + red[0][2] + red[0][3];
    float S2 = red[1][0] + red[1][1] + red[1][2] + red[1][3];
    statsPart[idx] = make_float2(S, S2);
  } else if (tid == 1 && part == 0) {
    statsCA[bg] = make_float2(0.f, 0.f);
  } else if (tid == 2 && part == 0) {
    statsFFN[bg] = make_float2(0.f, 0.f);
  }
}

// ---------- GroupNorm apply + transpose: [B,C,N] f32 -> token-major bf16 [4096,512] ----------
__global__ __launch_bounds__(TPB) void gn_apply(const float* __restrict__ x,
                                                const float* __restrict__ w,
                                                const float* __restrict__ bb,
                                                const float2* __restrict__ stats,
                                                short* __restrict__ outp,
                                                int npart) {
  int t = blockIdx.x, bg = blockIdx.y;
  int b = bg >> 3, g = bg & 7;
  float S = 0.f, S2 = 0.f;
  for (int p = 0; p < npart; ++p) {
    float2 st = stats[bg * npart + p];
    S += st.x; S2 += st.y;
  }
  const float inv = 1.f / 65536.f;
  float mu = S * inv;
  float var = S2 * inv - mu * mu;
  float rstd = rsqrtf(var + EPSV);
  __shared__ float tile[64][65];
  int tid = threadIdx.x;
  int n0 = t * 64;
  const float* p = x + (size_t)bg * 65536;
#pragma unroll
  for (int it = 0; it < 4; ++it) {
    int idx = it * 256 + tid;
    int c = idx >> 4, n4 = (idx & 15) * 4;
    float4 v = *(const float4*)(p + (size_t)c * 1024 + n0 + n4);
    float wc = w[g * 64 + c] * rstd;
    float bc = bb[g * 64 + c] - mu * wc;
    tile[c][n4 + 0] = v.x * wc + bc;
    tile[c][n4 + 1] = v.y * wc + bc;
    tile[c][n4 + 2] = v.z * wc + bc;
    tile[c][n4 + 3] = v.w * wc + bc;
  }
  __syncthreads();
  int n = tid >> 2, cs = (tid & 3) * 16;
  short ob[16];
#pragma unroll
  for (int j = 0; j < 16; ++j) ob[j] = f2bf(tile[cs + j][n]);
  short* op = outp + (size_t)(b * 1024 + n0 + n) * 512 + g * 64 + cs;
  *(int4*)op = *(int4*)&ob[0];
  *(int4*)(op + 8) = *(int4*)&ob[8];
}

// ---------- bf16 MFMA NT-GEMM (generic): Out[m,o] = sum_k A[m,k]*W[o,k] + bias[o] ----------
// MODE 0: bf16 tm out, scaled by oscale
// MODE 1: f32 channel-major out [B,O,1024] + cm f32 residual; optional stats accumulation
// MODE 2: gelu -> bf16 tm out
template<int BM, int BN, int MODE>
__global__ __launch_bounds__(TPB) void gemm_nt(const short* __restrict__ A,
                                               const short* __restrict__ Bw,
                                               const float* __restrict__ bias,
                                               const float* __restrict__ resid,
                                               void* __restrict__ outp,
                                               int K, int O,
                                               float oscale,
                                               float2* __restrict__ stats_out) {
  const int FM = BM / 32, FN = BN / 32;
  __shared__ __align__(16) short As[BM * 64];
  __shared__ __align__(16) short Bs[BN * 64];
  int tid = threadIdx.x;
  int lane = tid & 63, w = tid >> 6;
  int wr = w >> 1, wc = w & 1;
  int m0 = blockIdx.x * BM, o0 = blockIdx.y * BN;
  f32x4 acc[FM][FN];
#pragma unroll
  for (int i = 0; i < FM; ++i)
#pragma unroll
    for (int j = 0; j < FN; ++j) acc[i][j] = (f32x4){0.f, 0.f, 0.f, 0.f};
  int nk = K >> 6;
  for (int kt = 0; kt < nk; ++kt) {
    int k0 = kt << 6;
    __syncthreads();
#pragma unroll
    for (int i = 0; i < BM / 32; ++i) {
      int c = i * 256 + tid;
      int r = c >> 3, qs = c & 7, qg = qs ^ (r & 7);
      const char* ga = (const char*)(A + ((size_t)(m0 + r) * K + k0)) + (qg << 4);
      __builtin_amdgcn_global_load_lds((gas_t)ga, (las_t)((char*)As + (c << 4)), 16, 0, 0);
    }
#pragma unroll
    for (int i = 0; i < BN / 32; ++i) {
      int c = i * 256 + tid;
      int r = c >> 3, qs = c & 7, qg = qs ^ (r & 7);
      const char* gb = (const char*)(Bw + ((size_t)(o0 + r) * K + k0)) + (qg << 4);
      __builtin_amdgcn_global_load_lds((gas_t)gb, (las_t)((char*)Bs + (c << 4)), 16, 0, 0);
    }
    __syncthreads();
#pragma unroll
    for (int kk = 0; kk < 2; ++kk) {
      s8v a[FM], bfr[FN];
#pragma unroll
      for (int m = 0; m < FM; ++m) {
        int r = wr * (BM / 2) + m * 16 + (lane & 15);
        int q = (lane >> 4) + (kk << 2);
        a[m] = *(const s8v*)((const char*)As + r * 128 + ((q ^ (r & 7)) << 4));
      }
#pragma unroll
      for (int n = 0; n < FN; ++n) {
        int r = wc * (BN / 2) + n * 16 + (lane & 15);
        int q = (lane >> 4) + (kk << 2);
        bfr[n] = *(const s8v*)((const char*)Bs + r * 128 + ((q ^ (r & 7)) << 4));
      }
#pragma unroll
      for (int m = 0; m < FM; ++m)
#pragma unroll
        for (int n = 0; n < FN; ++n)
          acc[m][n] = __builtin_amdgcn_mfma_f32_16x16x32_bf16(a[m], bfr[n], acc[m][n], 0, 0, 0);
    }
  }
  float bv[FN];
#pragma unroll
  for (int n = 0; n < FN; ++n) bv[n] = bias[o0 + wc * (BN / 2) + n * 16 + (lane & 15)];
  int row_b = m0 + wr * (BM / 2) + ((lane >> 4) << 2);
  int col_b = o0 + wc * (BN / 2) + (lane & 15);
  if (MODE == 1) {
    float ls = 0.f, ls2 = 0.f;
#pragma unroll
    for (int m = 0; m < FM; ++m) {
      int t0 = row_b + m * 16;
      int b = t0 >> 10, n_ = t0 & 1023;
#pragma unroll
      for (int n = 0; n < FN; ++n) {
        int og = col_b + n * 16;
        size_t idx = ((size_t)(b * O + og)) * 1024 + n_;
        float4 rv = *(const float4*)(resid + idx);
        float4 ov;
        ov.x = acc[m][n][0] + bv[n] + rv.x;
        ov.y = acc[m][n][1] + bv[n] + rv.y;
        ov.z = acc[m][n][2] + bv[n] + rv.z;
        ov.w = acc[m][n][3] + bv[n] + rv.w;
        *(float4*)((float*)outp + idx) = ov;
        ls += ov.x + ov.y + ov.z + ov.w;
        ls2 += ov.x * ov.x + ov.y * ov.y + ov.z * ov.z + ov.w * ov.w;
      }
    }
    if (stats_out != nullptr) {
      float s = ls, s2 = ls2;
      for (int off = 1; off < 64; off <<= 1) {
        s += __shfl_xor(s, off, 64);
        s2 += __shfl_xor(s2, off, 64);
      }
      __syncthreads();
      float* red = (float*)As;
      if (lane == 0) { red[w * 2] = s; red[w * 2 + 1] = s2; }
      __syncthreads();
      if (tid == 0) {
        float S = red[0] + red[2] + red[4] + red[6];
        float S2 = red[1] + red[3] + red[5] + red[7];
        int bg = (m0 >> 10) * 8 + (o0 >> 6);
        atomicAdd((float*)stats_out + bg * 2, S);
        atomicAdd((float*)stats_out + bg * 2 + 1, S2);
      }
    }
    return;
  }
#pragma unroll
  for (int m = 0; m < FM; ++m) {
#pragma unroll
    for (int i = 0; i < 4; ++i) {
      int mg = row_b + m * 16 + i;
#pragma unroll
      for (int n = 0; n < FN; ++n) {
        int og = col_b + n * 16;
        float v = acc[m][n][i] + bv[n];
        size_t idx = (size_t)mg * O + og;
        if (MODE == 2) {
          float gv = 0.5f * v * (1.f + erff(v * 0.70710678118654752f));
          ((short*)outp)[idx] = f2bf(gv);
        } else {
          ((short*)outp)[idx] = f2bf(v * oscale);
        }
      }
    }
  }
}

// ---------- merged qkv + ca_kv GEMM: flat grid of 408 blocks, 128x128 tiles ----------
// blocks [0,384): qkv (M=4096,K=512,O=1536); [384,408): kv (M=384,K=768,O=1024)
__global__ __launch_bounds__(TPB) void gemm_qkvkv(
    const short* __restrict__ hb, const short* __restrict__ wqkv, const float* __restrict__ bqkv,
    const short* __restrict__ ctxb, const short* __restrict__ wkv, const float* __restrict__ bkv,
    short* __restrict__ qkvb, short* __restrict__ vt,
    short* __restrict__ kvb, short* __restrict__ cavt) {
  __shared__ __align__(16) short As[128 * 64];
  __shared__ __align__(16) short Bs[128 * 64];
  int bid = blockIdx.x;
  const short *A, *Bw; const float* bias;
  short *outp, *tout;
  int K, O, m0, o0, split, tstride, qsplit;
  if (bid < 384) {
    A = hb; Bw = wqkv; bias = bqkv; outp = qkvb; tout = vt;
    K = 512; O = 1536; split = 1024; tstride = 4096; qsplit = 512;
    m0 = (bid & 31) * 128; o0 = (bid >> 5) * 128;
  } else {
    int idx = bid - 384;
    A = ctxb; Bw = wkv; bias = bkv; outp = kvb; tout = cavt;
    K = 768; O = 1024; split = 512; tstride = 384; qsplit = 0;
    m0 = (idx % 3) * 128; o0 = (idx / 3) * 128;
  }
  int tid = threadIdx.x;
  int lane = tid & 63, w = tid >> 6;
  int wr = w >> 1, wc = w & 1;
  f32x4 acc[4][4];
#pragma unroll
  for (int i = 0; i < 4; ++i)
#pragma unroll
    for (int j = 0; j < 4; ++j) acc[i][j] = (f32x4){0.f, 0.f, 0.f, 0.f};
  int nk = K >> 6;
  for (int kt = 0; kt < nk; ++kt) {
    int k0 = kt << 6;
    __syncthreads();
#pragma unroll
    for (int i = 0; i < 4; ++i) {
      int c = i * 256 + tid;
      int r = c >> 3, qs = c & 7, qg = qs ^ (r & 7);
      const char* ga = (const char*)(A + ((size_t)(m0 + r) * K + k0)) + (qg << 4);
      __builtin_amdgcn_global_load_lds((gas_t)ga, (las_t)((char*)As + (c << 4)), 16, 0, 0);
    }
#pragma unroll
    for (int i = 0; i < 4; ++i) {
      int c = i * 256 + tid;
      int r = c >> 3, qs = c & 7, qg = qs ^ (r & 7);
      const char* gb = (const char*)(Bw + ((size_t)(o0 + r) * K + k0)) + (qg << 4);
      __builtin_amdgcn_global_load_lds((gas_t)gb, (las_t)((char*)Bs + (c << 4)), 16, 0, 0);
    }
    __syncthreads();
#pragma unroll
    for (int kk = 0; kk < 2; ++kk) {
      s8v a[4], bfr[4];
#pragma unroll
      for (int m = 0; m < 4; ++m) {
        int r = wr * 64 + m * 16 + (lane & 15);
        int q = (lane >> 4) + (kk << 2);
        a[m] = *(const s8v*)((const char*)As + r * 128 + ((q ^ (r & 7)) << 4));
      }
#pragma unroll
      for (int n = 0; n < 4; ++n) {
        int r = wc * 64 + n * 16 + (lane & 15);
        int q = (lane >> 4) + (kk << 2);
        bfr[n] = *(const s8v*)((const char*)Bs + r * 128 + ((q ^ (r & 7)) << 4));
      }
#pragma unroll
      for (int m = 0; m < 4; ++m)
#pragma unroll
        for (int n = 0; n < 4; ++n)
          acc[m][n] = __builtin_amdgcn_mfma_f32_16x16x32_bf16(a[m], bfr[n], acc[m][n], 0, 0, 0);
    }
  }
  float bv[4];
#pragma unroll
  for (int n = 0; n < 4; ++n) bv[n] = bias[o0 + wc * 64 + n * 16 + (lane & 15)];
  int row_b = m0 + wr * 64 + ((lane >> 4) << 2);
  int col_b = o0 + wc * 64 + (lane & 15);
  if (o0 >= split) {
#pragma unroll
    for (int m = 0; m < 4; ++m) {
#pragma unroll
      for (int n = 0; n < 4; ++n) {
        int og = col_b + n * 16;
        short4 s4 = make_short4(f2bf(acc[m][n][0] + bv[n]), f2bf(acc[m][n][1] + bv[n]),
                                f2bf(acc[m][n][2] + bv[n]), f2bf(acc[m][n][3] + bv[n]));
        *(short4*)(tout + (size_t)(og - split) * tstride + row_b + m * 16) = s4;
      }
    }
    return;
  }
#pragma unroll
  for (int m = 0; m < 4; ++m) {
#pragma unroll
    for (int i = 0; i < 4; ++i) {
      int mg = row_b + m * 16 + i;
#pragma unroll
      for (int n = 0; n < 4; ++n) {
        int og = col_b + n * 16;
        float v = acc[m][n][i] + bv[n];
        if (og < qsplit) v *= SCL_L2E;
        ((short*)outp)[(size_t)mg * O + og] = f2bf(v);
      }
    }
  }
}

// ---------- self-attention, MFMA flash, KVBLK=128, dbuf, exp2 softmax, defer-max ----------
__global__ __launch_bounds__(TPB) void sa_attn_mfma(const short* __restrict__ qkv,
                                                    const short* __restrict__ vt,
                                                    short* __restrict__ outp) {
  __shared__ __align__(16) short Ks[2][128 * 64];
  __shared__ __align__(16) short Vs[2][64 * 128];
  __shared__ __align__(16) short Ps[4][16 * 128];
  int b = blockIdx.z, h = blockIdx.y, q0 = blockIdx.x * 64;
  int tid = threadIdx.x, lane = tid & 63, w = tid >> 6;
  int g = lane >> 4, qi = lane & 15;
  s8v qf[2];
  {
    const short* qp = qkv + (size_t)(b * 1024 + q0 + w * 16 + qi) * 1536 + h * 64 + g * 8;
    qf[0] = *(const s8v*)qp;
    qf[1] = *(const s8v*)(qp + 32);
  }
  f32x4 o[4];
#pragma unroll
  for (int d = 0; d < 4; ++d) o[d] = (f32x4){0.f, 0.f, 0.f, 0.f};
  float mrun = -1e30f, lrun = 0.f;
  const short* kbase = qkv + (size_t)(b * 1024) * 1536 + 512 + h * 64;
  const short* vbase = vt + (size_t)(h * 64) * 4096 + b * 1024;
  char* psw = (char*)Ps + w * 4096;
  int pswz = (qi & 15) << 4;

  auto stage = [&](int bufi, int kt) {
    int k0 = kt * 128;
#pragma unroll
    for (int i = 0; i < 4; ++i) {            // K: 128 rows x 8 slots
      int c = i * 256 + tid;
      int r = c >> 3, cs = c & 7, cg = cs ^ (r & 7);
      const char* gp = (const char*)(kbase + (size_t)(k0 + r) * 1536) + (cg << 4);
      __builtin_amdgcn_global_load_lds((gas_t)gp, (las_t)((char*)Ks[bufi] + (c << 4)), 16, 0, 0);
    }
#pragma unroll
    for (int i = 0; i < 4; ++i) {            // V^T: 64 rows x 16 slots
      int c = i * 256 + tid;
      int r = c >> 4, cs = c & 15, cg = cs ^ (r & 15);
      const char* gp = (const char*)(vbase + (size_t)r * 4096 + k0) + (cg << 4);
      __builtin_amdgcn_global_load_lds((gas_t)gp, (las_t)((char*)Vs[bufi] + (c << 4)), 16, 0, 0);
    }
  };

  stage(0, 0);
  __syncthreads();
  for (int kt = 0; kt < 8; ++kt) {
    int cur = kt & 1;
    if (kt < 7) stage(cur ^ 1, kt + 1);
    // S^T[key][q] = K . Q^T   (log2-domain scores)
    f32x4 st[8];
#pragma unroll
    for (int t = 0; t < 8; ++t) st[t] = (f32x4){0.f, 0.f, 0.f, 0.f};
    __builtin_amdgcn_s_setprio(1);
#pragma unroll
    for (int s = 0; s < 2; ++s) {
#pragma unroll
      for (int t = 0; t < 8; ++t) {
        int r = t * 16 + qi;
        s8v kf = *(const s8v*)((const char*)Ks[cur] + r * 128 + (((s * 4 + g) ^ (r & 7)) << 4));
        st[t] = __builtin_amdgcn_mfma_f32_16x16x32_bf16(kf, qf[s], st[t], 0, 0, 0);
      }
    }
    __builtin_amdgcn_s_setprio(0);
    float sv[32];
#pragma unroll
    for (int t = 0; t < 8; ++t)
#pragma unroll
      for (int r2 = 0; r2 < 4; ++r2) sv[t * 4 + r2] = st[t][r2];
    float mx = sv[0];
#pragma unroll
    for (int i = 1; i < 32; ++i) mx = fmaxf(mx, sv[i]);
    mx = fmaxf(mx, __shfl_xor(mx, 16));
    mx = fmaxf(mx, __shfl_xor(mx, 32));
    // defer-max (T13): skip O-rescale when tile max grew by <= 11 (log2 units)
    if (!__all(mx - mrun <= 11.f)) {
      float mnew = fmaxf(mrun, mx);
      float scale = exp2f(mrun - mnew);
      lrun *= scale;
#pragma unroll
      for (int d = 0; d < 4; ++d) o[d] *= scale;
      mrun = mnew;
    }
    float psum = 0.f;
#pragma unroll
    for (int i = 0; i < 32; ++i) { sv[i] = exp2f(sv[i] - mrun); psum += sv[i]; }
    psum += __shfl_xor(psum, 16);
    psum += __shfl_xor(psum, 32);
    lrun += psum;
#pragma unroll
    for (int t = 0; t < 8; ++t) {
      short4 pk = make_short4(f2bf(sv[t * 4]), f2bf(sv[t * 4 + 1]),
                              f2bf(sv[t * 4 + 2]), f2bf(sv[t * 4 + 3]));
      *(short4*)(psw + qi * 256 + ((t * 32 + g * 8) ^ pswz)) = pk;
    }
    __builtin_amdgcn_s_setprio(1);
#pragma unroll
    for (int s = 0; s < 4; ++s) {
      s8v bf = *(const s8v*)(psw + qi * 256 + ((s * 64 + g * 16) ^ pswz));
#pragma unroll
      for (int d = 0; d < 4; ++d) {
        int r = d * 16 + qi;
        s8v af = *(const s8v*)((const char*)Vs[cur] + r * 256 + (((s * 4 + g) ^ (r & 15)) << 4));
        o[d] = __builtin_amdgcn_mfma_f32_16x16x32_bf16(af, bf, o[d], 0, 0, 0);
      }
    }
    __builtin_amdgcn_s_setprio(0);
    __syncthreads();
  }
  float rl = 1.f / lrun;
  short* ob = outp + (size_t)(b * 1024 + q0 + w * 16 + qi) * 512 + h * 64;
#pragma unroll
  for (int d = 0; d < 4; ++d) {
    short4 s4 = make_short4(f2bf(o[d][0] * rl), f2bf(o[d][1] * rl),
                            f2bf(o[d][2] * rl), f2bf(o[d][3] * rl));
    *(short4*)(ob + d * 16 + g * 4) = s4;
  }
}

// ---------- cross-attention, MFMA single-pass (q pre-scaled, exp2) ----------
__global__ __launch_bounds__(TPB) void ca_attn_mfma(const short* __restrict__ qb,
                                                    const short* __restrict__ kvb,
                                                    const short* __restrict__ cavt,
                                                    short* __restrict__ outp) {
  __shared__ __align__(16) short Ks[96 * 64];
  __shared__ __align__(16) short Vs[64 * 128];
  __shared__ __align__(16) short Ps[4][16 * 128];
  int b = blockIdx.z, h = blockIdx.y, q0 = blockIdx.x * 64;
  int tid = threadIdx.x, lane = tid & 63, w = tid >> 6;
  int g = lane >> 4, qi = lane & 15;
  s8v qf[2];
  {
    const short* qp = qb + (size_t)(b * 1024 + q0 + w * 16 + qi) * 512 + h * 64 + g * 8;
    qf[0] = *(const s8v*)qp;
    qf[1] = *(const s8v*)(qp + 32);
  }
  const short* kbase = kvb + (size_t)(b * 96) * 1024 + h * 64;
#pragma unroll
  for (int i = 0; i < 3; ++i) {
    int c = i * 256 + tid;
    int r = c >> 3, cs = c & 7, cg = cs ^ (r & 7);
    const char* gp = (const char*)(kbase + (size_t)r * 1024) + (cg << 4);
    __builtin_amdgcn_global_load_lds((gas_t)gp, (las_t)((char*)Ks + (c << 4)), 16, 0, 0);
  }
#pragma unroll
  for (int i = 0; i < 3; ++i) {
    int c = i * 256 + tid;
    int r = c / 12, jj = c - r * 12;
    int4 dv = *(const int4*)(cavt + (size_t)(h * 64 + r) * 384 + b * 96 + jj * 8);
    *(int4*)((char*)Vs + r * 256 + ((jj * 16) ^ ((r & 7) << 4))) = dv;
  }
  __syncthreads();
  f32x4 st[6];
#pragma unroll
  for (int t = 0; t < 6; ++t) st[t] = (f32x4){0.f, 0.f, 0.f, 0.f};
  __builtin_amdgcn_s_setprio(1);
#pragma unroll
  for (int s = 0; s < 2; ++s) {
#pragma unroll
    for (int t = 0; t < 6; ++t) {
      int r = t * 16 + qi;
      s8v kf = *(const s8v*)((const char*)Ks + r * 128 + (((s * 4 + g) ^ (r & 7)) << 4));
      st[t] = __builtin_amdgcn_mfma_f32_16x16x32_bf16(kf, qf[s], st[t], 0, 0, 0);
    }
  }
  __builtin_amdgcn_s_setprio(0);
  float sv[24];
#pragma unroll
  for (int t = 0; t < 6; ++t)
#pragma unroll
    for (int r2 = 0; r2 < 4; ++r2) {
      int key = t * 16 + g * 4 + r2;
      sv[t * 4 + r2] = (key < SEQ) ? st[t][r2] : -1e30f;
    }
  float mx = sv[0];
#pragma unroll
  for (int i = 1; i < 24; ++i) mx = fmaxf(mx, sv[i]);
  mx = fmaxf(mx, __shfl_xor(mx, 16));
  mx = fmaxf(mx, __shfl_xor(mx, 32));
  float l = 0.f;
#pragma unroll
  for (int i = 0; i < 24; ++i) { sv[i] = exp2f(sv[i] - mx); l += sv[i]; }
  l += __shfl_xor(l, 16);
  l += __shfl_xor(l, 32);
  char* psw = (char*)Ps + w * 4096;
  int pswz = (qi & 7) << 4;
#pragma unroll
  for (int t = 0; t < 6; ++t) {
    short4 pk = make_short4(f2bf(sv[t * 4]), f2bf(sv[t * 4 + 1]),
                            f2bf(sv[t * 4 + 2]), f2bf(sv[t * 4 + 3]));
    *(short4*)(psw + qi * 256 + ((t * 32 + g * 8) ^ pswz)) = pk;
  }
  f32x4 o[4];
#pragma unroll
  for (int d = 0; d < 4; ++d) o[d] = (f32x4){0.f, 0.f, 0.f, 0.f};
  __builtin_amdgcn_s_setprio(1);
#pragma unroll
  for (int s = 0; s < 3; ++s) {
    s8v bf = *(const s8v*)(psw + qi * 256 + ((s * 64 + g * 16) ^ pswz));
#pragma unroll
    for (int d = 0; d < 4; ++d) {
      int r = d * 16 + qi;
      s8v af = *(const s8v*)((const char*)Vs + r * 256 + (((s * 64 + g * 16) ^ ((r & 7) << 4))));
      o[d] = __builtin_amdgcn_mfma_f32_16x16x32_bf16(af, bf, o[d], 0, 0, 0);
    }
  }
  __builtin_amdgcn_s_setprio(0);
  float rl = 1.f / l;
  short* ob = outp + (size_t)(b * 1024 + q0 + w * 16 + qi) * 512 + h * 64;
#pragma unroll
  for (int d = 0; d < 4; ++d) {
    short4 s4 = make_short4(f2bf(o[d][0] * rl), f2bf(o[d][1] * rl),
                            f2bf(o[d][2] * rl), f2bf(o[d][3] * rl));
    *(short4*)(ob + d * 16 + g * 4) = s4;
  }
}

extern "C" void kernel_launch(void* const* d_in, const int* in_sizes, int n_in,
                              void* d_out, int out_size, void* d_ws, size_t ws_size,
                              hipStream_t stream) {
  const float* x        = (const float*)d_in[0];
  const float* context  = (const float*)d_in[1];
  const float* sa_nw    = (const float*)d_in[2];
  const float* sa_nb    = (const float*)d_in[3];
  const float* sa_qkv_w = (const float*)d_in[4];
  const float* sa_qkv_b = (const float*)d_in[5];
  const float* sa_pw    = (const float*)d_in[6];
  const float* sa_pb    = (const float*)d_in[7];
  const float* ca_nw    = (const float*)d_in[8];
  const float* ca_nb    = (const float*)d_in[9];
  const float* ca_qw    = (const float*)d_in[10];
  const float* ca_qb    = (const float*)d_in[11];
  const float* ca_kvw   = (const float*)d_in[12];
  const float* ca_kvb   = (const float*)d_in[13];
  const float* ca_pw    = (const float*)d_in[14];
  const float* ca_pb    = (const float*)d_in[15];
  const float* ff_nw    = (const float*)d_in[16];
  const float* ff_nb    = (const float*)d_in[17];
  const float* ff_w1    = (const float*)d_in[18];
  const float* ff_b1    = (const float*)d_in[19];
  const float* ff_w2    = (const float*)d_in[20];
  const float* ff_b2    = (const float*)d_in[21];
  float* outp = (float*)d_out;

  char* ws = (char*)d_ws;
  float*  xcur  = (float*)(ws);                          // [0,8M)  residual stream (cm f32)
  short*  hb    = (short*)(ws + (8u << 20));             // [8,12M) GN out / attn out (bf16 tm)
  short*  big   = (short*)(ws + (12u << 20));            // [12,28M) qkvb / qb / h1
  short*  qkvb  = big;
  short*  qb    = big;
  short*  h1    = big;
  short*  vt    = (short*)(ws + (28u << 20));            // [28,32M) V^T [512][4096]
  short*  kvb   = (short*)(ws + (32u << 20));            // 768KB
  short*  cavt  = (short*)(ws + (33u << 20));            // 384KB [512][384]
  short*  ctxb  = (short*)(ws + (34u << 20));            // 576KB
  float2* statsPart = (float2*)(ws + (35u << 20));       // [32][8] partials (SA)
  float2* statsCA   = statsPart + 256;                   // 32 raw sums (CA)
  float2* statsFFN  = statsPart + 288;                   // 32 raw sums (FFN)
  short*  wb    = (short*)(ws + (36u << 20));            // bf16 weights (~8.7MB)

  short* w_qkv = wb;
  short* w_sap = wb + 786432;
  short* w_caq = wb + 1048576;
  short* w_kv  = wb + 1310720;
  short* w_cap = wb + 2097152;
  short* w_f1  = wb + 2359296;
  short* w_f2  = wb + 3407872;

  dim3 blk(TPB);
  prep<<<4896, blk, 0, stream>>>(sa_qkv_w, sa_pw, ca_qw, ca_kvw, ca_pw, ff_w1, ff_w2, wb,
                                 context, ctxb, x, statsPart, statsCA, statsFFN);

  // ---- self-attention (+ merged CA kv projection) ----
  gn_apply<<<dim3(16, 32), blk, 0, stream>>>(x, sa_nw, sa_nb, statsPart, hb, 8);
  gemm_qkvkv<<<408, blk, 0, stream>>>(hb, w_qkv, sa_qkv_b, ctxb, w_kv, ca_kvb,
                                      qkvb, vt, kvb, cavt);
  sa_attn_mfma<<<dim3(16, 8, 4), blk, 0, stream>>>(qkvb, vt, hb);
  gemm_nt<128, 64, 1><<<dim3(32, 8), blk, 0, stream>>>(hb, w_sap, sa_pb, x, xcur, 512, 512, 1.f, statsCA);

  // ---- cross-attention ----
  gn_apply<<<dim3(16, 32), blk, 0, stream>>>(xcur, ca_nw, ca_nb, statsCA, hb, 1);
  gemm_nt<128, 64, 0><<<dim3(32, 8), blk, 0, stream>>>(hb, w_caq, ca_qb, nullptr, qb, 512, 512, SCL_L2E, nullptr);
  ca_attn_mfma<<<dim3(16, 8, 4), blk, 0, stream>>>(qb, kvb, cavt, hb);
  gemm_nt<128, 64, 1><<<dim3(32, 8), blk, 0, stream>>>(hb, w_cap, ca_pb, xcur, xcur, 512, 512, 1.f, statsFFN);

  // ---- FFN ----
  gn_apply<<<dim3(16, 32), blk, 0, stream>>>(xcur, ff_nw, ff_nb, statsFFN, hb, 1);
  gemm_nt<128, 128, 2><<<dim3(32, 16), blk, 0, stream>>>(hb, w_f1, ff_b1, nullptr, h1, 512, 2048, 1.f, nullptr);
  gemm_nt<128, 64, 1><<<dim3(32, 8), blk, 0, stream>>>(h1, w_f2, ff_b2, xcur, outp, 2048, 512, 1.f, nullptr);
}

// Round 8
// 166.054 us; speedup vs baseline: 6.6900x; 1.0179x over previous
//
#include <hip/hip_runtime.h>
#include <hip/hip_bf16.h>

#define TPB 256
#define Bsz 4
#define Nsp 1024
#define Cch 512
#define SEQ 77
#define CTX 768
#define EPSV 1e-5f
#define MTOK 4096   // B * N
#define SCL_L2E 0.18033688011111834f   // 0.125 * log2(e)

typedef __attribute__((ext_vector_type(8))) short s8v;
typedef __attribute__((ext_vector_type(4))) float f32x4;
typedef const __attribute__((address_space(1))) void* gas_t;
typedef __attribute__((address_space(3))) void* las_t;

static __device__ __forceinline__ float bf2f(short s) {
  union { unsigned u; float f; } z; z.u = ((unsigned)(unsigned short)s) << 16; return z.f;
}
static __device__ __forceinline__ short f2bf(float f) {
  union { __hip_bfloat16 h; short s; } u;
  u.h = __float2bfloat16(f);
  return u.s;
}

// ---------- prep: weight/ctx convert + SA gn partial stats + stats zero ----------
__global__ __launch_bounds__(TPB) void prep(const float* a0, const float* a1,
                                            const float* a2, const float* a3,
                                            const float* a4, const float* a5,
                                            const float* a6, short* __restrict__ wdst,
                                            const float* __restrict__ ctx,
                                            short* __restrict__ cdst,
                                            const float* __restrict__ x,
                                            float2* __restrict__ statsPart,
                                            float2* __restrict__ statsCA,
                                            float2* __restrict__ statsFFN) {
  int blk = blockIdx.x;
  int tid = threadIdx.x;
  if (blk < 4352) {
    int u = blk * TPB + tid;
    const float* src; int base;
    if      (u < 196608) { src = a0; base = 0; }
    else if (u < 262144) { src = a1; base = 196608; }
    else if (u < 327680) { src = a2; base = 262144; }
    else if (u < 524288) { src = a3; base = 327680; }
    else if (u < 589824) { src = a4; base = 524288; }
    else if (u < 851968) { src = a5; base = 589824; }
    else                 { src = a6; base = 851968; }
    float4 v = *(const float4*)(src + (size_t)(u - base) * 4);
    short4 o = make_short4(f2bf(v.x), f2bf(v.y), f2bf(v.z), f2bf(v.w));
    *(short4*)(wdst + (size_t)u * 4) = o;
    return;
  }
  if (blk < 4640) {
    int u = (blk - 4352) * TPB + tid;
    int row = u / 192, c4 = u - row * 192;
    int b = row / 96, s_ = row - b * 96;
    short4 o;
    if (s_ < SEQ) {
      float4 v = *(const float4*)(ctx + ((size_t)(b * SEQ + s_)) * CTX + c4 * 4);
      o = make_short4(f2bf(v.x), f2bf(v.y), f2bf(v.z), f2bf(v.w));
    } else {
      o = make_short4(0, 0, 0, 0);
    }
    *(short4*)(cdst + (size_t)row * CTX + c4 * 4) = o;
    return;
  }
  int idx = blk - 4640;
  int bg = idx >> 3, part = idx & 7;
  const float* base = x + (size_t)bg * 65536 + part * 8192;
  float s = 0.f, s2 = 0.f;
#pragma unroll
  for (int it = 0; it < 8; ++it) {
    float4 v = ((const float4*)base)[it * 256 + tid];
    s += v.x + v.y + v.z + v.w;
    s2 += v.x * v.x + v.y * v.y + v.z * v.z + v.w * v.w;
  }
  for (int off = 1; off < 64; off <<= 1) {
    s += __shfl_xor(s, off, 64);
    s2 += __shfl_xor(s2, off, 64);
  }
  __shared__ float red[2][4];
  int wid = tid >> 6;
  if ((tid & 63) == 0) { red[0][wid] = s; red[1][wid] = s2; }
  __syncthreads();
  if (tid == 0) {
    float S = red[0][0] + red[0][1] + red[0][2] + red[0][3];
    float S2 = red[1][0] + red[1][1] + red[1][2] + red[1][3];
    statsPart[idx] = make_float2(S, S2);
  } else if (tid == 1 && part == 0) {
    statsCA[bg] = make_float2(0.f, 0.f);
  } else if (tid == 2 && part == 0) {
    statsFFN[bg] = make_float2(0.f, 0.f);
  }
}

// ---------- GroupNorm apply + transpose: [B,C,N] f32 -> token-major bf16 [4096,512] ----------
__global__ __launch_bounds__(TPB) void gn_apply(const float* __restrict__ x,
                                                const float* __restrict__ w,
                                                const float* __restrict__ bb,
                                                const float2* __restrict__ stats,
                                                short* __restrict__ outp,
                                                int npart) {
  int t = blockIdx.x, bg = blockIdx.y;
  int b = bg >> 3, g = bg & 7;
  float S = 0.f, S2 = 0.f;
  for (int p = 0; p < npart; ++p) {
    float2 st = stats[bg * npart + p];
    S += st.x; S2 += st.y;
  }
  const float inv = 1.f / 65536.f;
  float mu = S * inv;
  float var = S2 * inv - mu * mu;
  float rstd = rsqrtf(var + EPSV);
  __shared__ float tile[64][65];
  int tid = threadIdx.x;
  int n0 = t * 64;
  const float* p = x + (size_t)bg * 65536;
#pragma unroll
  for (int it = 0; it < 4; ++it) {
    int idx = it * 256 + tid;
    int c = idx >> 4, n4 = (idx & 15) * 4;
    float4 v = *(const float4*)(p + (size_t)c * 1024 + n0 + n4);
    float wc = w[g * 64 + c] * rstd;
    float bc = bb[g * 64 + c] - mu * wc;
    tile[c][n4 + 0] = v.x * wc + bc;
    tile[c][n4 + 1] = v.y * wc + bc;
    tile[c][n4 + 2] = v.z * wc + bc;
    tile[c][n4 + 3] = v.w * wc + bc;
  }
  __syncthreads();
  int n = tid >> 2, cs = (tid & 3) * 16;
  short ob[16];
#pragma unroll
  for (int j = 0; j < 16; ++j) ob[j] = f2bf(tile[cs + j][n]);
  short* op = outp + (size_t)(b * 1024 + n0 + n) * 512 + g * 64 + cs;
  *(int4*)op = *(int4*)&ob[0];
  *(int4*)(op + 8) = *(int4*)&ob[8];
}

// ---------- bf16 MFMA NT-GEMM, 2-phase double-buffered staging ----------
// MODE 0: bf16 tm out, scaled by oscale
// MODE 1: f32 channel-major out [B,O,1024] + cm f32 residual; optional stats accumulation
// MODE 2: gelu -> bf16 tm out
template<int BM, int BN, int MODE>
__global__ __launch_bounds__(TPB) void gemm_nt(const short* __restrict__ A,
                                               const short* __restrict__ Bw,
                                               const float* __restrict__ bias,
                                               const float* __restrict__ resid,
                                               void* __restrict__ outp,
                                               int K, int O,
                                               float oscale,
                                               float2* __restrict__ stats_out) {
  const int FM = BM / 32, FN = BN / 32;
  __shared__ __align__(16) short As[2][BM * 64];
  __shared__ __align__(16) short Bs[2][BN * 64];
  int tid = threadIdx.x;
  int lane = tid & 63, w = tid >> 6;
  int wr = w >> 1, wc = w & 1;
  int m0 = blockIdx.x * BM, o0 = blockIdx.y * BN;
  f32x4 acc[FM][FN];
#pragma unroll
  for (int i = 0; i < FM; ++i)
#pragma unroll
    for (int j = 0; j < FN; ++j) acc[i][j] = (f32x4){0.f, 0.f, 0.f, 0.f};
  int nk = K >> 6;

  auto stage = [&](int bi, int kt) {
    int k0 = kt << 6;
#pragma unroll
    for (int i = 0; i < BM / 32; ++i) {
      int c = i * 256 + tid;
      int r = c >> 3, qs = c & 7, qg = qs ^ (r & 7);
      const char* ga = (const char*)(A + ((size_t)(m0 + r) * K + k0)) + (qg << 4);
      __builtin_amdgcn_global_load_lds((gas_t)ga, (las_t)((char*)As[bi] + (c << 4)), 16, 0, 0);
    }
#pragma unroll
    for (int i = 0; i < BN / 32; ++i) {
      int c = i * 256 + tid;
      int r = c >> 3, qs = c & 7, qg = qs ^ (r & 7);
      const char* gb = (const char*)(Bw + ((size_t)(o0 + r) * K + k0)) + (qg << 4);
      __builtin_amdgcn_global_load_lds((gas_t)gb, (las_t)((char*)Bs[bi] + (c << 4)), 16, 0, 0);
    }
  };

  stage(0, 0);
  __syncthreads();
  for (int kt = 0; kt < nk; ++kt) {
    int cur = kt & 1;
    if (kt + 1 < nk) stage(cur ^ 1, kt + 1);
#pragma unroll
    for (int kk = 0; kk < 2; ++kk) {
      s8v a[FM], bfr[FN];
#pragma unroll
      for (int m = 0; m < FM; ++m) {
        int r = wr * (BM / 2) + m * 16 + (lane & 15);
        int q = (lane >> 4) + (kk << 2);
        a[m] = *(const s8v*)((const char*)As[cur] + r * 128 + ((q ^ (r & 7)) << 4));
      }
#pragma unroll
      for (int n = 0; n < FN; ++n) {
        int r = wc * (BN / 2) + n * 16 + (lane & 15);
        int q = (lane >> 4) + (kk << 2);
        bfr[n] = *(const s8v*)((const char*)Bs[cur] + r * 128 + ((q ^ (r & 7)) << 4));
      }
#pragma unroll
      for (int m = 0; m < FM; ++m)
#pragma unroll
        for (int n = 0; n < FN; ++n)
          acc[m][n] = __builtin_amdgcn_mfma_f32_16x16x32_bf16(a[m], bfr[n], acc[m][n], 0, 0, 0);
    }
    __syncthreads();
  }
  float bv[FN];
#pragma unroll
  for (int n = 0; n < FN; ++n) bv[n] = bias[o0 + wc * (BN / 2) + n * 16 + (lane & 15)];
  int row_b = m0 + wr * (BM / 2) + ((lane >> 4) << 2);
  int col_b = o0 + wc * (BN / 2) + (lane & 15);
  if (MODE == 1) {
    float ls = 0.f, ls2 = 0.f;
#pragma unroll
    for (int m = 0; m < FM; ++m) {
      int t0 = row_b + m * 16;
      int b = t0 >> 10, n_ = t0 & 1023;
#pragma unroll
      for (int n = 0; n < FN; ++n) {
        int og = col_b + n * 16;
        size_t idx = ((size_t)(b * O + og)) * 1024 + n_;
        float4 rv = *(const float4*)(resid + idx);
        float4 ov;
        ov.x = acc[m][n][0] + bv[n] + rv.x;
        ov.y = acc[m][n][1] + bv[n] + rv.y;
        ov.z = acc[m][n][2] + bv[n] + rv.z;
        ov.w = acc[m][n][3] + bv[n] + rv.w;
        *(float4*)((float*)outp + idx) = ov;
        ls += ov.x + ov.y + ov.z + ov.w;
        ls2 += ov.x * ov.x + ov.y * ov.y + ov.z * ov.z + ov.w * ov.w;
      }
    }
    if (stats_out != nullptr) {
      float s = ls, s2 = ls2;
      for (int off = 1; off < 64; off <<= 1) {
        s += __shfl_xor(s, off, 64);
        s2 += __shfl_xor(s2, off, 64);
      }
      __syncthreads();
      float* red = (float*)As;
      if (lane == 0) { red[w * 2] = s; red[w * 2 + 1] = s2; }
      __syncthreads();
      if (tid == 0) {
        float S = red[0] + red[2] + red[4] + red[6];
        float S2 = red[1] + red[3] + red[5] + red[7];
        int bg = (m0 >> 10) * 8 + (o0 >> 6);
        atomicAdd((float*)stats_out + bg * 2, S);
        atomicAdd((float*)stats_out + bg * 2 + 1, S2);
      }
    }
    return;
  }
#pragma unroll
  for (int m = 0; m < FM; ++m) {
#pragma unroll
    for (int i = 0; i < 4; ++i) {
      int mg = row_b + m * 16 + i;
#pragma unroll
      for (int n = 0; n < FN; ++n) {
        int og = col_b + n * 16;
        float v = acc[m][n][i] + bv[n];
        size_t idx = (size_t)mg * O + og;
        if (MODE == 2) {
          float gv = 0.5f * v * (1.f + erff(v * 0.70710678118654752f));
          ((short*)outp)[idx] = f2bf(gv);
        } else {
          ((short*)outp)[idx] = f2bf(v * oscale);
        }
      }
    }
  }
}

// ---------- merged qkv + ca_kv GEMM, 2-phase dbuf: 408 blocks, 128x128 tiles ----------
__global__ __launch_bounds__(TPB) void gemm_qkvkv(
    const short* __restrict__ hb, const short* __restrict__ wqkv, const float* __restrict__ bqkv,
    const short* __restrict__ ctxb, const short* __restrict__ wkv, const float* __restrict__ bkv,
    short* __restrict__ qkvb, short* __restrict__ vt,
    short* __restrict__ kvb, short* __restrict__ cavt) {
  __shared__ __align__(16) short As[2][128 * 64];
  __shared__ __align__(16) short Bs[2][128 * 64];
  int bid = blockIdx.x;
  const short *A, *Bw; const float* bias;
  short *outp, *tout;
  int K, O, m0, o0, split, tstride, qsplit;
  if (bid < 384) {
    A = hb; Bw = wqkv; bias = bqkv; outp = qkvb; tout = vt;
    K = 512; O = 1536; split = 1024; tstride = 4096; qsplit = 512;
    m0 = (bid & 31) * 128; o0 = (bid >> 5) * 128;
  } else {
    int idx = bid - 384;
    A = ctxb; Bw = wkv; bias = bkv; outp = kvb; tout = cavt;
    K = 768; O = 1024; split = 512; tstride = 384; qsplit = 0;
    m0 = (idx % 3) * 128; o0 = (idx / 3) * 128;
  }
  int tid = threadIdx.x;
  int lane = tid & 63, w = tid >> 6;
  int wr = w >> 1, wc = w & 1;
  f32x4 acc[4][4];
#pragma unroll
  for (int i = 0; i < 4; ++i)
#pragma unroll
    for (int j = 0; j < 4; ++j) acc[i][j] = (f32x4){0.f, 0.f, 0.f, 0.f};
  int nk = K >> 6;

  auto stage = [&](int bi, int kt) {
    int k0 = kt << 6;
#pragma unroll
    for (int i = 0; i < 4; ++i) {
      int c = i * 256 + tid;
      int r = c >> 3, qs = c & 7, qg = qs ^ (r & 7);
      const char* ga = (const char*)(A + ((size_t)(m0 + r) * K + k0)) + (qg << 4);
      __builtin_amdgcn_global_load_lds((gas_t)ga, (las_t)((char*)As[bi] + (c << 4)), 16, 0, 0);
    }
#pragma unroll
    for (int i = 0; i < 4; ++i) {
      int c = i * 256 + tid;
      int r = c >> 3, qs = c & 7, qg = qs ^ (r & 7);
      const char* gb = (const char*)(Bw + ((size_t)(o0 + r) * K + k0)) + (qg << 4);
      __builtin_amdgcn_global_load_lds((gas_t)gb, (las_t)((char*)Bs[bi] + (c << 4)), 16, 0, 0);
    }
  };

  stage(0, 0);
  __syncthreads();
  for (int kt = 0; kt < nk; ++kt) {
    int cur = kt & 1;
    if (kt + 1 < nk) stage(cur ^ 1, kt + 1);
#pragma unroll
    for (int kk = 0; kk < 2; ++kk) {
      s8v a[4], bfr[4];
#pragma unroll
      for (int m = 0; m < 4; ++m) {
        int r = wr * 64 + m * 16 + (lane & 15);
        int q = (lane >> 4) + (kk << 2);
        a[m] = *(const s8v*)((const char*)As[cur] + r * 128 + ((q ^ (r & 7)) << 4));
      }
#pragma unroll
      for (int n = 0; n < 4; ++n) {
        int r = wc * 64 + n * 16 + (lane & 15);
        int q = (lane >> 4) + (kk << 2);
        bfr[n] = *(const s8v*)((const char*)Bs[cur] + r * 128 + ((q ^ (r & 7)) << 4));
      }
#pragma unroll
      for (int m = 0; m < 4; ++m)
#pragma unroll
        for (int n = 0; n < 4; ++n)
          acc[m][n] = __builtin_amdgcn_mfma_f32_16x16x32_bf16(a[m], bfr[n], acc[m][n], 0, 0, 0);
    }
    __syncthreads();
  }
  float bv[4];
#pragma unroll
  for (int n = 0; n < 4; ++n) bv[n] = bias[o0 + wc * 64 + n * 16 + (lane & 15)];
  int row_b = m0 + wr * 64 + ((lane >> 4) << 2);
  int col_b = o0 + wc * 64 + (lane & 15);
  if (o0 >= split) {
#pragma unroll
    for (int m = 0; m < 4; ++m) {
#pragma unroll
      for (int n = 0; n < 4; ++n) {
        int og = col_b + n * 16;
        short4 s4 = make_short4(f2bf(acc[m][n][0] + bv[n]), f2bf(acc[m][n][1] + bv[n]),
                                f2bf(acc[m][n][2] + bv[n]), f2bf(acc[m][n][3] + bv[n]));
        *(short4*)(tout + (size_t)(og - split) * tstride + row_b + m * 16) = s4;
      }
    }
    return;
  }
#pragma unroll
  for (int m = 0; m < 4; ++m) {
#pragma unroll
    for (int i = 0; i < 4; ++i) {
      int mg = row_b + m * 16 + i;
#pragma unroll
      for (int n = 0; n < 4; ++n) {
        int og = col_b + n * 16;
        float v = acc[m][n][i] + bv[n];
        if (og < qsplit) v *= SCL_L2E;
        ((short*)outp)[(size_t)mg * O + og] = f2bf(v);
      }
    }
  }
}

// ---------- self-attention, MFMA flash, KVBLK=128, dbuf, exp2 softmax, defer-max ----------
__global__ __launch_bounds__(TPB) void sa_attn_mfma(const short* __restrict__ qkv,
                                                    const short* __restrict__ vt,
                                                    short* __restrict__ outp) {
  __shared__ __align__(16) short Ks[2][128 * 64];
  __shared__ __align__(16) short Vs[2][64 * 128];
  __shared__ __align__(16) short Ps[4][16 * 128];
  int b = blockIdx.z, h = blockIdx.y, q0 = blockIdx.x * 64;
  int tid = threadIdx.x, lane = tid & 63, w = tid >> 6;
  int g = lane >> 4, qi = lane & 15;
  s8v qf[2];
  {
    const short* qp = qkv + (size_t)(b * 1024 + q0 + w * 16 + qi) * 1536 + h * 64 + g * 8;
    qf[0] = *(const s8v*)qp;
    qf[1] = *(const s8v*)(qp + 32);
  }
  f32x4 o[4];
#pragma unroll
  for (int d = 0; d < 4; ++d) o[d] = (f32x4){0.f, 0.f, 0.f, 0.f};
  float mrun = -1e30f, lrun = 0.f;
  const short* kbase = qkv + (size_t)(b * 1024) * 1536 + 512 + h * 64;
  const short* vbase = vt + (size_t)(h * 64) * 4096 + b * 1024;
  char* psw = (char*)Ps + w * 4096;
  int pswz = (qi & 15) << 4;

  auto stage = [&](int bufi, int kt) {
    int k0 = kt * 128;
#pragma unroll
    for (int i = 0; i < 4; ++i) {
      int c = i * 256 + tid;
      int r = c >> 3, cs = c & 7, cg = cs ^ (r & 7);
      const char* gp = (const char*)(kbase + (size_t)(k0 + r) * 1536) + (cg << 4);
      __builtin_amdgcn_global_load_lds((gas_t)gp, (las_t)((char*)Ks[bufi] + (c << 4)), 16, 0, 0);
    }
#pragma unroll
    for (int i = 0; i < 4; ++i) {
      int c = i * 256 + tid;
      int r = c >> 4, cs = c & 15, cg = cs ^ (r & 15);
      const char* gp = (const char*)(vbase + (size_t)r * 4096 + k0) + (cg << 4);
      __builtin_amdgcn_global_load_lds((gas_t)gp, (las_t)((char*)Vs[bufi] + (c << 4)), 16, 0, 0);
    }
  };

  stage(0, 0);
  __syncthreads();
  for (int kt = 0; kt < 8; ++kt) {
    int cur = kt & 1;
    if (kt < 7) stage(cur ^ 1, kt + 1);
    f32x4 st[8];
#pragma unroll
    for (int t = 0; t < 8; ++t) st[t] = (f32x4){0.f, 0.f, 0.f, 0.f};
    __builtin_amdgcn_s_setprio(1);
#pragma unroll
    for (int s = 0; s < 2; ++s) {
#pragma unroll
      for (int t = 0; t < 8; ++t) {
        int r = t * 16 + qi;
        s8v kf = *(const s8v*)((const char*)Ks[cur] + r * 128 + (((s * 4 + g) ^ (r & 7)) << 4));
        st[t] = __builtin_amdgcn_mfma_f32_16x16x32_bf16(kf, qf[s], st[t], 0, 0, 0);
      }
    }
    __builtin_amdgcn_s_setprio(0);
    float sv[32];
#pragma unroll
    for (int t = 0; t < 8; ++t)
#pragma unroll
      for (int r2 = 0; r2 < 4; ++r2) sv[t * 4 + r2] = st[t][r2];
    float mx = sv[0];
#pragma unroll
    for (int i = 1; i < 32; ++i) mx = fmaxf(mx, sv[i]);
    mx = fmaxf(mx, __shfl_xor(mx, 16));
    mx = fmaxf(mx, __shfl_xor(mx, 32));
    if (!__all(mx - mrun <= 11.f)) {
      float mnew = fmaxf(mrun, mx);
      float scale = exp2f(mrun - mnew);
      lrun *= scale;
#pragma unroll
      for (int d = 0; d < 4; ++d) o[d] *= scale;
      mrun = mnew;
    }
    float psum = 0.f;
#pragma unroll
    for (int i = 0; i < 32; ++i) { sv[i] = exp2f(sv[i] - mrun); psum += sv[i]; }
    psum += __shfl_xor(psum, 16);
    psum += __shfl_xor(psum, 32);
    lrun += psum;
#pragma unroll
    for (int t = 0; t < 8; ++t) {
      short4 pk = make_short4(f2bf(sv[t * 4]), f2bf(sv[t * 4 + 1]),
                              f2bf(sv[t * 4 + 2]), f2bf(sv[t * 4 + 3]));
      *(short4*)(psw + qi * 256 + ((t * 32 + g * 8) ^ pswz)) = pk;
    }
    __builtin_amdgcn_s_setprio(1);
#pragma unroll
    for (int s = 0; s < 4; ++s) {
      s8v bf = *(const s8v*)(psw + qi * 256 + ((s * 64 + g * 16) ^ pswz));
#pragma unroll
      for (int d = 0; d < 4; ++d) {
        int r = d * 16 + qi;
        s8v af = *(const s8v*)((const char*)Vs[cur] + r * 256 + (((s * 4 + g) ^ (r & 15)) << 4));
        o[d] = __builtin_amdgcn_mfma_f32_16x16x32_bf16(af, bf, o[d], 0, 0, 0);
      }
    }
    __builtin_amdgcn_s_setprio(0);
    __syncthreads();
  }
  float rl = 1.f / lrun;
  short* ob = outp + (size_t)(b * 1024 + q0 + w * 16 + qi) * 512 + h * 64;
#pragma unroll
  for (int d = 0; d < 4; ++d) {
    short4 s4 = make_short4(f2bf(o[d][0] * rl), f2bf(o[d][1] * rl),
                            f2bf(o[d][2] * rl), f2bf(o[d][3] * rl));
    *(short4*)(ob + d * 16 + g * 4) = s4;
  }
}

// ---------- cross-attention, MFMA single-pass (q pre-scaled, exp2) ----------
__global__ __launch_bounds__(TPB) void ca_attn_mfma(const short* __restrict__ qb,
                                                    const short* __restrict__ kvb,
                                                    const short* __restrict__ cavt,
                                                    short* __restrict__ outp) {
  __shared__ __align__(16) short Ks[96 * 64];
  __shared__ __align__(16) short Vs[64 * 128];
  __shared__ __align__(16) short Ps[4][16 * 128];
  int b = blockIdx.z, h = blockIdx.y, q0 = blockIdx.x * 64;
  int tid = threadIdx.x, lane = tid & 63, w = tid >> 6;
  int g = lane >> 4, qi = lane & 15;
  s8v qf[2];
  {
    const short* qp = qb + (size_t)(b * 1024 + q0 + w * 16 + qi) * 512 + h * 64 + g * 8;
    qf[0] = *(const s8v*)qp;
    qf[1] = *(const s8v*)(qp + 32);
  }
  const short* kbase = kvb + (size_t)(b * 96) * 1024 + h * 64;
#pragma unroll
  for (int i = 0; i < 3; ++i) {
    int c = i * 256 + tid;
    int r = c >> 3, cs = c & 7, cg = cs ^ (r & 7);
    const char* gp = (const char*)(kbase + (size_t)r * 1024) + (cg << 4);
    __builtin_amdgcn_global_load_lds((gas_t)gp, (las_t)((char*)Ks + (c << 4)), 16, 0, 0);
  }
#pragma unroll
  for (int i = 0; i < 3; ++i) {
    int c = i * 256 + tid;
    int r = c / 12, jj = c - r * 12;
    int4 dv = *(const int4*)(cavt + (size_t)(h * 64 + r) * 384 + b * 96 + jj * 8);
    *(int4*)((char*)Vs + r * 256 + ((jj * 16) ^ ((r & 7) << 4))) = dv;
  }
  __syncthreads();
  f32x4 st[6];
#pragma unroll
  for (int t = 0; t < 6; ++t) st[t] = (f32x4){0.f, 0.f, 0.f, 0.f};
  __builtin_amdgcn_s_setprio(1);
#pragma unroll
  for (int s = 0; s < 2; ++s) {
#pragma unroll
    for (int t = 0; t < 6; ++t) {
      int r = t * 16 + qi;
      s8v kf = *(const s8v*)((const char*)Ks + r * 128 + (((s * 4 + g) ^ (r & 7)) << 4));
      st[t] = __builtin_amdgcn_mfma_f32_16x16x32_bf16(kf, qf[s], st[t], 0, 0, 0);
    }
  }
  __builtin_amdgcn_s_setprio(0);
  float sv[24];
#pragma unroll
  for (int t = 0; t < 6; ++t)
#pragma unroll
    for (int r2 = 0; r2 < 4; ++r2) {
      int key = t * 16 + g * 4 + r2;
      sv[t * 4 + r2] = (key < SEQ) ? st[t][r2] : -1e30f;
    }
  float mx = sv[0];
#pragma unroll
  for (int i = 1; i < 24; ++i) mx = fmaxf(mx, sv[i]);
  mx = fmaxf(mx, __shfl_xor(mx, 16));
  mx = fmaxf(mx, __shfl_xor(mx, 32));
  float l = 0.f;
#pragma unroll
  for (int i = 0; i < 24; ++i) { sv[i] = exp2f(sv[i] - mx); l += sv[i]; }
  l += __shfl_xor(l, 16);
  l += __shfl_xor(l, 32);
  char* psw = (char*)Ps + w * 4096;
  int pswz = (qi & 7) << 4;
#pragma unroll
  for (int t = 0; t < 6; ++t) {
    short4 pk = make_short4(f2bf(sv[t * 4]), f2bf(sv[t * 4 + 1]),
                            f2bf(sv[t * 4 + 2]), f2bf(sv[t * 4 + 3]));
    *(short4*)(psw + qi * 256 + ((t * 32 + g * 8) ^ pswz)) = pk;
  }
  f32x4 o[4];
#pragma unroll
  for (int d = 0; d < 4; ++d) o[d] = (f32x4){0.f, 0.f, 0.f, 0.f};
  __builtin_amdgcn_s_setprio(1);
#pragma unroll
  for (int s = 0; s < 3; ++s) {
    s8v bf = *(const s8v*)(psw + qi * 256 + ((s * 64 + g * 16) ^ pswz));
#pragma unroll
    for (int d = 0; d < 4; ++d) {
      int r = d * 16 + qi;
      s8v af = *(const s8v*)((const char*)Vs + r * 256 + (((s * 64 + g * 16) ^ ((r & 7) << 4))));
      o[d] = __builtin_amdgcn_mfma_f32_16x16x32_bf16(af, bf, o[d], 0, 0, 0);
    }
  }
  __builtin_amdgcn_s_setprio(0);
  float rl = 1.f / l;
  short* ob = outp + (size_t)(b * 1024 + q0 + w * 16 + qi) * 512 + h * 64;
#pragma unroll
  for (int d = 0; d < 4; ++d) {
    short4 s4 = make_short4(f2bf(o[d][0] * rl), f2bf(o[d][1] * rl),
                            f2bf(o[d][2] * rl), f2bf(o[d][3] * rl));
    *(short4*)(ob + d * 16 + g * 4) = s4;
  }
}

extern "C" void kernel_launch(void* const* d_in, const int* in_sizes, int n_in,
                              void* d_out, int out_size, void* d_ws, size_t ws_size,
                              hipStream_t stream) {
  const float* x        = (const float*)d_in[0];
  const float* context  = (const float*)d_in[1];
  const float* sa_nw    = (const float*)d_in[2];
  const float* sa_nb    = (const float*)d_in[3];
  const float* sa_qkv_w = (const float*)d_in[4];
  const float* sa_qkv_b = (const float*)d_in[5];
  const float* sa_pw    = (const float*)d_in[6];
  const float* sa_pb    = (const float*)d_in[7];
  const float* ca_nw    = (const float*)d_in[8];
  const float* ca_nb    = (const float*)d_in[9];
  const float* ca_qw    = (const float*)d_in[10];
  const float* ca_qb    = (const float*)d_in[11];
  const float* ca_kvw   = (const float*)d_in[12];
  const float* ca_kvb   = (const float*)d_in[13];
  const float* ca_pw    = (const float*)d_in[14];
  const float* ca_pb    = (const float*)d_in[15];
  const float* ff_nw    = (const float*)d_in[16];
  const float* ff_nb    = (const float*)d_in[17];
  const float* ff_w1    = (const float*)d_in[18];
  const float* ff_b1    = (const float*)d_in[19];
  const float* ff_w2    = (const float*)d_in[20];
  const float* ff_b2    = (const float*)d_in[21];
  float* outp = (float*)d_out;

  char* ws = (char*)d_ws;
  float*  xcur  = (float*)(ws);                          // [0,8M)  residual stream (cm f32)
  short*  hb    = (short*)(ws + (8u << 20));             // [8,12M) GN out / attn out (bf16 tm)
  short*  big   = (short*)(ws + (12u << 20));            // [12,28M) qkvb / qb / h1
  short*  qkvb  = big;
  short*  qb    = big;
  short*  h1    = big;
  short*  vt    = (short*)(ws + (28u << 20));            // [28,32M) V^T [512][4096]
  short*  kvb   = (short*)(ws + (32u << 20));            // 768KB
  short*  cavt  = (short*)(ws + (33u << 20));            // 384KB [512][384]
  short*  ctxb  = (short*)(ws + (34u << 20));            // 576KB
  float2* statsPart = (float2*)(ws + (35u << 20));       // [32][8] partials (SA)
  float2* statsCA   = statsPart + 256;                   // 32 raw sums (CA)
  float2* statsFFN  = statsPart + 288;                   // 32 raw sums (FFN)
  short*  wb    = (short*)(ws + (36u << 20));            // bf16 weights (~8.7MB)

  short* w_qkv = wb;
  short* w_sap = wb + 786432;
  short* w_caq = wb + 1048576;
  short* w_kv  = wb + 1310720;
  short* w_cap = wb + 2097152;
  short* w_f1  = wb + 2359296;
  short* w_f2  = wb + 3407872;

  dim3 blk(TPB);
  prep<<<4896, blk, 0, stream>>>(sa_qkv_w, sa_pw, ca_qw, ca_kvw, ca_pw, ff_w1, ff_w2, wb,
                                 context, ctxb, x, statsPart, statsCA, statsFFN);

  // ---- self-attention (+ merged CA kv projection) ----
  gn_apply<<<dim3(16, 32), blk, 0, stream>>>(x, sa_nw, sa_nb, statsPart, hb, 8);
  gemm_qkvkv<<<408, blk, 0, stream>>>(hb, w_qkv, sa_qkv_b, ctxb, w_kv, ca_kvb,
                                      qkvb, vt, kvb, cavt);
  sa_attn_mfma<<<dim3(16, 8, 4), blk, 0, stream>>>(qkvb, vt, hb);
  gemm_nt<128, 64, 1><<<dim3(32, 8), blk, 0, stream>>>(hb, w_sap, sa_pb, x, xcur, 512, 512, 1.f, statsCA);

  // ---- cross-attention ----
  gn_apply<<<dim3(16, 32), blk, 0, stream>>>(xcur, ca_nw, ca_nb, statsCA, hb, 1);
  gemm_nt<128, 64, 0><<<dim3(32, 8), blk, 0, stream>>>(hb, w_caq, ca_qb, nullptr, qb, 512, 512, SCL_L2E, nullptr);
  ca_attn_mfma<<<dim3(16, 8, 4), blk, 0, stream>>>(qb, kvb, cavt, hb);
  gemm_nt<128, 64, 1><<<dim3(32, 8), blk, 0, stream>>>(hb, w_cap, ca_pb, xcur, xcur, 512, 512, 1.f, statsFFN);

  // ---- FFN ----
  gn_apply<<<dim3(16, 32), blk, 0, stream>>>(xcur, ff_nw, ff_nb, statsFFN, hb, 1);
  gemm_nt<128, 128, 2><<<dim3(32, 16), blk, 0, stream>>>(hb, w_f1, ff_b1, nullptr, h1, 512, 2048, 1.f, nullptr);
  gemm_nt<128, 64, 1><<<dim3(32, 8), blk, 0, stream>>>(h1, w_f2, ff_b2, xcur, outp, 2048, 512, 1.f, nullptr);
}

// Round 9
// 156.262 us; speedup vs baseline: 7.1093x; 1.0627x over previous
//
#include <hip/hip_runtime.h>
#include <hip/hip_bf16.h>

#define TPB 256
#define Bsz 4
#define Nsp 1024
#define Cch 512
#define SEQ 77
#define CTX 768
#define EPSV 1e-5f
#define MTOK 4096   // B * N
#define SCL_L2E 0.18033688011111834f   // 0.125 * log2(e)

typedef __attribute__((ext_vector_type(8))) short s8v;
typedef __attribute__((ext_vector_type(4))) float f32x4;
typedef const __attribute__((address_space(1))) void* gas_t;
typedef __attribute__((address_space(3))) void* las_t;

static __device__ __forceinline__ float bf2f(short s) {
  union { unsigned u; float f; } z; z.u = ((unsigned)(unsigned short)s) << 16; return z.f;
}
static __device__ __forceinline__ short f2bf(float f) {
  union { __hip_bfloat16 h; short s; } u;
  u.h = __float2bfloat16(f);
  return u.s;
}
static __device__ __forceinline__ float fast_exp2(float x) {
  return __builtin_amdgcn_exp2f(x);
}
// tanh-form GELU via one v_exp_f32; exponent clamped so z stays finite.
// max |err| vs exact ~3e-4, far below bf16 rounding of the stored activation.
static __device__ __forceinline__ float fast_gelu(float v) {
  float s = v * (2.3021144f + 0.1029451f * v * v);
  s = fminf(fmaxf(s, -60.f), 60.f);
  float z = __builtin_amdgcn_exp2f(s);
  return v * z / (z + 1.f);
}

// ---------- prep: weight/ctx convert + SA gn partial stats + stats zero ----------
__global__ __launch_bounds__(TPB) void prep(const float* a0, const float* a1,
                                            const float* a2, const float* a3,
                                            const float* a4, const float* a5,
                                            const float* a6, short* __restrict__ wdst,
                                            const float* __restrict__ ctx,
                                            short* __restrict__ cdst,
                                            const float* __restrict__ x,
                                            float2* __restrict__ statsPart,
                                            float2* __restrict__ statsCA,
                                            float2* __restrict__ statsFFN) {
  int blk = blockIdx.x;
  int tid = threadIdx.x;
  if (blk < 4352) {
    int u = blk * TPB + tid;
    const float* src; int base;
    if      (u < 196608) { src = a0; base = 0; }
    else if (u < 262144) { src = a1; base = 196608; }
    else if (u < 327680) { src = a2; base = 262144; }
    else if (u < 524288) { src = a3; base = 327680; }
    else if (u < 589824) { src = a4; base = 524288; }
    else if (u < 851968) { src = a5; base = 589824; }
    else                 { src = a6; base = 851968; }
    float4 v = *(const float4*)(src + (size_t)(u - base) * 4);
    short4 o = make_short4(f2bf(v.x), f2bf(v.y), f2bf(v.z), f2bf(v.w));
    *(short4*)(wdst + (size_t)u * 4) = o;
    return;
  }
  if (blk < 4640) {
    int u = (blk - 4352) * TPB + tid;
    int row = u / 192, c4 = u - row * 192;
    int b = row / 96, s_ = row - b * 96;
    short4 o;
    if (s_ < SEQ) {
      float4 v = *(const float4*)(ctx + ((size_t)(b * SEQ + s_)) * CTX + c4 * 4);
      o = make_short4(f2bf(v.x), f2bf(v.y), f2bf(v.z), f2bf(v.w));
    } else {
      o = make_short4(0, 0, 0, 0);
    }
    *(short4*)(cdst + (size_t)row * CTX + c4 * 4) = o;
    return;
  }
  int idx = blk - 4640;
  int bg = idx >> 3, part = idx & 7;
  const float* base = x + (size_t)bg * 65536 + part * 8192;
  float s = 0.f, s2 = 0.f;
#pragma unroll
  for (int it = 0; it < 8; ++it) {
    float4 v = ((const float4*)base)[it * 256 + tid];
    s += v.x + v.y + v.z + v.w;
    s2 += v.x * v.x + v.y * v.y + v.z * v.z + v.w * v.w;
  }
  for (int off = 1; off < 64; off <<= 1) {
    s += __shfl_xor(s, off, 64);
    s2 += __shfl_xor(s2, off, 64);
  }
  __shared__ float red[2][4];
  int wid = tid >> 6;
  if ((tid & 63) == 0) { red[0][wid] = s; red[1][wid] = s2; }
  __syncthreads();
  if (tid == 0) {
    float S = red[0][0] + red[0][1] + red[0][2] + red[0][3];
    float S2 = red[1][0] + red[1][1] + red[1][2] + red[1][3];
    statsPart[idx] = make_float2(S, S2);
  } else if (tid == 1 && part == 0) {
    statsCA[bg] = make_float2(0.f, 0.f);
  } else if (tid == 2 && part == 0) {
    statsFFN[bg] = make_float2(0.f, 0.f);
  }
}

// ---------- GroupNorm apply + transpose: [B,C,N] f32 -> token-major bf16 [4096,512] ----------
__global__ __launch_bounds__(TPB) void gn_apply(const float* __restrict__ x,
                                                const float* __restrict__ w,
                                                const float* __restrict__ bb,
                                                const float2* __restrict__ stats,
                                                short* __restrict__ outp,
                                                int npart) {
  int t = blockIdx.x, bg = blockIdx.y;
  int b = bg >> 3, g = bg & 7;
  float S = 0.f, S2 = 0.f;
  for (int p = 0; p < npart; ++p) {
    float2 st = stats[bg * npart + p];
    S += st.x; S2 += st.y;
  }
  const float inv = 1.f / 65536.f;
  float mu = S * inv;
  float var = S2 * inv - mu * mu;
  float rstd = rsqrtf(var + EPSV);
  __shared__ float tile[64][65];
  int tid = threadIdx.x;
  int n0 = t * 64;
  const float* p = x + (size_t)bg * 65536;
#pragma unroll
  for (int it = 0; it < 4; ++it) {
    int idx = it * 256 + tid;
    int c = idx >> 4, n4 = (idx & 15) * 4;
    float4 v = *(const float4*)(p + (size_t)c * 1024 + n0 + n4);
    float wc = w[g * 64 + c] * rstd;
    float bc = bb[g * 64 + c] - mu * wc;
    tile[c][n4 + 0] = v.x * wc + bc;
    tile[c][n4 + 1] = v.y * wc + bc;
    tile[c][n4 + 2] = v.z * wc + bc;
    tile[c][n4 + 3] = v.w * wc + bc;
  }
  __syncthreads();
  int n = tid >> 2, cs = (tid & 3) * 16;
  short ob[16];
#pragma unroll
  for (int j = 0; j < 16; ++j) ob[j] = f2bf(tile[cs + j][n]);
  short* op = outp + (size_t)(b * 1024 + n0 + n) * 512 + g * 64 + cs;
  *(int4*)op = *(int4*)&ob[0];
  *(int4*)(op + 8) = *(int4*)&ob[8];
}

// ---------- bf16 MFMA NT-GEMM, 2-phase double-buffered staging ----------
// MODE 0: bf16 tm out, scaled by oscale
// MODE 1: f32 channel-major out [B,O,1024] + cm f32 residual; optional stats accumulation
// MODE 2: gelu -> bf16 tm out
template<int BM, int BN, int MODE>
__global__ __launch_bounds__(TPB) void gemm_nt(const short* __restrict__ A,
                                               const short* __restrict__ Bw,
                                               const float* __restrict__ bias,
                                               const float* __restrict__ resid,
                                               void* __restrict__ outp,
                                               int K, int O,
                                               float oscale,
                                               float2* __restrict__ stats_out) {
  const int FM = BM / 32, FN = BN / 32;
  __shared__ __align__(16) short As[2][BM * 64];
  __shared__ __align__(16) short Bs[2][BN * 64];
  int tid = threadIdx.x;
  int lane = tid & 63, w = tid >> 6;
  int wr = w >> 1, wc = w & 1;
  int m0 = blockIdx.x * BM, o0 = blockIdx.y * BN;
  f32x4 acc[FM][FN];
#pragma unroll
  for (int i = 0; i < FM; ++i)
#pragma unroll
    for (int j = 0; j < FN; ++j) acc[i][j] = (f32x4){0.f, 0.f, 0.f, 0.f};
  int nk = K >> 6;

  auto stage = [&](int bi, int kt) {
    int k0 = kt << 6;
#pragma unroll
    for (int i = 0; i < BM / 32; ++i) {
      int c = i * 256 + tid;
      int r = c >> 3, qs = c & 7, qg = qs ^ (r & 7);
      const char* ga = (const char*)(A + ((size_t)(m0 + r) * K + k0)) + (qg << 4);
      __builtin_amdgcn_global_load_lds((gas_t)ga, (las_t)((char*)As[bi] + (c << 4)), 16, 0, 0);
    }
#pragma unroll
    for (int i = 0; i < BN / 32; ++i) {
      int c = i * 256 + tid;
      int r = c >> 3, qs = c & 7, qg = qs ^ (r & 7);
      const char* gb = (const char*)(Bw + ((size_t)(o0 + r) * K + k0)) + (qg << 4);
      __builtin_amdgcn_global_load_lds((gas_t)gb, (las_t)((char*)Bs[bi] + (c << 4)), 16, 0, 0);
    }
  };

  stage(0, 0);
  __syncthreads();
  for (int kt = 0; kt < nk; ++kt) {
    int cur = kt & 1;
    if (kt + 1 < nk) stage(cur ^ 1, kt + 1);
#pragma unroll
    for (int kk = 0; kk < 2; ++kk) {
      s8v a[FM], bfr[FN];
#pragma unroll
      for (int m = 0; m < FM; ++m) {
        int r = wr * (BM / 2) + m * 16 + (lane & 15);
        int q = (lane >> 4) + (kk << 2);
        a[m] = *(const s8v*)((const char*)As[cur] + r * 128 + ((q ^ (r & 7)) << 4));
      }
#pragma unroll
      for (int n = 0; n < FN; ++n) {
        int r = wc * (BN / 2) + n * 16 + (lane & 15);
        int q = (lane >> 4) + (kk << 2);
        bfr[n] = *(const s8v*)((const char*)Bs[cur] + r * 128 + ((q ^ (r & 7)) << 4));
      }
#pragma unroll
      for (int m = 0; m < FM; ++m)
#pragma unroll
        for (int n = 0; n < FN; ++n)
          acc[m][n] = __builtin_amdgcn_mfma_f32_16x16x32_bf16(a[m], bfr[n], acc[m][n], 0, 0, 0);
    }
    __syncthreads();
  }
  float bv[FN];
#pragma unroll
  for (int n = 0; n < FN; ++n) bv[n] = bias[o0 + wc * (BN / 2) + n * 16 + (lane & 15)];
  int row_b = m0 + wr * (BM / 2) + ((lane >> 4) << 2);
  int col_b = o0 + wc * (BN / 2) + (lane & 15);
  if (MODE == 1) {
    float ls = 0.f, ls2 = 0.f;
#pragma unroll
    for (int m = 0; m < FM; ++m) {
      int t0 = row_b + m * 16;
      int b = t0 >> 10, n_ = t0 & 1023;
#pragma unroll
      for (int n = 0; n < FN; ++n) {
        int og = col_b + n * 16;
        size_t idx = ((size_t)(b * O + og)) * 1024 + n_;
        float4 rv = *(const float4*)(resid + idx);
        float4 ov;
        ov.x = acc[m][n][0] + bv[n] + rv.x;
        ov.y = acc[m][n][1] + bv[n] + rv.y;
        ov.z = acc[m][n][2] + bv[n] + rv.z;
        ov.w = acc[m][n][3] + bv[n] + rv.w;
        *(float4*)((float*)outp + idx) = ov;
        ls += ov.x + ov.y + ov.z + ov.w;
        ls2 += ov.x * ov.x + ov.y * ov.y + ov.z * ov.z + ov.w * ov.w;
      }
    }
    if (stats_out != nullptr) {
      float s = ls, s2 = ls2;
      for (int off = 1; off < 64; off <<= 1) {
        s += __shfl_xor(s, off, 64);
        s2 += __shfl_xor(s2, off, 64);
      }
      __syncthreads();
      float* red = (float*)As;
      if (lane == 0) { red[w * 2] = s; red[w * 2 + 1] = s2; }
      __syncthreads();
      if (tid == 0) {
        float S = red[0] + red[2] + red[4] + red[6];
        float S2 = red[1] + red[3] + red[5] + red[7];
        int bg = (m0 >> 10) * 8 + (o0 >> 6);
        atomicAdd((float*)stats_out + bg * 2, S);
        atomicAdd((float*)stats_out + bg * 2 + 1, S2);
      }
    }
    return;
  }
#pragma unroll
  for (int m = 0; m < FM; ++m) {
#pragma unroll
    for (int i = 0; i < 4; ++i) {
      int mg = row_b + m * 16 + i;
#pragma unroll
      for (int n = 0; n < FN; ++n) {
        int og = col_b + n * 16;
        float v = acc[m][n][i] + bv[n];
        size_t idx = (size_t)mg * O + og;
        if (MODE == 2) {
          ((short*)outp)[idx] = f2bf(fast_gelu(v));
        } else {
          ((short*)outp)[idx] = f2bf(v * oscale);
        }
      }
    }
  }
}

// ---------- merged qkv + ca_kv GEMM, 2-phase dbuf: 408 blocks, 128x128 tiles ----------
__global__ __launch_bounds__(TPB) void gemm_qkvkv(
    const short* __restrict__ hb, const short* __restrict__ wqkv, const float* __restrict__ bqkv,
    const short* __restrict__ ctxb, const short* __restrict__ wkv, const float* __restrict__ bkv,
    short* __restrict__ qkvb, short* __restrict__ vt,
    short* __restrict__ kvb, short* __restrict__ cavt) {
  __shared__ __align__(16) short As[2][128 * 64];
  __shared__ __align__(16) short Bs[2][128 * 64];
  int bid = blockIdx.x;
  const short *A, *Bw; const float* bias;
  short *outp, *tout;
  int K, O, m0, o0, split, tstride, qsplit;
  if (bid < 384) {
    A = hb; Bw = wqkv; bias = bqkv; outp = qkvb; tout = vt;
    K = 512; O = 1536; split = 1024; tstride = 4096; qsplit = 512;
    m0 = (bid & 31) * 128; o0 = (bid >> 5) * 128;
  } else {
    int idx = bid - 384;
    A = ctxb; Bw = wkv; bias = bkv; outp = kvb; tout = cavt;
    K = 768; O = 1024; split = 512; tstride = 384; qsplit = 0;
    m0 = (idx % 3) * 128; o0 = (idx / 3) * 128;
  }
  int tid = threadIdx.x;
  int lane = tid & 63, w = tid >> 6;
  int wr = w >> 1, wc = w & 1;
  f32x4 acc[4][4];
#pragma unroll
  for (int i = 0; i < 4; ++i)
#pragma unroll
    for (int j = 0; j < 4; ++j) acc[i][j] = (f32x4){0.f, 0.f, 0.f, 0.f};
  int nk = K >> 6;

  auto stage = [&](int bi, int kt) {
    int k0 = kt << 6;
#pragma unroll
    for (int i = 0; i < 4; ++i) {
      int c = i * 256 + tid;
      int r = c >> 3, qs = c & 7, qg = qs ^ (r & 7);
      const char* ga = (const char*)(A + ((size_t)(m0 + r) * K + k0)) + (qg << 4);
      __builtin_amdgcn_global_load_lds((gas_t)ga, (las_t)((char*)As[bi] + (c << 4)), 16, 0, 0);
    }
#pragma unroll
    for (int i = 0; i < 4; ++i) {
      int c = i * 256 + tid;
      int r = c >> 3, qs = c & 7, qg = qs ^ (r & 7);
      const char* gb = (const char*)(Bw + ((size_t)(o0 + r) * K + k0)) + (qg << 4);
      __builtin_amdgcn_global_load_lds((gas_t)gb, (las_t)((char*)Bs[bi] + (c << 4)), 16, 0, 0);
    }
  };

  stage(0, 0);
  __syncthreads();
  for (int kt = 0; kt < nk; ++kt) {
    int cur = kt & 1;
    if (kt + 1 < nk) stage(cur ^ 1, kt + 1);
#pragma unroll
    for (int kk = 0; kk < 2; ++kk) {
      s8v a[4], bfr[4];
#pragma unroll
      for (int m = 0; m < 4; ++m) {
        int r = wr * 64 + m * 16 + (lane & 15);
        int q = (lane >> 4) + (kk << 2);
        a[m] = *(const s8v*)((const char*)As[cur] + r * 128 + ((q ^ (r & 7)) << 4));
      }
#pragma unroll
      for (int n = 0; n < 4; ++n) {
        int r = wc * 64 + n * 16 + (lane & 15);
        int q = (lane >> 4) + (kk << 2);
        bfr[n] = *(const s8v*)((const char*)Bs[cur] + r * 128 + ((q ^ (r & 7)) << 4));
      }
#pragma unroll
      for (int m = 0; m < 4; ++m)
#pragma unroll
        for (int n = 0; n < 4; ++n)
          acc[m][n] = __builtin_amdgcn_mfma_f32_16x16x32_bf16(a[m], bfr[n], acc[m][n], 0, 0, 0);
    }
    __syncthreads();
  }
  float bv[4];
#pragma unroll
  for (int n = 0; n < 4; ++n) bv[n] = bias[o0 + wc * 64 + n * 16 + (lane & 15)];
  int row_b = m0 + wr * 64 + ((lane >> 4) << 2);
  int col_b = o0 + wc * 64 + (lane & 15);
  if (o0 >= split) {
#pragma unroll
    for (int m = 0; m < 4; ++m) {
#pragma unroll
      for (int n = 0; n < 4; ++n) {
        int og = col_b + n * 16;
        short4 s4 = make_short4(f2bf(acc[m][n][0] + bv[n]), f2bf(acc[m][n][1] + bv[n]),
                                f2bf(acc[m][n][2] + bv[n]), f2bf(acc[m][n][3] + bv[n]));
        *(short4*)(tout + (size_t)(og - split) * tstride + row_b + m * 16) = s4;
      }
    }
    return;
  }
#pragma unroll
  for (int m = 0; m < 4; ++m) {
#pragma unroll
    for (int i = 0; i < 4; ++i) {
      int mg = row_b + m * 16 + i;
#pragma unroll
      for (int n = 0; n < 4; ++n) {
        int og = col_b + n * 16;
        float v = acc[m][n][i] + bv[n];
        if (og < qsplit) v *= SCL_L2E;
        ((short*)outp)[(size_t)mg * O + og] = f2bf(v);
      }
    }
  }
}

// ---------- self-attention, MFMA flash, KVBLK=128, dbuf, exp2 softmax, defer-max ----------
__global__ __launch_bounds__(TPB) void sa_attn_mfma(const short* __restrict__ qkv,
                                                    const short* __restrict__ vt,
                                                    short* __restrict__ outp) {
  __shared__ __align__(16) short Ks[2][128 * 64];
  __shared__ __align__(16) short Vs[2][64 * 128];
  __shared__ __align__(16) short Ps[4][16 * 128];
  int b = blockIdx.z, h = blockIdx.y, q0 = blockIdx.x * 64;
  int tid = threadIdx.x, lane = tid & 63, w = tid >> 6;
  int g = lane >> 4, qi = lane & 15;
  s8v qf[2];
  {
    const short* qp = qkv + (size_t)(b * 1024 + q0 + w * 16 + qi) * 1536 + h * 64 + g * 8;
    qf[0] = *(const s8v*)qp;
    qf[1] = *(const s8v*)(qp + 32);
  }
  f32x4 o[4];
#pragma unroll
  for (int d = 0; d < 4; ++d) o[d] = (f32x4){0.f, 0.f, 0.f, 0.f};
  float mrun = -1e30f, lrun = 0.f;
  const short* kbase = qkv + (size_t)(b * 1024) * 1536 + 512 + h * 64;
  const short* vbase = vt + (size_t)(h * 64) * 4096 + b * 1024;
  char* psw = (char*)Ps + w * 4096;
  int pswz = (qi & 15) << 4;

  auto stage = [&](int bufi, int kt) {
    int k0 = kt * 128;
#pragma unroll
    for (int i = 0; i < 4; ++i) {
      int c = i * 256 + tid;
      int r = c >> 3, cs = c & 7, cg = cs ^ (r & 7);
      const char* gp = (const char*)(kbase + (size_t)(k0 + r) * 1536) + (cg << 4);
      __builtin_amdgcn_global_load_lds((gas_t)gp, (las_t)((char*)Ks[bufi] + (c << 4)), 16, 0, 0);
    }
#pragma unroll
    for (int i = 0; i < 4; ++i) {
      int c = i * 256 + tid;
      int r = c >> 4, cs = c & 15, cg = cs ^ (r & 15);
      const char* gp = (const char*)(vbase + (size_t)r * 4096 + k0) + (cg << 4);
      __builtin_amdgcn_global_load_lds((gas_t)gp, (las_t)((char*)Vs[bufi] + (c << 4)), 16, 0, 0);
    }
  };

  stage(0, 0);
  __syncthreads();
  for (int kt = 0; kt < 8; ++kt) {
    int cur = kt & 1;
    if (kt < 7) stage(cur ^ 1, kt + 1);
    f32x4 st[8];
#pragma unroll
    for (int t = 0; t < 8; ++t) st[t] = (f32x4){0.f, 0.f, 0.f, 0.f};
    __builtin_amdgcn_s_setprio(1);
#pragma unroll
    for (int s = 0; s < 2; ++s) {
#pragma unroll
      for (int t = 0; t < 8; ++t) {
        int r = t * 16 + qi;
        s8v kf = *(const s8v*)((const char*)Ks[cur] + r * 128 + (((s * 4 + g) ^ (r & 7)) << 4));
        st[t] = __builtin_amdgcn_mfma_f32_16x16x32_bf16(kf, qf[s], st[t], 0, 0, 0);
      }
    }
    __builtin_amdgcn_s_setprio(0);
    float sv[32];
#pragma unroll
    for (int t = 0; t < 8; ++t)
#pragma unroll
      for (int r2 = 0; r2 < 4; ++r2) sv[t * 4 + r2] = st[t][r2];
    float mx = sv[0];
#pragma unroll
    for (int i = 1; i < 32; ++i) mx = fmaxf(mx, sv[i]);
    mx = fmaxf(mx, __shfl_xor(mx, 16));
    mx = fmaxf(mx, __shfl_xor(mx, 32));
    if (!__all(mx - mrun <= 11.f)) {
      float mnew = fmaxf(mrun, mx);
      float scale = fast_exp2(mrun - mnew);
      lrun *= scale;
#pragma unroll
      for (int d = 0; d < 4; ++d) o[d] *= scale;
      mrun = mnew;
    }
    float psum = 0.f;
#pragma unroll
    for (int i = 0; i < 32; ++i) { sv[i] = fast_exp2(sv[i] - mrun); psum += sv[i]; }
    psum += __shfl_xor(psum, 16);
    psum += __shfl_xor(psum, 32);
    lrun += psum;
#pragma unroll
    for (int t = 0; t < 8; ++t) {
      short4 pk = make_short4(f2bf(sv[t * 4]), f2bf(sv[t * 4 + 1]),
                              f2bf(sv[t * 4 + 2]), f2bf(sv[t * 4 + 3]));
      *(short4*)(psw + qi * 256 + ((t * 32 + g * 8) ^ pswz)) = pk;
    }
    __builtin_amdgcn_s_setprio(1);
#pragma unroll
    for (int s = 0; s < 4; ++s) {
      s8v bf = *(const s8v*)(psw + qi * 256 + ((s * 64 + g * 16) ^ pswz));
#pragma unroll
      for (int d = 0; d < 4; ++d) {
        int r = d * 16 + qi;
        s8v af = *(const s8v*)((const char*)Vs[cur] + r * 256 + (((s * 4 + g) ^ (r & 15)) << 4));
        o[d] = __builtin_amdgcn_mfma_f32_16x16x32_bf16(af, bf, o[d], 0, 0, 0);
      }
    }
    __builtin_amdgcn_s_setprio(0);
    __syncthreads();
  }
  float rl = 1.f / lrun;
  short* ob = outp + (size_t)(b * 1024 + q0 + w * 16 + qi) * 512 + h * 64;
#pragma unroll
  for (int d = 0; d < 4; ++d) {
    short4 s4 = make_short4(f2bf(o[d][0] * rl), f2bf(o[d][1] * rl),
                            f2bf(o[d][2] * rl), f2bf(o[d][3] * rl));
    *(short4*)(ob + d * 16 + g * 4) = s4;
  }
}

// ---------- cross-attention, MFMA single-pass (q pre-scaled, exp2) ----------
__global__ __launch_bounds__(TPB) void ca_attn_mfma(const short* __restrict__ qb,
                                                    const short* __restrict__ kvb,
                                                    const short* __restrict__ cavt,
                                                    short* __restrict__ outp) {
  __shared__ __align__(16) short Ks[96 * 64];
  __shared__ __align__(16) short Vs[64 * 128];
  __shared__ __align__(16) short Ps[4][16 * 128];
  int b = blockIdx.z, h = blockIdx.y, q0 = blockIdx.x * 64;
  int tid = threadIdx.x, lane = tid & 63, w = tid >> 6;
  int g = lane >> 4, qi = lane & 15;
  s8v qf[2];
  {
    const short* qp = qb + (size_t)(b * 1024 + q0 + w * 16 + qi) * 512 + h * 64 + g * 8;
    qf[0] = *(const s8v*)qp;
    qf[1] = *(const s8v*)(qp + 32);
  }
  const short* kbase = kvb + (size_t)(b * 96) * 1024 + h * 64;
#pragma unroll
  for (int i = 0; i < 3; ++i) {
    int c = i * 256 + tid;
    int r = c >> 3, cs = c & 7, cg = cs ^ (r & 7);
    const char* gp = (const char*)(kbase + (size_t)r * 1024) + (cg << 4);
    __builtin_amdgcn_global_load_lds((gas_t)gp, (las_t)((char*)Ks + (c << 4)), 16, 0, 0);
  }
#pragma unroll
  for (int i = 0; i < 3; ++i) {
    int c = i * 256 + tid;
    int r = c / 12, jj = c - r * 12;
    int4 dv = *(const int4*)(cavt + (size_t)(h * 64 + r) * 384 + b * 96 + jj * 8);
    *(int4*)((char*)Vs + r * 256 + ((jj * 16) ^ ((r & 7) << 4))) = dv;
  }
  __syncthreads();
  f32x4 st[6];
#pragma unroll
  for (int t = 0; t < 6; ++t) st[t] = (f32x4){0.f, 0.f, 0.f, 0.f};
  __builtin_amdgcn_s_setprio(1);
#pragma unroll
  for (int s = 0; s < 2; ++s) {
#pragma unroll
    for (int t = 0; t < 6; ++t) {
      int r = t * 16 + qi;
      s8v kf = *(const s8v*)((const char*)Ks + r * 128 + (((s * 4 + g) ^ (r & 7)) << 4));
      st[t] = __builtin_amdgcn_mfma_f32_16x16x32_bf16(kf, qf[s], st[t], 0, 0, 0);
    }
  }
  __builtin_amdgcn_s_setprio(0);
  float sv[24];
#pragma unroll
  for (int t = 0; t < 6; ++t)
#pragma unroll
    for (int r2 = 0; r2 < 4; ++r2) {
      int key = t * 16 + g * 4 + r2;
      sv[t * 4 + r2] = (key < SEQ) ? st[t][r2] : -1e30f;
    }
  float mx = sv[0];
#pragma unroll
  for (int i = 1; i < 24; ++i) mx = fmaxf(mx, sv[i]);
  mx = fmaxf(mx, __shfl_xor(mx, 16));
  mx = fmaxf(mx, __shfl_xor(mx, 32));
  float l = 0.f;
#pragma unroll
  for (int i = 0; i < 24; ++i) { sv[i] = fast_exp2(sv[i] - mx); l += sv[i]; }
  l += __shfl_xor(l, 16);
  l += __shfl_xor(l, 32);
  char* psw = (char*)Ps + w * 4096;
  int pswz = (qi & 7) << 4;
#pragma unroll
  for (int t = 0; t < 6; ++t) {
    short4 pk = make_short4(f2bf(sv[t * 4]), f2bf(sv[t * 4 + 1]),
                            f2bf(sv[t * 4 + 2]), f2bf(sv[t * 4 + 3]));
    *(short4*)(psw + qi * 256 + ((t * 32 + g * 8) ^ pswz)) = pk;
  }
  f32x4 o[4];
#pragma unroll
  for (int d = 0; d < 4; ++d) o[d] = (f32x4){0.f, 0.f, 0.f, 0.f};
  __builtin_amdgcn_s_setprio(1);
#pragma unroll
  for (int s = 0; s < 3; ++s) {
    s8v bf = *(const s8v*)(psw + qi * 256 + ((s * 64 + g * 16) ^ pswz));
#pragma unroll
    for (int d = 0; d < 4; ++d) {
      int r = d * 16 + qi;
      s8v af = *(const s8v*)((const char*)Vs + r * 256 + (((s * 64 + g * 16) ^ ((r & 7) << 4))));
      o[d] = __builtin_amdgcn_mfma_f32_16x16x32_bf16(af, bf, o[d], 0, 0, 0);
    }
  }
  __builtin_amdgcn_s_setprio(0);
  float rl = 1.f / l;
  short* ob = outp + (size_t)(b * 1024 + q0 + w * 16 + qi) * 512 + h * 64;
#pragma unroll
  for (int d = 0; d < 4; ++d) {
    short4 s4 = make_short4(f2bf(o[d][0] * rl), f2bf(o[d][1] * rl),
                            f2bf(o[d][2] * rl), f2bf(o[d][3] * rl));
    *(short4*)(ob + d * 16 + g * 4) = s4;
  }
}

extern "C" void kernel_launch(void* const* d_in, const int* in_sizes, int n_in,
                              void* d_out, int out_size, void* d_ws, size_t ws_size,
                              hipStream_t stream) {
  const float* x        = (const float*)d_in[0];
  const float* context  = (const float*)d_in[1];
  const float* sa_nw    = (const float*)d_in[2];
  const float* sa_nb    = (const float*)d_in[3];
  const float* sa_qkv_w = (const float*)d_in[4];
  const float* sa_qkv_b = (const float*)d_in[5];
  const float* sa_pw    = (const float*)d_in[6];
  const float* sa_pb    = (const float*)d_in[7];
  const float* ca_nw    = (const float*)d_in[8];
  const float* ca_nb    = (const float*)d_in[9];
  const float* ca_qw    = (const float*)d_in[10];
  const float* ca_qb    = (const float*)d_in[11];
  const float* ca_kvw   = (const float*)d_in[12];
  const float* ca_kvb   = (const float*)d_in[13];
  const float* ca_pw    = (const float*)d_in[14];
  const float* ca_pb    = (const float*)d_in[15];
  const float* ff_nw    = (const float*)d_in[16];
  const float* ff_nb    = (const float*)d_in[17];
  const float* ff_w1    = (const float*)d_in[18];
  const float* ff_b1    = (const float*)d_in[19];
  const float* ff_w2    = (const float*)d_in[20];
  const float* ff_b2    = (const float*)d_in[21];
  float* outp = (float*)d_out;

  char* ws = (char*)d_ws;
  float*  xcur  = (float*)(ws);                          // [0,8M)  residual stream (cm f32)
  short*  hb    = (short*)(ws + (8u << 20));             // [8,12M) GN out / attn out (bf16 tm)
  short*  big   = (short*)(ws + (12u << 20));            // [12,28M) qkvb / qb / h1
  short*  qkvb  = big;
  short*  qb    = big;
  short*  h1    = big;
  short*  vt    = (short*)(ws + (28u << 20));            // [28,32M) V^T [512][4096]
  short*  kvb   = (short*)(ws + (32u << 20));            // 768KB
  short*  cavt  = (short*)(ws + (33u << 20));            // 384KB [512][384]
  short*  ctxb  = (short*)(ws + (34u << 20));            // 576KB
  float2* statsPart = (float2*)(ws + (35u << 20));       // [32][8] partials (SA)
  float2* statsCA   = statsPart + 256;                   // 32 raw sums (CA)
  float2* statsFFN  = statsPart + 288;                   // 32 raw sums (FFN)
  short*  wb    = (short*)(ws + (36u << 20));            // bf16 weights (~8.7MB)

  short* w_qkv = wb;
  short* w_sap = wb + 786432;
  short* w_caq = wb + 1048576;
  short* w_kv  = wb + 1310720;
  short* w_cap = wb + 2097152;
  short* w_f1  = wb + 2359296;
  short* w_f2  = wb + 3407872;

  dim3 blk(TPB);
  prep<<<4896, blk, 0, stream>>>(sa_qkv_w, sa_pw, ca_qw, ca_kvw, ca_pw, ff_w1, ff_w2, wb,
                                 context, ctxb, x, statsPart, statsCA, statsFFN);

  // ---- self-attention (+ merged CA kv projection) ----
  gn_apply<<<dim3(16, 32), blk, 0, stream>>>(x, sa_nw, sa_nb, statsPart, hb, 8);
  gemm_qkvkv<<<408, blk, 0, stream>>>(hb, w_qkv, sa_qkv_b, ctxb, w_kv, ca_kvb,
                                      qkvb, vt, kvb, cavt);
  sa_attn_mfma<<<dim3(16, 8, 4), blk, 0, stream>>>(qkvb, vt, hb);
  gemm_nt<128, 64, 1><<<dim3(32, 8), blk, 0, stream>>>(hb, w_sap, sa_pb, x, xcur, 512, 512, 1.f, statsCA);

  // ---- cross-attention ----
  gn_apply<<<dim3(16, 32), blk, 0, stream>>>(xcur, ca_nw, ca_nb, statsCA, hb, 1);
  gemm_nt<128, 64, 0><<<dim3(32, 8), blk, 0, stream>>>(hb, w_caq, ca_qb, nullptr, qb, 512, 512, SCL_L2E, nullptr);
  ca_attn_mfma<<<dim3(16, 8, 4), blk, 0, stream>>>(qb, kvb, cavt, hb);
  gemm_nt<128, 64, 1><<<dim3(32, 8), blk, 0, stream>>>(hb, w_cap, ca_pb, xcur, xcur, 512, 512, 1.f, statsFFN);

  // ---- FFN ----
  gn_apply<<<dim3(16, 32), blk, 0, stream>>>(xcur, ff_nw, ff_nb, statsFFN, hb, 1);
  gemm_nt<128, 128, 2><<<dim3(32, 16), blk, 0, stream>>>(hb, w_f1, ff_b1, nullptr, h1, 512, 2048, 1.f, nullptr);
  gemm_nt<128, 64, 1><<<dim3(32, 8), blk, 0, stream>>>(h1, w_f2, ff_b2, xcur, outp, 2048, 512, 1.f, nullptr);
}

// Round 10
// 154.092 us; speedup vs baseline: 7.2094x; 1.0141x over previous
//
#include <hip/hip_runtime.h>
#include <hip/hip_bf16.h>

#define TPB 256
#define Bsz 4
#define Nsp 1024
#define Cch 512
#define SEQ 77
#define CTX 768
#define EPSV 1e-5f
#define MTOK 4096   // B * N
#define SCL_L2E 0.18033688011111834f   // 0.125 * log2(e)

typedef __attribute__((ext_vector_type(8))) short s8v;
typedef __attribute__((ext_vector_type(4))) float f32x4;
typedef const __attribute__((address_space(1))) void* gas_t;
typedef __attribute__((address_space(3))) void* las_t;

static __device__ __forceinline__ float bf2f(short s) {
  union { unsigned u; float f; } z; z.u = ((unsigned)(unsigned short)s) << 16; return z.f;
}
static __device__ __forceinline__ short f2bf(float f) {
  union { __hip_bfloat16 h; short s; } u;
  u.h = __float2bfloat16(f);
  return u.s;
}
static __device__ __forceinline__ float fast_exp2(float x) {
  return __builtin_amdgcn_exp2f(x);
}
// tanh-form GELU via one v_exp_f32; clamped exponent. |err| ~3e-4 << bf16 ulp.
static __device__ __forceinline__ float fast_gelu(float v) {
  float s = v * (2.3021144f + 0.1029451f * v * v);
  s = fminf(fmaxf(s, -60.f), 60.f);
  float z = __builtin_amdgcn_exp2f(s);
  return v * z / (z + 1.f);
}

// ---------- prep: weight/ctx convert + SA gn partial stats + stats zero ----------
__global__ __launch_bounds__(TPB) void prep(const float* a0, const float* a1,
                                            const float* a2, const float* a3,
                                            const float* a4, const float* a5,
                                            const float* a6, short* __restrict__ wdst,
                                            const float* __restrict__ ctx,
                                            short* __restrict__ cdst,
                                            const float* __restrict__ x,
                                            float2* __restrict__ statsPart,
                                            float2* __restrict__ statsCA,
                                            float2* __restrict__ statsFFN) {
  int blk = blockIdx.x;
  int tid = threadIdx.x;
  if (blk < 4352) {
    int u = blk * TPB + tid;
    const float* src; int base;
    if      (u < 196608) { src = a0; base = 0; }
    else if (u < 262144) { src = a1; base = 196608; }
    else if (u < 327680) { src = a2; base = 262144; }
    else if (u < 524288) { src = a3; base = 327680; }
    else if (u < 589824) { src = a4; base = 524288; }
    else if (u < 851968) { src = a5; base = 589824; }
    else                 { src = a6; base = 851968; }
    float4 v = *(const float4*)(src + (size_t)(u - base) * 4);
    short4 o = make_short4(f2bf(v.x), f2bf(v.y), f2bf(v.z), f2bf(v.w));
    *(short4*)(wdst + (size_t)u * 4) = o;
    return;
  }
  if (blk < 4640) {
    int u = (blk - 4352) * TPB + tid;
    int row = u / 192, c4 = u - row * 192;
    int b = row / 96, s_ = row - b * 96;
    short4 o;
    if (s_ < SEQ) {
      float4 v = *(const float4*)(ctx + ((size_t)(b * SEQ + s_)) * CTX + c4 * 4);
      o = make_short4(f2bf(v.x), f2bf(v.y), f2bf(v.z), f2bf(v.w));
    } else {
      o = make_short4(0, 0, 0, 0);
    }
    *(short4*)(cdst + (size_t)row * CTX + c4 * 4) = o;
    return;
  }
  int idx = blk - 4640;
  int bg = idx >> 3, part = idx & 7;
  const float* base = x + (size_t)bg * 65536 + part * 8192;
  float s = 0.f, s2 = 0.f;
#pragma unroll
  for (int it = 0; it < 8; ++it) {
    float4 v = ((const float4*)base)[it * 256 + tid];
    s += v.x + v.y + v.z + v.w;
    s2 += v.x * v.x + v.y * v.y + v.z * v.z + v.w * v.w;
  }
  for (int off = 1; off < 64; off <<= 1) {
    s += __shfl_xor(s, off, 64);
    s2 += __shfl_xor(s2, off, 64);
  }
  __shared__ float red[2][4];
  int wid = tid >> 6;
  if ((tid & 63) == 0) { red[0][wid] = s; red[1][wid] = s2; }
  __syncthreads();
  if (tid == 0) {
    float S = red[0][0] + red[0][1] + red[0][2] + red[0][3];
    float S2 = red[1][0] + red[1][1] + red[1][2] + red[1][3];
    statsPart[idx] = make_float2(S, S2);
  } else if (tid == 1 && part == 0) {
    statsCA[bg] = make_float2(0.f, 0.f);
  } else if (tid == 2 && part == 0) {
    statsFFN[bg] = make_float2(0.f, 0.f);
  }
}

// ---------- GroupNorm apply + transpose: cm (f32 or bf16) -> token-major bf16 ----------
// INBF=0: input f32 [B,C,N]; INBF=1: input bf16 [B,C,N]
template<int INBF>
__global__ __launch_bounds__(TPB) void gn_apply(const void* __restrict__ xin,
                                                const float* __restrict__ w,
                                                const float* __restrict__ bb,
                                                const float2* __restrict__ stats,
                                                short* __restrict__ outp,
                                                int npart) {
  int t = blockIdx.x, bg = blockIdx.y;
  int b = bg >> 3, g = bg & 7;
  float S = 0.f, S2 = 0.f;
  for (int p = 0; p < npart; ++p) {
    float2 st = stats[bg * npart + p];
    S += st.x; S2 += st.y;
  }
  const float inv = 1.f / 65536.f;
  float mu = S * inv;
  float var = S2 * inv - mu * mu;
  float rstd = rsqrtf(var + EPSV);
  __shared__ float tile[64][65];
  int tid = threadIdx.x;
  int n0 = t * 64;
#pragma unroll
  for (int it = 0; it < 4; ++it) {
    int idx = it * 256 + tid;
    int c = idx >> 4, n4 = (idx & 15) * 4;
    float vx, vy, vz, vw;
    if (INBF) {
      const short* p = (const short*)xin + (size_t)bg * 65536;
      short4 v = *(const short4*)(p + (size_t)c * 1024 + n0 + n4);
      vx = bf2f(v.x); vy = bf2f(v.y); vz = bf2f(v.z); vw = bf2f(v.w);
    } else {
      const float* p = (const float*)xin + (size_t)bg * 65536;
      float4 v = *(const float4*)(p + (size_t)c * 1024 + n0 + n4);
      vx = v.x; vy = v.y; vz = v.z; vw = v.w;
    }
    float wc = w[g * 64 + c] * rstd;
    float bc = bb[g * 64 + c] - mu * wc;
    tile[c][n4 + 0] = vx * wc + bc;
    tile[c][n4 + 1] = vy * wc + bc;
    tile[c][n4 + 2] = vz * wc + bc;
    tile[c][n4 + 3] = vw * wc + bc;
  }
  __syncthreads();
  int n = tid >> 2, cs = (tid & 3) * 16;
  short ob[16];
#pragma unroll
  for (int j = 0; j < 16; ++j) ob[j] = f2bf(tile[cs + j][n]);
  short* op = outp + (size_t)(b * 1024 + n0 + n) * 512 + g * 64 + cs;
  *(int4*)op = *(int4*)&ob[0];
  *(int4*)(op + 8) = *(int4*)&ob[8];
}

// ---------- bf16 MFMA NT-GEMM, 2-phase double-buffered staging ----------
// MODE 0 : bf16 tm out, scaled by oscale
// MODE 2 : gelu -> bf16 tm out
// MODE 10: cm bf16 out + f32 cm resid + stats
// MODE 11: cm bf16 out + bf16 cm resid + stats
// MODE 12: cm f32 out (d_out) + bf16 cm resid, no stats
template<int BM, int BN, int MODE>
__global__ __launch_bounds__(TPB) void gemm_nt(const short* __restrict__ A,
                                               const short* __restrict__ Bw,
                                               const float* __restrict__ bias,
                                               const void* __restrict__ resid,
                                               void* __restrict__ outp,
                                               int K, int O,
                                               float oscale,
                                               float2* __restrict__ stats_out) {
  const int FM = BM / 32, FN = BN / 32;
  __shared__ __align__(16) short As[2][BM * 64];
  __shared__ __align__(16) short Bs[2][BN * 64];
  int tid = threadIdx.x;
  int lane = tid & 63, w = tid >> 6;
  int wr = w >> 1, wc = w & 1;
  int m0 = blockIdx.x * BM, o0 = blockIdx.y * BN;
  f32x4 acc[FM][FN];
#pragma unroll
  for (int i = 0; i < FM; ++i)
#pragma unroll
    for (int j = 0; j < FN; ++j) acc[i][j] = (f32x4){0.f, 0.f, 0.f, 0.f};
  int nk = K >> 6;

  auto stage = [&](int bi, int kt) {
    int k0 = kt << 6;
#pragma unroll
    for (int i = 0; i < BM / 32; ++i) {
      int c = i * 256 + tid;
      int r = c >> 3, qs = c & 7, qg = qs ^ (r & 7);
      const char* ga = (const char*)(A + ((size_t)(m0 + r) * K + k0)) + (qg << 4);
      __builtin_amdgcn_global_load_lds((gas_t)ga, (las_t)((char*)As[bi] + (c << 4)), 16, 0, 0);
    }
#pragma unroll
    for (int i = 0; i < BN / 32; ++i) {
      int c = i * 256 + tid;
      int r = c >> 3, qs = c & 7, qg = qs ^ (r & 7);
      const char* gb = (const char*)(Bw + ((size_t)(o0 + r) * K + k0)) + (qg << 4);
      __builtin_amdgcn_global_load_lds((gas_t)gb, (las_t)((char*)Bs[bi] + (c << 4)), 16, 0, 0);
    }
  };

  stage(0, 0);
  __syncthreads();
  for (int kt = 0; kt < nk; ++kt) {
    int cur = kt & 1;
    if (kt + 1 < nk) stage(cur ^ 1, kt + 1);
#pragma unroll
    for (int kk = 0; kk < 2; ++kk) {
      s8v a[FM], bfr[FN];
#pragma unroll
      for (int m = 0; m < FM; ++m) {
        int r = wr * (BM / 2) + m * 16 + (lane & 15);
        int q = (lane >> 4) + (kk << 2);
        a[m] = *(const s8v*)((const char*)As[cur] + r * 128 + ((q ^ (r & 7)) << 4));
      }
#pragma unroll
      for (int n = 0; n < FN; ++n) {
        int r = wc * (BN / 2) + n * 16 + (lane & 15);
        int q = (lane >> 4) + (kk << 2);
        bfr[n] = *(const s8v*)((const char*)Bs[cur] + r * 128 + ((q ^ (r & 7)) << 4));
      }
#pragma unroll
      for (int m = 0; m < FM; ++m)
#pragma unroll
        for (int n = 0; n < FN; ++n)
          acc[m][n] = __builtin_amdgcn_mfma_f32_16x16x32_bf16(a[m], bfr[n], acc[m][n], 0, 0, 0);
    }
    __syncthreads();
  }
  float bv[FN];
#pragma unroll
  for (int n = 0; n < FN; ++n) bv[n] = bias[o0 + wc * (BN / 2) + n * 16 + (lane & 15)];
  int row_b = m0 + wr * (BM / 2) + ((lane >> 4) << 2);
  int col_b = o0 + wc * (BN / 2) + (lane & 15);
  if (MODE >= 10) {
    float ls = 0.f, ls2 = 0.f;
#pragma unroll
    for (int m = 0; m < FM; ++m) {
      int t0 = row_b + m * 16;
      int b = t0 >> 10, n_ = t0 & 1023;
#pragma unroll
      for (int n = 0; n < FN; ++n) {
        int og = col_b + n * 16;
        size_t idx = ((size_t)(b * O + og)) * 1024 + n_;
        float rv[4];
        if (MODE == 10) {
          float4 r4 = *(const float4*)((const float*)resid + idx);
          rv[0] = r4.x; rv[1] = r4.y; rv[2] = r4.z; rv[3] = r4.w;
        } else {
          short4 r4 = *(const short4*)((const short*)resid + idx);
          rv[0] = bf2f(r4.x); rv[1] = bf2f(r4.y); rv[2] = bf2f(r4.z); rv[3] = bf2f(r4.w);
        }
        float ov[4];
#pragma unroll
        for (int j = 0; j < 4; ++j) ov[j] = acc[m][n][j] + bv[n] + rv[j];
        if (MODE == 12) {
          *(float4*)((float*)outp + idx) = make_float4(ov[0], ov[1], ov[2], ov[3]);
        } else {
          *(short4*)((short*)outp + idx) =
              make_short4(f2bf(ov[0]), f2bf(ov[1]), f2bf(ov[2]), f2bf(ov[3]));
          ls += ov[0] + ov[1] + ov[2] + ov[3];
          ls2 += ov[0] * ov[0] + ov[1] * ov[1] + ov[2] * ov[2] + ov[3] * ov[3];
        }
      }
    }
    if (MODE != 12 && stats_out != nullptr) {
      float s = ls, s2 = ls2;
      for (int off = 1; off < 64; off <<= 1) {
        s += __shfl_xor(s, off, 64);
        s2 += __shfl_xor(s2, off, 64);
      }
      __syncthreads();
      float* red = (float*)As;
      if (lane == 0) { red[w * 2] = s; red[w * 2 + 1] = s2; }
      __syncthreads();
      if (tid == 0) {
        float S = red[0] + red[2] + red[4] + red[6];
        float S2 = red[1] + red[3] + red[5] + red[7];
        int bg = (m0 >> 10) * 8 + (o0 >> 6);
        atomicAdd((float*)stats_out + bg * 2, S);
        atomicAdd((float*)stats_out + bg * 2 + 1, S2);
      }
    }
    return;
  }
#pragma unroll
  for (int m = 0; m < FM; ++m) {
#pragma unroll
    for (int i = 0; i < 4; ++i) {
      int mg = row_b + m * 16 + i;
#pragma unroll
      for (int n = 0; n < FN; ++n) {
        int og = col_b + n * 16;
        float v = acc[m][n][i] + bv[n];
        size_t idx = (size_t)mg * O + og;
        if (MODE == 2) {
          ((short*)outp)[idx] = f2bf(fast_gelu(v));
        } else {
          ((short*)outp)[idx] = f2bf(v * oscale);
        }
      }
    }
  }
}

// ---------- merged qkv + ca_kv GEMM, 2-phase dbuf: 408 blocks, 128x128 tiles ----------
__global__ __launch_bounds__(TPB) void gemm_qkvkv(
    const short* __restrict__ hb, const short* __restrict__ wqkv, const float* __restrict__ bqkv,
    const short* __restrict__ ctxb, const short* __restrict__ wkv, const float* __restrict__ bkv,
    short* __restrict__ qkvb, short* __restrict__ vt,
    short* __restrict__ kvb, short* __restrict__ cavt) {
  __shared__ __align__(16) short As[2][128 * 64];
  __shared__ __align__(16) short Bs[2][128 * 64];
  int bid = blockIdx.x;
  const short *A, *Bw; const float* bias;
  short *outp, *tout;
  int K, O, m0, o0, split, tstride, qsplit;
  if (bid < 384) {
    A = hb; Bw = wqkv; bias = bqkv; outp = qkvb; tout = vt;
    K = 512; O = 1536; split = 1024; tstride = 4096; qsplit = 512;
    m0 = (bid & 31) * 128; o0 = (bid >> 5) * 128;
  } else {
    int idx = bid - 384;
    A = ctxb; Bw = wkv; bias = bkv; outp = kvb; tout = cavt;
    K = 768; O = 1024; split = 512; tstride = 384; qsplit = 0;
    m0 = (idx % 3) * 128; o0 = (idx / 3) * 128;
  }
  int tid = threadIdx.x;
  int lane = tid & 63, w = tid >> 6;
  int wr = w >> 1, wc = w & 1;
  f32x4 acc[4][4];
#pragma unroll
  for (int i = 0; i < 4; ++i)
#pragma unroll
    for (int j = 0; j < 4; ++j) acc[i][j] = (f32x4){0.f, 0.f, 0.f, 0.f};
  int nk = K >> 6;

  auto stage = [&](int bi, int kt) {
    int k0 = kt << 6;
#pragma unroll
    for (int i = 0; i < 4; ++i) {
      int c = i * 256 + tid;
      int r = c >> 3, qs = c & 7, qg = qs ^ (r & 7);
      const char* ga = (const char*)(A + ((size_t)(m0 + r) * K + k0)) + (qg << 4);
      __builtin_amdgcn_global_load_lds((gas_t)ga, (las_t)((char*)As[bi] + (c << 4)), 16, 0, 0);
    }
#pragma unroll
    for (int i = 0; i < 4; ++i) {
      int c = i * 256 + tid;
      int r = c >> 3, qs = c & 7, qg = qs ^ (r & 7);
      const char* gb = (const char*)(Bw + ((size_t)(o0 + r) * K + k0)) + (qg << 4);
      __builtin_amdgcn_global_load_lds((gas_t)gb, (las_t)((char*)Bs[bi] + (c << 4)), 16, 0, 0);
    }
  };

  stage(0, 0);
  __syncthreads();
  for (int kt = 0; kt < nk; ++kt) {
    int cur = kt & 1;
    if (kt + 1 < nk) stage(cur ^ 1, kt + 1);
#pragma unroll
    for (int kk = 0; kk < 2; ++kk) {
      s8v a[4], bfr[4];
#pragma unroll
      for (int m = 0; m < 4; ++m) {
        int r = wr * 64 + m * 16 + (lane & 15);
        int q = (lane >> 4) + (kk << 2);
        a[m] = *(const s8v*)((const char*)As[cur] + r * 128 + ((q ^ (r & 7)) << 4));
      }
#pragma unroll
      for (int n = 0; n < 4; ++n) {
        int r = wc * 64 + n * 16 + (lane & 15);
        int q = (lane >> 4) + (kk << 2);
        bfr[n] = *(const s8v*)((const char*)Bs[cur] + r * 128 + ((q ^ (r & 7)) << 4));
      }
#pragma unroll
      for (int m = 0; m < 4; ++m)
#pragma unroll
        for (int n = 0; n < 4; ++n)
          acc[m][n] = __builtin_amdgcn_mfma_f32_16x16x32_bf16(a[m], bfr[n], acc[m][n], 0, 0, 0);
    }
    __syncthreads();
  }
  float bv[4];
#pragma unroll
  for (int n = 0; n < 4; ++n) bv[n] = bias[o0 + wc * 64 + n * 16 + (lane & 15)];
  int row_b = m0 + wr * 64 + ((lane >> 4) << 2);
  int col_b = o0 + wc * 64 + (lane & 15);
  if (o0 >= split) {
#pragma unroll
    for (int m = 0; m < 4; ++m) {
#pragma unroll
      for (int n = 0; n < 4; ++n) {
        int og = col_b + n * 16;
        short4 s4 = make_short4(f2bf(acc[m][n][0] + bv[n]), f2bf(acc[m][n][1] + bv[n]),
                                f2bf(acc[m][n][2] + bv[n]), f2bf(acc[m][n][3] + bv[n]));
        *(short4*)(tout + (size_t)(og - split) * tstride + row_b + m * 16) = s4;
      }
    }
    return;
  }
#pragma unroll
  for (int m = 0; m < 4; ++m) {
#pragma unroll
    for (int i = 0; i < 4; ++i) {
      int mg = row_b + m * 16 + i;
#pragma unroll
      for (int n = 0; n < 4; ++n) {
        int og = col_b + n * 16;
        float v = acc[m][n][i] + bv[n];
        if (og < qsplit) v *= SCL_L2E;
        ((short*)outp)[(size_t)mg * O + og] = f2bf(v);
      }
    }
  }
}

// ---------- self-attention, MFMA flash, KVBLK=128, dbuf, exp2 softmax, defer-max ----------
__global__ __launch_bounds__(TPB) void sa_attn_mfma(const short* __restrict__ qkv,
                                                    const short* __restrict__ vt,
                                                    short* __restrict__ outp) {
  __shared__ __align__(16) short Ks[2][128 * 64];
  __shared__ __align__(16) short Vs[2][64 * 128];
  __shared__ __align__(16) short Ps[4][16 * 128];
  int b = blockIdx.z, h = blockIdx.y, q0 = blockIdx.x * 64;
  int tid = threadIdx.x, lane = tid & 63, w = tid >> 6;
  int g = lane >> 4, qi = lane & 15;
  s8v qf[2];
  {
    const short* qp = qkv + (size_t)(b * 1024 + q0 + w * 16 + qi) * 1536 + h * 64 + g * 8;
    qf[0] = *(const s8v*)qp;
    qf[1] = *(const s8v*)(qp + 32);
  }
  f32x4 o[4];
#pragma unroll
  for (int d = 0; d < 4; ++d) o[d] = (f32x4){0.f, 0.f, 0.f, 0.f};
  float mrun = -1e30f, lrun = 0.f;
  const short* kbase = qkv + (size_t)(b * 1024) * 1536 + 512 + h * 64;
  const short* vbase = vt + (size_t)(h * 64) * 4096 + b * 1024;
  char* psw = (char*)Ps + w * 4096;
  int pswz = (qi & 15) << 4;

  auto stage = [&](int bufi, int kt) {
    int k0 = kt * 128;
#pragma unroll
    for (int i = 0; i < 4; ++i) {
      int c = i * 256 + tid;
      int r = c >> 3, cs = c & 7, cg = cs ^ (r & 7);
      const char* gp = (const char*)(kbase + (size_t)(k0 + r) * 1536) + (cg << 4);
      __builtin_amdgcn_global_load_lds((gas_t)gp, (las_t)((char*)Ks[bufi] + (c << 4)), 16, 0, 0);
    }
#pragma unroll
    for (int i = 0; i < 4; ++i) {
      int c = i * 256 + tid;
      int r = c >> 4, cs = c & 15, cg = cs ^ (r & 15);
      const char* gp = (const char*)(vbase + (size_t)r * 4096 + k0) + (cg << 4);
      __builtin_amdgcn_global_load_lds((gas_t)gp, (las_t)((char*)Vs[bufi] + (c << 4)), 16, 0, 0);
    }
  };

  stage(0, 0);
  __syncthreads();
  for (int kt = 0; kt < 8; ++kt) {
    int cur = kt & 1;
    if (kt < 7) stage(cur ^ 1, kt + 1);
    f32x4 st[8];
#pragma unroll
    for (int t = 0; t < 8; ++t) st[t] = (f32x4){0.f, 0.f, 0.f, 0.f};
    __builtin_amdgcn_s_setprio(1);
#pragma unroll
    for (int s = 0; s < 2; ++s) {
#pragma unroll
      for (int t = 0; t < 8; ++t) {
        int r = t * 16 + qi;
        s8v kf = *(const s8v*)((const char*)Ks[cur] + r * 128 + (((s * 4 + g) ^ (r & 7)) << 4));
        st[t] = __builtin_amdgcn_mfma_f32_16x16x32_bf16(kf, qf[s], st[t], 0, 0, 0);
      }
    }
    __builtin_amdgcn_s_setprio(0);
    float sv[32];
#pragma unroll
    for (int t = 0; t < 8; ++t)
#pragma unroll
      for (int r2 = 0; r2 < 4; ++r2) sv[t * 4 + r2] = st[t][r2];
    float mx = sv[0];
#pragma unroll
    for (int i = 1; i < 32; ++i) mx = fmaxf(mx, sv[i]);
    mx = fmaxf(mx, __shfl_xor(mx, 16));
    mx = fmaxf(mx, __shfl_xor(mx, 32));
    if (!__all(mx - mrun <= 11.f)) {
      float mnew = fmaxf(mrun, mx);
      float scale = fast_exp2(mrun - mnew);
      lrun *= scale;
#pragma unroll
      for (int d = 0; d < 4; ++d) o[d] *= scale;
      mrun = mnew;
    }
    float psum = 0.f;
#pragma unroll
    for (int i = 0; i < 32; ++i) { sv[i] = fast_exp2(sv[i] - mrun); psum += sv[i]; }
    psum += __shfl_xor(psum, 16);
    psum += __shfl_xor(psum, 32);
    lrun += psum;
#pragma unroll
    for (int t = 0; t < 8; ++t) {
      short4 pk = make_short4(f2bf(sv[t * 4]), f2bf(sv[t * 4 + 1]),
                              f2bf(sv[t * 4 + 2]), f2bf(sv[t * 4 + 3]));
      *(short4*)(psw + qi * 256 + ((t * 32 + g * 8) ^ pswz)) = pk;
    }
    __builtin_amdgcn_s_setprio(1);
#pragma unroll
    for (int s = 0; s < 4; ++s) {
      s8v bf = *(const s8v*)(psw + qi * 256 + ((s * 64 + g * 16) ^ pswz));
#pragma unroll
      for (int d = 0; d < 4; ++d) {
        int r = d * 16 + qi;
        s8v af = *(const s8v*)((const char*)Vs[cur] + r * 256 + (((s * 4 + g) ^ (r & 15)) << 4));
        o[d] = __builtin_amdgcn_mfma_f32_16x16x32_bf16(af, bf, o[d], 0, 0, 0);
      }
    }
    __builtin_amdgcn_s_setprio(0);
    __syncthreads();
  }
  float rl = 1.f / lrun;
  short* ob = outp + (size_t)(b * 1024 + q0 + w * 16 + qi) * 512 + h * 64;
#pragma unroll
  for (int d = 0; d < 4; ++d) {
    short4 s4 = make_short4(f2bf(o[d][0] * rl), f2bf(o[d][1] * rl),
                            f2bf(o[d][2] * rl), f2bf(o[d][3] * rl));
    *(short4*)(ob + d * 16 + g * 4) = s4;
  }
}

// ---------- cross-attention, MFMA single-pass (q pre-scaled, exp2) ----------
__global__ __launch_bounds__(TPB) void ca_attn_mfma(const short* __restrict__ qb,
                                                    const short* __restrict__ kvb,
                                                    const short* __restrict__ cavt,
                                                    short* __restrict__ outp) {
  __shared__ __align__(16) short Ks[96 * 64];
  __shared__ __align__(16) short Vs[64 * 128];
  __shared__ __align__(16) short Ps[4][16 * 128];
  int b = blockIdx.z, h = blockIdx.y, q0 = blockIdx.x * 64;
  int tid = threadIdx.x, lane = tid & 63, w = tid >> 6;
  int g = lane >> 4, qi = lane & 15;
  s8v qf[2];
  {
    const short* qp = qb + (size_t)(b * 1024 + q0 + w * 16 + qi) * 512 + h * 64 + g * 8;
    qf[0] = *(const s8v*)qp;
    qf[1] = *(const s8v*)(qp + 32);
  }
  const short* kbase = kvb + (size_t)(b * 96) * 1024 + h * 64;
#pragma unroll
  for (int i = 0; i < 3; ++i) {
    int c = i * 256 + tid;
    int r = c >> 3, cs = c & 7, cg = cs ^ (r & 7);
    const char* gp = (const char*)(kbase + (size_t)r * 1024) + (cg << 4);
    __builtin_amdgcn_global_load_lds((gas_t)gp, (las_t)((char*)Ks + (c << 4)), 16, 0, 0);
  }
#pragma unroll
  for (int i = 0; i < 3; ++i) {
    int c = i * 256 + tid;
    int r = c / 12, jj = c - r * 12;
    int4 dv = *(const int4*)(cavt + (size_t)(h * 64 + r) * 384 + b * 96 + jj * 8);
    *(int4*)((char*)Vs + r * 256 + ((jj * 16) ^ ((r & 7) << 4))) = dv;
  }
  __syncthreads();
  f32x4 st[6];
#pragma unroll
  for (int t = 0; t < 6; ++t) st[t] = (f32x4){0.f, 0.f, 0.f, 0.f};
  __builtin_amdgcn_s_setprio(1);
#pragma unroll
  for (int s = 0; s < 2; ++s) {
#pragma unroll
    for (int t = 0; t < 6; ++t) {
      int r = t * 16 + qi;
      s8v kf = *(const s8v*)((const char*)Ks + r * 128 + (((s * 4 + g) ^ (r & 7)) << 4));
      st[t] = __builtin_amdgcn_mfma_f32_16x16x32_bf16(kf, qf[s], st[t], 0, 0, 0);
    }
  }
  __builtin_amdgcn_s_setprio(0);
  float sv[24];
#pragma unroll
  for (int t = 0; t < 6; ++t)
#pragma unroll
    for (int r2 = 0; r2 < 4; ++r2) {
      int key = t * 16 + g * 4 + r2;
      sv[t * 4 + r2] = (key < SEQ) ? st[t][r2] : -1e30f;
    }
  float mx = sv[0];
#pragma unroll
  for (int i = 1; i < 24; ++i) mx = fmaxf(mx, sv[i]);
  mx = fmaxf(mx, __shfl_xor(mx, 16));
  mx = fmaxf(mx, __shfl_xor(mx, 32));
  float l = 0.f;
#pragma unroll
  for (int i = 0; i < 24; ++i) { sv[i] = fast_exp2(sv[i] - mx); l += sv[i]; }
  l += __shfl_xor(l, 16);
  l += __shfl_xor(l, 32);
  char* psw = (char*)Ps + w * 4096;
  int pswz = (qi & 7) << 4;
#pragma unroll
  for (int t = 0; t < 6; ++t) {
    short4 pk = make_short4(f2bf(sv[t * 4]), f2bf(sv[t * 4 + 1]),
                            f2bf(sv[t * 4 + 2]), f2bf(sv[t * 4 + 3]));
    *(short4*)(psw + qi * 256 + ((t * 32 + g * 8) ^ pswz)) = pk;
  }
  f32x4 o[4];
#pragma unroll
  for (int d = 0; d < 4; ++d) o[d] = (f32x4){0.f, 0.f, 0.f, 0.f};
  __builtin_amdgcn_s_setprio(1);
#pragma unroll
  for (int s = 0; s < 3; ++s) {
    s8v bf = *(const s8v*)(psw + qi * 256 + ((s * 64 + g * 16) ^ pswz));
#pragma unroll
    for (int d = 0; d < 4; ++d) {
      int r = d * 16 + qi;
      s8v af = *(const s8v*)((const char*)Vs + r * 256 + (((s * 64 + g * 16) ^ ((r & 7) << 4))));
      o[d] = __builtin_amdgcn_mfma_f32_16x16x32_bf16(af, bf, o[d], 0, 0, 0);
    }
  }
  __builtin_amdgcn_s_setprio(0);
  float rl = 1.f / l;
  short* ob = outp + (size_t)(b * 1024 + q0 + w * 16 + qi) * 512 + h * 64;
#pragma unroll
  for (int d = 0; d < 4; ++d) {
    short4 s4 = make_short4(f2bf(o[d][0] * rl), f2bf(o[d][1] * rl),
                            f2bf(o[d][2] * rl), f2bf(o[d][3] * rl));
    *(short4*)(ob + d * 16 + g * 4) = s4;
  }
}

extern "C" void kernel_launch(void* const* d_in, const int* in_sizes, int n_in,
                              void* d_out, int out_size, void* d_ws, size_t ws_size,
                              hipStream_t stream) {
  const float* x        = (const float*)d_in[0];
  const float* context  = (const float*)d_in[1];
  const float* sa_nw    = (const float*)d_in[2];
  const float* sa_nb    = (const float*)d_in[3];
  const float* sa_qkv_w = (const float*)d_in[4];
  const float* sa_qkv_b = (const float*)d_in[5];
  const float* sa_pw    = (const float*)d_in[6];
  const float* sa_pb    = (const float*)d_in[7];
  const float* ca_nw    = (const float*)d_in[8];
  const float* ca_nb    = (const float*)d_in[9];
  const float* ca_qw    = (const float*)d_in[10];
  const float* ca_qb    = (const float*)d_in[11];
  const float* ca_kvw   = (const float*)d_in[12];
  const float* ca_kvb   = (const float*)d_in[13];
  const float* ca_pw    = (const float*)d_in[14];
  const float* ca_pb    = (const float*)d_in[15];
  const float* ff_nw    = (const float*)d_in[16];
  const float* ff_nb    = (const float*)d_in[17];
  const float* ff_w1    = (const float*)d_in[18];
  const float* ff_b1    = (const float*)d_in[19];
  const float* ff_w2    = (const float*)d_in[20];
  const float* ff_b2    = (const float*)d_in[21];
  float* outp = (float*)d_out;

  char* ws = (char*)d_ws;
  short*  xcur  = (short*)(ws);                          // [0,4M)  residual stream (cm bf16)
  short*  hb    = (short*)(ws + (4u << 20));             // [4,8M)  GN out / attn out (bf16 tm)
  short*  big   = (short*)(ws + (8u << 20));             // [8,24M) qkvb / qb / h1
  short*  qkvb  = big;
  short*  qb    = big;
  short*  h1    = big;
  short*  vt    = (short*)(ws + (24u << 20));            // [24,28M) V^T [512][4096]
  short*  kvb   = (short*)(ws + (28u << 20));            // 768KB
  short*  cavt  = (short*)(ws + (29u << 20));            // 384KB [512][384]
  short*  ctxb  = (short*)(ws + (30u << 20));            // 576KB
  float2* statsPart = (float2*)(ws + (31u << 20));       // [32][8] partials (SA)
  float2* statsCA   = statsPart + 256;                   // 32 raw sums (CA)
  float2* statsFFN  = statsPart + 288;                   // 32 raw sums (FFN)
  short*  wb    = (short*)(ws + (32u << 20));            // bf16 weights (~8.7MB)

  short* w_qkv = wb;
  short* w_sap = wb + 786432;
  short* w_caq = wb + 1048576;
  short* w_kv  = wb + 1310720;
  short* w_cap = wb + 2097152;
  short* w_f1  = wb + 2359296;
  short* w_f2  = wb + 3407872;

  dim3 blk(TPB);
  prep<<<4896, blk, 0, stream>>>(sa_qkv_w, sa_pw, ca_qw, ca_kvw, ca_pw, ff_w1, ff_w2, wb,
                                 context, ctxb, x, statsPart, statsCA, statsFFN);

  // ---- self-attention (+ merged CA kv projection) ----
  gn_apply<0><<<dim3(16, 32), blk, 0, stream>>>(x, sa_nw, sa_nb, statsPart, hb, 8);
  gemm_qkvkv<<<408, blk, 0, stream>>>(hb, w_qkv, sa_qkv_b, ctxb, w_kv, ca_kvb,
                                      qkvb, vt, kvb, cavt);
  sa_attn_mfma<<<dim3(16, 8, 4), blk, 0, stream>>>(qkvb, vt, hb);
  gemm_nt<128, 64, 10><<<dim3(32, 8), blk, 0, stream>>>(hb, w_sap, sa_pb, x, xcur, 512, 512, 1.f, statsCA);

  // ---- cross-attention ----
  gn_apply<1><<<dim3(16, 32), blk, 0, stream>>>(xcur, ca_nw, ca_nb, statsCA, hb, 1);
  gemm_nt<128, 64, 0><<<dim3(32, 8), blk, 0, stream>>>(hb, w_caq, ca_qb, nullptr, qb, 512, 512, SCL_L2E, nullptr);
  ca_attn_mfma<<<dim3(16, 8, 4), blk, 0, stream>>>(qb, kvb, cavt, hb);
  gemm_nt<128, 64, 11><<<dim3(32, 8), blk, 0, stream>>>(hb, w_cap, ca_pb, xcur, xcur, 512, 512, 1.f, statsFFN);

  // ---- FFN ----
  gn_apply<1><<<dim3(16, 32), blk, 0, stream>>>(xcur, ff_nw, ff_nb, statsFFN, hb, 1);
  gemm_nt<128, 128, 2><<<dim3(32, 16), blk, 0, stream>>>(hb, w_f1, ff_b1, nullptr, h1, 512, 2048, 1.f, nullptr);
  gemm_nt<128, 64, 12><<<dim3(32, 8), blk, 0, stream>>>(h1, w_f2, ff_b2, xcur, outp, 2048, 512, 1.f, nullptr);
}